// Round 12
// baseline (335.370 us; speedup 1.0000x reference)
//
#include <hip/hip_runtime.h>

namespace {
constexpr int kB = 16;
constexpr int kMAXLEN = 1024;
constexpr int kPE = 256;
constexpr int kN = 1024;
constexpr int kEMB = 256;
constexpr int kC = 128;
constexpr float kEPS = 1e-5f;

// workspace offsets in floats
constexpr size_t OFF_FEATPART = 0;                         // 16*64*256 = 262144
constexpr size_t OFF_M1       = 262144;                    // 512*16
constexpr size_t OFF_X        = 270336;                    // 16*1024*128
constexpr size_t OFF_Z        = OFF_X    + 2097152;
constexpr size_t OFF_TCUR     = OFF_Z    + 2097152;
constexpr size_t OFF_TNEXT    = OFF_TCUR + 2097152;
constexpr size_t OFF_GOPART   = OFF_TNEXT+ 2097152;        // 8*16*65536 = 8388608
constexpr size_t OFF_PSUM     = OFF_GOPART + 8388608;      // 16*16*1024
constexpr size_t OFF_SUMZ     = OFF_PSUM + 262144;         // 16384
constexpr size_t OFF_SUMZZ    = OFF_SUMZ + 16384;          // 16384
constexpr size_t OFF_ADJH     = OFF_SUMZZ + 16384;
constexpr size_t OFF_ADJL     = OFF_ADJH + 8388608;
constexpr size_t OFF_XTH      = OFF_ADJL + 8388608;
constexpr size_t OFF_XTL      = OFF_XTH  + 1048576;
constexpr size_t OFF_QH       = OFF_XTL  + 1048576;
constexpr size_t OFF_QL       = OFF_QH   + 524288;
constexpr size_t OFF_KH       = OFF_QL   + 524288;
constexpr size_t OFF_KL       = OFF_KH   + 524288;
constexpr size_t OFF_TTH      = OFF_KL   + 524288;
constexpr size_t OFF_TTL      = OFF_TTH  + 1048576;

typedef __attribute__((ext_vector_type(8))) short bfrag;
typedef __attribute__((ext_vector_type(4))) float f32x4;

__device__ inline ushort f2bf(float f) {
  unsigned u = __float_as_uint(f);
  unsigned r = (u + 0x7FFFu + ((u >> 16) & 1u)) >> 16;  // RNE
  return (ushort)r;
}
__device__ inline float bf2f(ushort h) { return __uint_as_float(((unsigned)h) << 16); }
} // namespace

// ---- 1. embedding gather partial sums: featpart[b][chunk64][e] ----
__global__ __launch_bounds__(256) void k_embsum(const int* __restrict__ data,
                                                const float* __restrict__ emb,
                                                float* __restrict__ featpart) {
  const int b = blockIdx.x, ch = blockIdx.y;   // 16 x 64
  const int e = threadIdx.x;                   // 256
  const int* row = data + b * (kMAXLEN + kPE) + ch * 16;
  float acc = 0.f;
#pragma unroll 4
  for (int l = 0; l < 16; ++l) {
    acc += emb[(size_t)row[l] * kEMB + e];
  }
  featpart[((b * 64 + ch) << 8) + e] = acc;
}

// ---- 2. BN over batch -> m1t (512,16). 16 blocks x 32 j, 8 lanes/j ----
__global__ __launch_bounds__(256) void k_bn_feat(const float* __restrict__ featpart,
                                                 const int* __restrict__ data,
                                                 const float* __restrict__ g1,
                                                 const float* __restrict__ b1,
                                                 float* __restrict__ m1t) {
  const int tid = threadIdx.x;
  const int jl = tid >> 3, part = tid & 7;
  const int j = blockIdx.x * 32 + jl;
  float v[kB];
  if (j < kPE) {
#pragma unroll
    for (int b = 0; b < kB; ++b) {
      float s = 0.f;
      const int ch0 = part * 8;
#pragma unroll
      for (int ch = 0; ch < 8; ++ch)
        s += featpart[((b * 64 + ch0 + ch) << 8) + j];
      v[b] = s;
    }
  } else {
#pragma unroll
    for (int b = 0; b < kB; ++b)
      v[b] = (part == 0) ? (float)data[b * (kMAXLEN + kPE) + kMAXLEN + (j - kPE)] : 0.f;
  }
#pragma unroll
  for (int m = 1; m < 8; m <<= 1) {
#pragma unroll
    for (int b = 0; b < kB; ++b) v[b] += __shfl_xor(v[b], m);
  }
  const float pe = (j < kPE) ? sinf((float)j) : sinf((float)(j - kPE));
#pragma unroll
  for (int b = 0; b < kB; ++b)
    v[b] = (j < kPE) ? (v[b] * (1.f / 1024.f) + pe) : (v[b] + pe);
  float s = 0.f;
#pragma unroll
  for (int b = 0; b < kB; ++b) s += v[b];
  const float mean = s * (1.f / kB);
  float s2 = 0.f;
#pragma unroll
  for (int b = 0; b < kB; ++b) { float d = v[b] - mean; s2 += d * d; }
  const float inv = rsqrtf(s2 * (1.f / kB) + kEPS);
  if (part == 0) {
    const float g = g1[j], bb = b1[j];
    float o[kB];
#pragma unroll
    for (int b = 0; b < kB; ++b) o[b] = (v[b] - mean) * inv * g + bb;
#pragma unroll
    for (int q = 0; q < 4; ++q)
      *reinterpret_cast<float4*>(&m1t[j * kB + q * 4]) =
          *reinterpret_cast<float4*>(&o[q * 4]);
  }
}

// ---- 3a. split-K GEMM, 8 k-slices, m1 via LDS broadcast ----
__global__ __launch_bounds__(256) void k_go_gemm2(const float* __restrict__ m1t,
                                                  const float* __restrict__ w_go,
                                                  float* __restrict__ part) {
  const int c0 = blockIdx.x * 1024 + threadIdx.x * 4;
  const int k0 = blockIdx.y * 64;
  __shared__ float4 m1s[64 * 4];
  {
    const int k = threadIdx.x >> 2, q = threadIdx.x & 3;
    m1s[threadIdx.x] = *reinterpret_cast<const float4*>(&m1t[(size_t)(k0 + k) * kB + q * 4]);
  }
  __syncthreads();
  float4 acc[kB];
#pragma unroll
  for (int b = 0; b < kB; ++b) acc[b] = make_float4(0.f, 0.f, 0.f, 0.f);
#pragma unroll 8
  for (int k = 0; k < 64; ++k) {
    const float4 w = *reinterpret_cast<const float4*>(&w_go[(size_t)(k0 + k) * 65536 + c0]);
    const float4 m0 = m1s[k * 4 + 0];
    const float4 m1v = m1s[k * 4 + 1];
    const float4 m2 = m1s[k * 4 + 2];
    const float4 m3 = m1s[k * 4 + 3];
    const float mv[kB] = {m0.x, m0.y, m0.z, m0.w, m1v.x, m1v.y, m1v.z, m1v.w,
                          m2.x, m2.y, m2.z, m2.w, m3.x, m3.y, m3.z, m3.w};
#pragma unroll
    for (int b = 0; b < kB; ++b) {
      acc[b].x += mv[b] * w.x; acc[b].y += mv[b] * w.y;
      acc[b].z += mv[b] * w.z; acc[b].w += mv[b] * w.w;
    }
  }
  const size_t kb16 = (size_t)blockIdx.y * kB;
#pragma unroll
  for (int b = 0; b < kB; ++b) {
    *reinterpret_cast<float4*>(&part[(kb16 + b) * 65536 + c0]) = acc[b];
  }
}

// ---- 3b+4 fused. per-node: reduce 8 go partials + bias/relu, nf concat, BN -> x ----
__global__ __launch_bounds__(256) void k_go_bn(const float* __restrict__ part,
                                               const float* __restrict__ b_go,
                                               const float* __restrict__ nf,
                                               const float* __restrict__ g3,
                                               const float* __restrict__ b3,
                                               float* __restrict__ x) {
  const int n = blockIdx.x;
  const int tid = threadIdx.x;
  __shared__ float nfs[64];
  if (tid < 64) nfs[tid] = nf[n * 64 + tid];
  float val[4];
  float s = 0.f, s2 = 0.f;
#pragma unroll
  for (int i = 0; i < 4; ++i) {
    const int e = i * 256 + tid;
    const int b = e >> 6, c = e & 63;
    float a = part[(size_t)b * 65536 + n * 64 + c];
#pragma unroll
    for (int kb = 1; kb < 8; ++kb)
      a += part[(size_t)(kb * kB + b) * 65536 + n * 64 + c];
    a = fmaxf(a + b_go[n * 64 + c], 0.f);
    val[i] = a;
    s += a; s2 += a * a;
  }
  __syncthreads();
  if (tid < 64) {
    const float v = nfs[tid];
    s += 16.f * v; s2 += 16.f * v * v;
  }
  for (int o = 32; o > 0; o >>= 1) { s += __shfl_down(s, o); s2 += __shfl_down(s2, o); }
  __shared__ float ls[4], ls2[4];
  __shared__ float sscale, sshift;
  const int w = tid >> 6;
  if ((tid & 63) == 0) { ls[w] = s; ls2[w] = s2; }
  __syncthreads();
  if (tid == 0) {
    float S = ls[0] + ls[1] + ls[2] + ls[3];
    float S2 = ls2[0] + ls2[1] + ls2[2] + ls2[3];
    float mean = S * (1.f / 2048.f);
    float var = fmaxf(S2 * (1.f / 2048.f) - mean * mean, 0.f);
    float inv = rsqrtf(var + kEPS);
    float gg = g3[n];
    sscale = inv * gg;
    sshift = b3[n] - mean * inv * gg;
  }
  __syncthreads();
  const float scale = sscale, shift = sshift;
#pragma unroll
  for (int i = 0; i < 4; ++i) {
    const int e = i * 256 + tid;
    const int b = e >> 6, c = e & 63;
    x[((size_t)(b * kN + n)) * kC + c] = val[i] * scale + shift;
  }
#pragma unroll
  for (int i = 0; i < 4; ++i) {
    const int e = i * 256 + tid;
    const int b = e >> 6, c = e & 63;
    x[((size_t)(b * kN + n)) * kC + 64 + c] = nfs[c] * scale + shift;
  }
}

// ---- 5. q/k projections -> bf16 hi/lo, [bn][64] layout ----
__global__ __launch_bounds__(256) void k_qkgen(const float* __restrict__ x,
                                               const float* __restrict__ wq,
                                               const float* __restrict__ wk,
                                               ushort* __restrict__ qh, ushort* __restrict__ ql,
                                               ushort* __restrict__ kh, ushort* __restrict__ kl) {
  __shared__ float a_s[32 * 68];
  __shared__ float w_s[32 * 128];
  const int row0 = blockIdx.x * 32;
  const int tid = threadIdx.x;
  const int tr = tid >> 5, tc = tid & 31;
  const int r0 = tr * 4, c0 = tc * 4;
  float acc[4][4] = {};
  for (int kc = 0; kc < 4; ++kc) {
    const int k0 = kc * 32;
    __syncthreads();
    {
      int r = tid >> 3, kk4 = tid & 7;
      float4 v = *reinterpret_cast<const float4*>(&x[(size_t)(row0 + r) * kC + k0 + kk4 * 4]);
      *reinterpret_cast<float4*>(&a_s[r * 68 + kk4 * 4]) = v;
    }
    for (int it = 0; it < 16; ++it) {
      int e = it * 256 + tid;
      int kk = e >> 7, h2 = e & 127;
      int c = k0 + kk;
      float v = (h2 < 64) ? wq[c * 64 + h2] : wk[c * 64 + (h2 - 64)];
      w_s[kk * 128 + h2] = v;
    }
    __syncthreads();
#pragma unroll 8
    for (int k = 0; k < 32; ++k) {
      float a[4];
#pragma unroll
      for (int i = 0; i < 4; ++i) a[i] = a_s[(r0 + i) * 68 + k];
      float4 b4 = *reinterpret_cast<float4*>(&w_s[k * 128 + c0]);
      float bj[4] = {b4.x, b4.y, b4.z, b4.w};
#pragma unroll
      for (int i = 0; i < 4; ++i)
#pragma unroll
        for (int j = 0; j < 4; ++j) acc[i][j] += a[i] * bj[j];
    }
  }
  const bool isq = (c0 < 64);
  const int h0 = isq ? c0 : (c0 - 64);
  ushort* oh = isq ? qh : kh;
  ushort* ol = isq ? ql : kl;
#pragma unroll
  for (int i = 0; i < 4; ++i) {
    ushort hs[4], ls[4];
#pragma unroll
    for (int j = 0; j < 4; ++j) {
      float v = acc[i][j];
      ushort h = f2bf(v);
      hs[j] = h;
      ls[j] = f2bf(v - bf2f(h));
    }
    const size_t o = (size_t)(row0 + r0 + i) * 64 + h0;
    *reinterpret_cast<ushort4*>(&oh[o]) = *reinterpret_cast<ushort4*>(hs);
    *reinterpret_cast<ushort4*>(&ol[o]) = *reinterpret_cast<ushort4*>(ls);
  }
}

// ---- 6. att sum-stats via MFMA, mc-range split across blockIdx.z ----
__global__ __launch_bounds__(512) void k_att_stats(const ushort* __restrict__ qh,
                                                   const ushort* __restrict__ ql,
                                                   const ushort* __restrict__ kh,
                                                   const ushort* __restrict__ kl,
                                                   float* __restrict__ psum) {
  const int nt = blockIdx.x, b = blockIdx.y;
  const int mc0 = blockIdx.z * 4;  // 2 halves x 4 chunks
  __shared__ uint4 smem4[3072];  // 48 KiB: Qh@0 Ql@8K Kh@16K Kl@32K
  char* smem = (char*)smem4;
  const int tid = threadIdx.x;
  const int lane = tid & 63, w = tid >> 6;
  const int l15 = lane & 15, lg = lane >> 4;

  {  // stage Q once
    const int r = tid >> 3, ch = tid & 7;
    const size_t g = (size_t)(b * kN + nt * 64 + r) * 64 + ch * 8;
    const unsigned off = (unsigned)(r * 128 + ch * 16) ^ (unsigned)((r & 7) << 4);
    *reinterpret_cast<uint4*>(smem + off) = *reinterpret_cast<const uint4*>(qh + g);
    *reinterpret_cast<uint4*>(smem + 8192 + off) = *reinterpret_cast<const uint4*>(ql + g);
  }

  const int c0s = tid >> 3, c1s = 64 + (tid >> 3);
  const int chs = tid & 7;
  const unsigned offK0 = (unsigned)(c0s * 128 + chs * 16) ^ (unsigned)((c0s & 7) << 4);
  const unsigned offK1 = (unsigned)(c1s * 128 + chs * 16) ^ (unsigned)((c1s & 7) << 4);
  const size_t gK0 = (size_t)(b * kN + mc0 * 128 + c0s) * 64 + chs * 8;
  const size_t gK1 = (size_t)(b * kN + mc0 * 128 + c1s) * 64 + chs * 8;

  uint4 ph0 = *reinterpret_cast<const uint4*>(kh + gK0);
  uint4 ph1 = *reinterpret_cast<const uint4*>(kh + gK1);
  uint4 pl0 = *reinterpret_cast<const uint4*>(kl + gK0);
  uint4 pl1 = *reinterpret_cast<const uint4*>(kl + gK1);

  for (int it = 0; it < 4; ++it) {
    const int mc = mc0 + it;
    __syncthreads();
    *reinterpret_cast<uint4*>(smem + 16384 + offK0) = ph0;
    *reinterpret_cast<uint4*>(smem + 16384 + offK1) = ph1;
    *reinterpret_cast<uint4*>(smem + 32768 + offK0) = pl0;
    *reinterpret_cast<uint4*>(smem + 32768 + offK1) = pl1;
    __syncthreads();
    if (it < 3) {
      const size_t k1 = (size_t)(it + 1) * 128 * 64;
      ph0 = *reinterpret_cast<const uint4*>(kh + gK0 + k1);
      ph1 = *reinterpret_cast<const uint4*>(kh + gK1 + k1);
      pl0 = *reinterpret_cast<const uint4*>(kl + gK0 + k1);
      pl1 = *reinterpret_cast<const uint4*>(kl + gK1 + k1);
    }
    f32x4 acc[4] = {{0.f,0.f,0.f,0.f},{0.f,0.f,0.f,0.f},{0.f,0.f,0.f,0.f},{0.f,0.f,0.f,0.f}};
#pragma unroll
    for (int ss = 0; ss < 2; ++ss) {
      const int r = w * 16 + l15;
      const unsigned aoff = (unsigned)(r * 128 + ss * 64 + lg * 16) ^ (unsigned)((r & 7) << 4);
      bfrag ah = *reinterpret_cast<const bfrag*>(smem + 16384 + aoff);
      bfrag al = *reinterpret_cast<const bfrag*>(smem + 32768 + aoff);
#pragma unroll
      for (int nf = 0; nf < 4; ++nf) {
        const int c = nf * 16 + l15;
        const unsigned boff = (unsigned)(c * 128 + ss * 64 + lg * 16) ^ (unsigned)((c & 7) << 4);
        bfrag bh = *reinterpret_cast<const bfrag*>(smem + boff);
        bfrag bl = *reinterpret_cast<const bfrag*>(smem + 8192 + boff);
        acc[nf] = __builtin_amdgcn_mfma_f32_16x16x32_bf16(ah, bh, acc[nf], 0, 0, 0);
        acc[nf] = __builtin_amdgcn_mfma_f32_16x16x32_bf16(ah, bl, acc[nf], 0, 0, 0);
        acc[nf] = __builtin_amdgcn_mfma_f32_16x16x32_bf16(al, bh, acc[nf], 0, 0, 0);
      }
    }
#pragma unroll
    for (int i = 0; i < 4; ++i) {
      float sm = __expf(acc[0][i] * 0.125f) + __expf(acc[1][i] * 0.125f)
               + __expf(acc[2][i] * 0.125f) + __expf(acc[3][i] * 0.125f);
#pragma unroll
      for (int msk = 1; msk < 16; msk <<= 1) sm += __shfl_xor(sm, msk);
      if (l15 == 0) {
        const int m = mc * 128 + w * 16 + lg * 4 + i;
        psum[(size_t)(b * 16 + nt) * kN + m] = sm;
      }
    }
  }
}

// ---- 8. adj emit: recompute Q·K^T, adj = go_adj + exp(s/8)*cinv (cinv inline) ----
__global__ __launch_bounds__(512) void k_adj_emit(const ushort* __restrict__ qh,
                                                  const ushort* __restrict__ ql,
                                                  const ushort* __restrict__ kh,
                                                  const ushort* __restrict__ kl,
                                                  const float* __restrict__ go_adj,
                                                  const float* __restrict__ psum,
                                                  ushort* __restrict__ adj_hi,
                                                  ushort* __restrict__ adj_lo) {
  const int mc = blockIdx.x, nt = blockIdx.y, b = blockIdx.z;
  __shared__ uint4 smem4[3072];
  __shared__ float cinvs[128];
  char* smem = (char*)smem4;
  float* c32 = (float*)smem4;
  const int tid = threadIdx.x;
  const int lane = tid & 63, w = tid >> 6;
  const int wr = w >> 2, wc = w & 3;
  const int l15 = lane & 15, lg = lane >> 4;

  if (tid < 128) {
    const int m = mc * 128 + tid;
    float S = 0.f;
#pragma unroll
    for (int c = 0; c < 16; ++c) S += psum[(size_t)(b * 16 + c) * kN + m];
    cinvs[tid] = 1.f / S;
  }
  {
    const int r = tid >> 3, ch = tid & 7;
    const size_t g = (size_t)(b * kN + nt * 64 + r) * 64 + ch * 8;
    const unsigned off = (unsigned)(r * 128 + ch * 16) ^ (unsigned)((r & 7) << 4);
    *reinterpret_cast<uint4*>(smem + off) = *reinterpret_cast<const uint4*>(qh + g);
    *reinterpret_cast<uint4*>(smem + 8192 + off) = *reinterpret_cast<const uint4*>(ql + g);
  }
#pragma unroll
  for (int p = 0; p < 2; ++p) {
    const int e = p * 512 + tid;
    const int c = e >> 3, ch = e & 7;
    const size_t g = (size_t)(b * kN + mc * 128 + c) * 64 + ch * 8;
    const unsigned off = (unsigned)(c * 128 + ch * 16) ^ (unsigned)((c & 7) << 4);
    *reinterpret_cast<uint4*>(smem + 16384 + off) = *reinterpret_cast<const uint4*>(kh + g);
    *reinterpret_cast<uint4*>(smem + 32768 + off) = *reinterpret_cast<const uint4*>(kl + g);
  }
  __syncthreads();
  f32x4 acc[2][2] = {{{0.f,0.f,0.f,0.f},{0.f,0.f,0.f,0.f}},
                     {{0.f,0.f,0.f,0.f},{0.f,0.f,0.f,0.f}}};
#pragma unroll
  for (int ss = 0; ss < 2; ++ss) {
    bfrag ah[2], al[2], bh[2], bl[2];
#pragma unroll
    for (int nf = 0; nf < 2; ++nf) {
      const int r = wr * 32 + nf * 16 + l15;
      const unsigned aoff = (unsigned)(r * 128 + ss * 64 + lg * 16) ^ (unsigned)((r & 7) << 4);
      ah[nf] = *reinterpret_cast<const bfrag*>(smem + aoff);
      al[nf] = *reinterpret_cast<const bfrag*>(smem + 8192 + aoff);
    }
#pragma unroll
    for (int mf = 0; mf < 2; ++mf) {
      const int c = wc * 32 + mf * 16 + l15;
      const unsigned boff = (unsigned)(c * 128 + ss * 64 + lg * 16) ^ (unsigned)((c & 7) << 4);
      bh[mf] = *reinterpret_cast<const bfrag*>(smem + 16384 + boff);
      bl[mf] = *reinterpret_cast<const bfrag*>(smem + 32768 + boff);
    }
#pragma unroll
    for (int nf = 0; nf < 2; ++nf)
#pragma unroll
      for (int mf = 0; mf < 2; ++mf) {
        acc[nf][mf] = __builtin_amdgcn_mfma_f32_16x16x32_bf16(ah[nf], bh[mf], acc[nf][mf], 0, 0, 0);
        acc[nf][mf] = __builtin_amdgcn_mfma_f32_16x16x32_bf16(ah[nf], bl[mf], acc[nf][mf], 0, 0, 0);
        acc[nf][mf] = __builtin_amdgcn_mfma_f32_16x16x32_bf16(al[nf], bh[mf], acc[nf][mf], 0, 0, 0);
      }
  }
  __syncthreads();
#pragma unroll
  for (int mf = 0; mf < 2; ++mf) {
    const int mLoc = wc * 32 + mf * 16 + l15;
    const float I = cinvs[mLoc];
#pragma unroll
    for (int nf = 0; nf < 2; ++nf) {
#pragma unroll
      for (int i = 0; i < 4; ++i) {
        const int nLoc = wr * 32 + nf * 16 + lg * 4 + i;
        c32[nLoc * 132 + mLoc] = __expf(acc[nf][mf][i] * 0.125f) * I;
      }
    }
  }
  __syncthreads();
#pragma unroll
  for (int p = 0; p < 2; ++p) {
    const int e = p * 512 + tid;
    const int n = e >> 4, m0 = (e & 15) * 8;
    const float* cr = &c32[n * 132 + m0];
    const float* ga = &go_adj[(size_t)(nt * 64 + n) * kN + mc * 128 + m0];
    ushort hs[8], ls[8];
#pragma unroll
    for (int j = 0; j < 8; ++j) {
      float v = cr[j] + ga[j];
      ushort h = f2bf(v);
      hs[j] = h;
      ls[j] = f2bf(v - bf2f(h));
    }
    const size_t o = (size_t)(b * kN + nt * 64 + n) * kN + mc * 128 + m0;
    *reinterpret_cast<uint4*>(&adj_hi[o]) = *reinterpret_cast<uint4*>(hs);
    *reinterpret_cast<uint4*>(&adj_lo[o]) = *reinterpret_cast<uint4*>(ls);
  }
}

// ---- T. transpose+split: f32 [16][1024][128] -> bf16 hi/lo [16][128][1024] ----
__global__ __launch_bounds__(256) void k_transp(const float* __restrict__ src,
                                                ushort* __restrict__ xt_hi,
                                                ushort* __restrict__ xt_lo) {
  const int nt = blockIdx.x, b = blockIdx.y;
  __shared__ float tile[64][133];
  const int tid = threadIdx.x;
#pragma unroll
  for (int it = 0; it < 8; ++it) {
    int e = it * 256 + tid;
    int r = e >> 5, c4 = e & 31;
    float4 v = *reinterpret_cast<const float4*>(&src[(size_t)(b * kN + nt * 64 + r) * kC + c4 * 4]);
    *reinterpret_cast<float4*>(&tile[r][c4 * 4]) = v;
  }
  __syncthreads();
  const int cl = tid >> 3;
  const int chunk = tid & 7;
  const int n0 = chunk * 8;
#pragma unroll
  for (int cg = 0; cg < 4; ++cg) {
    const int c = cg * 32 + cl;
    const size_t obase = (size_t)(b * kC + c) * kN + nt * 64 + n0;
    ushort hs[8], ls[8];
#pragma unroll
    for (int j = 0; j < 8; ++j) {
      float v = tile[n0 + j][c];
      ushort h = f2bf(v);
      hs[j] = h;
      ls[j] = f2bf(v - bf2f(h));
    }
    *reinterpret_cast<uint4*>(&xt_hi[obase]) = *reinterpret_cast<uint4*>(hs);
    *reinterpret_cast<uint4*>(&xt_lo[obase]) = *reinterpret_cast<uint4*>(ls);
  }
}

// ---- 9. Y = alpha * adj @ X (- Zsub); BM=32, grid 512 (2 blocks/CU), T14 prefetch ----
// block 256 = 4 waves. LDS 40KB: Ah@0 Al@4K Bh@8K Bl@24K. c32 overlay in epilogue.
__global__ __launch_bounds__(256) void k_adjmm_mfma(const ushort* __restrict__ adj_hi,
                                                    const ushort* __restrict__ adj_lo,
                                                    const ushort* __restrict__ xt_hi,
                                                    const ushort* __restrict__ xt_lo,
                                                    const float* __restrict__ Zsub,
                                                    float* __restrict__ Y, float alpha,
                                                    ushort* __restrict__ yt_hi,
                                                    ushort* __restrict__ yt_lo) {
  const int bid = blockIdx.x;
  const int swz = (bid & 7) * 64 + (bid >> 3);  // bijective: 512 = 8*64; 2 batches/XCD
  const int b = swz >> 5, rb = swz & 31;
  __shared__ uint4 smem4[2560];  // 40 KiB
  char* smem = (char*)smem4;
  float* c32 = (float*)smem4;    // [32][132] overlay in epilogue
  const int tid = threadIdx.x;
  const int lane = tid & 63, w = tid >> 6;
  const int wr = w >> 1, wc = w & 1;
  const int l15 = lane & 15, lg = lane >> 4;

  // staging geometry
  const int ra = tid >> 3, cha = tid & 7;
  const unsigned offA = (unsigned)(ra * 128 + cha * 16) ^ (unsigned)((ra & 7) << 4);
  const size_t gA = ((size_t)(b * kN + rb * 32 + ra)) * kN + cha * 8;
  unsigned offBp[4];
  size_t gBp[4];
#pragma unroll
  for (int p = 0; p < 4; ++p) {
    const int e = p * 256 + tid;
    const int c = e >> 3;
    offBp[p] = (unsigned)(c * 128 + cha * 16) ^ (unsigned)((c & 7) << 4);
    gBp[p] = ((size_t)b * kC + c) * kN + cha * 8;
  }

  f32x4 acc[4] = {{0.f,0.f,0.f,0.f},{0.f,0.f,0.f,0.f},{0.f,0.f,0.f,0.f},{0.f,0.f,0.f,0.f}};

  // prologue: prefetch tile 0
  uint4 pah = *reinterpret_cast<const uint4*>(adj_hi + gA);
  uint4 pal = *reinterpret_cast<const uint4*>(adj_lo + gA);
  uint4 pbh[4], pbl[4];
#pragma unroll
  for (int p = 0; p < 4; ++p) {
    pbh[p] = *reinterpret_cast<const uint4*>(xt_hi + gBp[p]);
    pbl[p] = *reinterpret_cast<const uint4*>(xt_lo + gBp[p]);
  }

  for (int kt = 0; kt < 16; ++kt) {
    __syncthreads();
    *reinterpret_cast<uint4*>(smem + offA)        = pah;
    *reinterpret_cast<uint4*>(smem + 4096 + offA) = pal;
#pragma unroll
    for (int p = 0; p < 4; ++p) {
      *reinterpret_cast<uint4*>(smem + 8192 + offBp[p])  = pbh[p];
      *reinterpret_cast<uint4*>(smem + 24576 + offBp[p]) = pbl[p];
    }
    __syncthreads();
    if (kt < 15) {
      const int k1 = (kt + 1) * 64;
      pah = *reinterpret_cast<const uint4*>(adj_hi + gA + k1);
      pal = *reinterpret_cast<const uint4*>(adj_lo + gA + k1);
#pragma unroll
      for (int p = 0; p < 4; ++p) {
        pbh[p] = *reinterpret_cast<const uint4*>(xt_hi + gBp[p] + k1);
        pbl[p] = *reinterpret_cast<const uint4*>(xt_lo + gBp[p] + k1);
      }
    }
#pragma unroll
    for (int ss = 0; ss < 2; ++ss) {
      const int r = wr * 16 + l15;
      const unsigned aoff = (unsigned)(r * 128 + ss * 64 + lg * 16) ^ (unsigned)((r & 7) << 4);
      bfrag ah = *reinterpret_cast<const bfrag*>(smem + aoff);
      bfrag al = *reinterpret_cast<const bfrag*>(smem + 4096 + aoff);
      bfrag bh[4], bl[4];
#pragma unroll
      for (int ct = 0; ct < 4; ++ct) {
        const int c = wc * 64 + ct * 16 + l15;
        const unsigned boff = (unsigned)(c * 128 + ss * 64 + lg * 16) ^ (unsigned)((c & 7) << 4);
        bh[ct] = *reinterpret_cast<const bfrag*>(smem + 8192 + boff);
        bl[ct] = *reinterpret_cast<const bfrag*>(smem + 24576 + boff);
      }
#pragma unroll
      for (int ct = 0; ct < 4; ++ct) {
        acc[ct] = __builtin_amdgcn_mfma_f32_16x16x32_bf16(ah, bh[ct], acc[ct], 0, 0, 0);
        acc[ct] = __builtin_amdgcn_mfma_f32_16x16x32_bf16(ah, bl[ct], acc[ct], 0, 0, 0);
        acc[ct] = __builtin_amdgcn_mfma_f32_16x16x32_bf16(al, bh[ct], acc[ct], 0, 0, 0);
      }
    }
  }
  const int orow = rb * 32 + wr * 16 + lg * 4;
  __syncthreads();  // all LDS reads done before c32 overlay
#pragma unroll
  for (int ct = 0; ct < 4; ++ct) {
    const int ocol = wc * 64 + ct * 16 + l15;
#pragma unroll
    for (int i = 0; i < 4; ++i) {
      const size_t idx = ((size_t)(b * kN + orow + i)) * kC + ocol;
      float v = alpha * acc[ct][i];
      if (Zsub) v -= Zsub[idx];
      Y[idx] = v;
      if (yt_hi) c32[(wr * 16 + lg * 4 + i) * 132 + ocol] = v;
    }
  }
  if (yt_hi) {
    __syncthreads();
    // write Y^T: [b][c][rb*32 + n], 16 n per thread
    const int c = tid >> 1, nch = tid & 1;
    const int n0 = nch * 16;
    ushort hs[16], ls[16];
#pragma unroll
    for (int j = 0; j < 16; ++j) {
      float v = c32[(n0 + j) * 132 + c];
      ushort h = f2bf(v);
      hs[j] = h;
      ls[j] = f2bf(v - bf2f(h));
    }
    const size_t obase = (size_t)(b * kC + c) * kN + rb * 32 + n0;
    *reinterpret_cast<uint4*>(&yt_hi[obase]) = *reinterpret_cast<uint4*>(hs);
    *reinterpret_cast<uint4*>(&yt_hi[obase + 8]) = *reinterpret_cast<uint4*>(hs + 8);
    *reinterpret_cast<uint4*>(&yt_lo[obase]) = *reinterpret_cast<uint4*>(ls);
    *reinterpret_cast<uint4*>(&yt_lo[obase + 8]) = *reinterpret_cast<uint4*>(ls + 8);
  }
}

// ---- 10. z = x@th0 + tcur@th1 + tnext@th2 + x ; emits per-row sum/sumsq ----
__global__ __launch_bounds__(256) void k_theta(const float* __restrict__ x,
                                               const float* __restrict__ tcur,
                                               const float* __restrict__ tnext,
                                               const float* __restrict__ theta,
                                               float* __restrict__ z,
                                               float* __restrict__ sumz,
                                               float* __restrict__ sumzz) {
  __shared__ float a_s[32 * 68];
  __shared__ float w_s[32 * 128];
  const int row0 = blockIdx.x * 32;
  const int tid = threadIdx.x;
  const int tr = tid >> 5, tc = tid & 31;
  const int r0 = tr * 4, c0 = tc * 4;
  float acc[4][4] = {};
  const float* srcs[3] = {x, tcur, tnext};
  for (int s = 0; s < 3; ++s) {
    const float* A = srcs[s];
    for (int kc = 0; kc < 4; ++kc) {
      const int k0 = kc * 32;
      __syncthreads();
      {
        int r = tid >> 3, kk4 = tid & 7;
        float4 v = *reinterpret_cast<const float4*>(&A[(size_t)(row0 + r) * kC + k0 + kk4 * 4]);
        *reinterpret_cast<float4*>(&a_s[r * 68 + kk4 * 4]) = v;
      }
#pragma unroll
      for (int it = 0; it < 4; ++it) {
        int e4 = it * 256 + tid;
        int kk = e4 >> 5, d4 = e4 & 31;
        float4 v = *reinterpret_cast<const float4*>(
            &theta[(size_t)s * 16384 + (size_t)(k0 + kk) * kC + d4 * 4]);
        *reinterpret_cast<float4*>(&w_s[kk * 128 + d4 * 4]) = v;
      }
      __syncthreads();
#pragma unroll 8
      for (int k = 0; k < 32; ++k) {
        float a[4];
#pragma unroll
        for (int i = 0; i < 4; ++i) a[i] = a_s[(r0 + i) * 68 + k];
        float4 b4 = *reinterpret_cast<float4*>(&w_s[k * 128 + c0]);
        float bj[4] = {b4.x, b4.y, b4.z, b4.w};
#pragma unroll
        for (int i = 0; i < 4; ++i)
#pragma unroll
          for (int j = 0; j < 4; ++j) acc[i][j] += a[i] * bj[j];
      }
    }
  }
  float rs[4], rq[4];
#pragma unroll
  for (int i = 0; i < 4; ++i) {
    size_t idx = (size_t)(row0 + r0 + i) * kC + c0;
    float4 xv = *reinterpret_cast<const float4*>(&x[idx]);
    float4 o = {acc[i][0] + xv.x, acc[i][1] + xv.y, acc[i][2] + xv.z, acc[i][3] + xv.w};
    *reinterpret_cast<float4*>(&z[idx]) = o;
    rs[i] = o.x + o.y + o.z + o.w;
    rq[i] = o.x * o.x + o.y * o.y + o.z * o.z + o.w * o.w;
  }
#pragma unroll
  for (int m = 1; m < 32; m <<= 1) {
#pragma unroll
    for (int i = 0; i < 4; ++i) { rs[i] += __shfl_xor(rs[i], m); rq[i] += __shfl_xor(rq[i], m); }
  }
  if (tc == 0) {
#pragma unroll
    for (int i = 0; i < 4; ++i) {
      sumz[row0 + r0 + i] = rs[i];
      sumzz[row0 + r0 + i] = rq[i];
    }
  }
}

// ---- 11. per-node BN (stats precomputed) + relu + dot(w_out) -> out ----
__global__ __launch_bounds__(256) void k_final(const float* __restrict__ z,
                                               const float* __restrict__ sumz,
                                               const float* __restrict__ sumzz,
                                               const float* __restrict__ g4,
                                               const float* __restrict__ b4v,
                                               const float* __restrict__ w_out,
                                               const float* __restrict__ b_out,
                                               float* __restrict__ out) {
  const int n = blockIdx.x;
  const int tid = threadIdx.x;
  __shared__ float sscale, sshift;
  if (tid < 16) {
    float a = sumz[tid * kN + n];
    float q = sumzz[tid * kN + n];
#pragma unroll
    for (int m = 1; m < 16; m <<= 1) { a += __shfl_xor(a, m); q += __shfl_xor(q, m); }
    if (tid == 0) {
      float mean = a * (1.f / 2048.f);
      float var = fmaxf(q * (1.f / 2048.f) - mean * mean, 0.f);
      float inv = rsqrtf(var + kEPS);
      float gg = g4[n];
      sscale = inv * gg;
      sshift = b4v[n] - mean * inv * gg;
    }
  }
  __syncthreads();
  const float scale = sscale, shift = sshift;
  const int b = tid >> 4, c0 = (tid & 15) * 8;
  float p = 0.f;
#pragma unroll
  for (int j = 0; j < 8; ++j) {
    float v = z[(size_t)(b * kN + n) * kC + c0 + j] * scale + shift;
    v = fmaxf(v, 0.f);
    p += v * w_out[c0 + j];
  }
  for (int o = 8; o > 0; o >>= 1) p += __shfl_down(p, o, 16);
  if ((tid & 15) == 0) out[b * kN + n] = p + b_out[0];
}

extern "C" void kernel_launch(void* const* d_in, const int* in_sizes, int n_in,
                              void* d_out, int out_size, void* d_ws, size_t ws_size,
                              hipStream_t stream) {
  const int*   data = (const int*)d_in[0];
  const float* node_features = (const float*)d_in[1];
  const float* go_adj = (const float*)d_in[2];
  const float* emb  = (const float*)d_in[4];
  const float* w_go = (const float*)d_in[5];
  const float* b_go = (const float*)d_in[6];
  const float* wq   = (const float*)d_in[7];
  const float* wk   = (const float*)d_in[8];
  const float* theta= (const float*)d_in[9];
  const float* g1   = (const float*)d_in[10];
  const float* b1   = (const float*)d_in[11];
  const float* g3   = (const float*)d_in[12];
  const float* b3   = (const float*)d_in[13];
  const float* g4   = (const float*)d_in[14];
  const float* b4   = (const float*)d_in[15];
  const float* w_out= (const float*)d_in[16];
  const float* b_out= (const float*)d_in[17];

  float* ws = (float*)d_ws;
  float* featpart = ws + OFF_FEATPART;
  float* m1t   = ws + OFF_M1;
  float* x     = ws + OFF_X;
  float* z     = ws + OFF_Z;
  float* tcur  = ws + OFF_TCUR;
  float* tnext = ws + OFF_TNEXT;
  float* gopart= ws + OFF_GOPART;
  float* psum  = ws + OFF_PSUM;
  float* sumz  = ws + OFF_SUMZ;
  float* sumzz = ws + OFF_SUMZZ;
  ushort* adj_hi = (ushort*)(ws + OFF_ADJH);
  ushort* adj_lo = (ushort*)(ws + OFF_ADJL);
  ushort* xt_hi  = (ushort*)(ws + OFF_XTH);
  ushort* xt_lo  = (ushort*)(ws + OFF_XTL);
  ushort* qh     = (ushort*)(ws + OFF_QH);
  ushort* ql     = (ushort*)(ws + OFF_QL);
  ushort* kh     = (ushort*)(ws + OFF_KH);
  ushort* kl     = (ushort*)(ws + OFF_KL);
  ushort* tth    = (ushort*)(ws + OFF_TTH);
  ushort* ttl    = (ushort*)(ws + OFF_TTL);

  k_embsum<<<dim3(16, 64), 256, 0, stream>>>(data, emb, featpart);
  k_bn_feat<<<16, 256, 0, stream>>>(featpart, data, g1, b1, m1t);
  k_go_gemm2<<<dim3(64, 8), 256, 0, stream>>>(m1t, w_go, gopart);
  k_go_bn<<<1024, 256, 0, stream>>>(gopart, b_go, node_features, g3, b3, x);
  k_qkgen<<<512, 256, 0, stream>>>(x, wq, wk, qh, ql, kh, kl);
  k_att_stats<<<dim3(16, 16, 2), 512, 0, stream>>>(qh, ql, kh, kl, psum);
  k_adj_emit<<<dim3(8, 16, 16), 512, 0, stream>>>(qh, ql, kh, kl, go_adj, psum,
                                                  adj_hi, adj_lo);
  k_transp<<<dim3(16, 16), 256, 0, stream>>>(x, xt_hi, xt_lo);
  k_adjmm_mfma<<<512, 256, 0, stream>>>(adj_hi, adj_lo, xt_hi, xt_lo,
                                        nullptr, tcur, 1.0f, tth, ttl);
  k_adjmm_mfma<<<512, 256, 0, stream>>>(adj_hi, adj_lo, tth, ttl,
                                        x, tnext, 2.0f, nullptr, nullptr);
  k_theta<<<512, 256, 0, stream>>>(x, tcur, tnext, theta, z, sumz, sumzz);
  k_final<<<1024, 256, 0, stream>>>(z, sumz, sumzz, g4, b4, w_out, b_out, (float*)d_out);
}

// Round 13
// 219.905 us; speedup vs baseline: 1.5251x; 1.5251x over previous
//
#include <hip/hip_runtime.h>

namespace {
constexpr int kB = 16;
constexpr int kMAXLEN = 1024;
constexpr int kPE = 256;
constexpr int kN = 1024;
constexpr int kEMB = 256;
constexpr int kC = 128;
constexpr float kEPS = 1e-5f;

// workspace offsets in floats
constexpr size_t OFF_FEATPART = 0;                         // 16*64*256 = 262144
constexpr size_t OFF_M1       = 262144;                    // 512*16
constexpr size_t OFF_X        = 270336;                    // 16*1024*128
constexpr size_t OFF_Z        = OFF_X    + 2097152;
constexpr size_t OFF_TCUR     = OFF_Z    + 2097152;
constexpr size_t OFF_TNEXT    = OFF_TCUR + 2097152;
constexpr size_t OFF_GOPART   = OFF_TNEXT+ 2097152;        // 4*16*65536 = 4194304
constexpr size_t OFF_PSUM     = OFF_GOPART + 4194304;      // 16*16*1024
constexpr size_t OFF_SUMZ     = OFF_PSUM + 262144;         // 16384
constexpr size_t OFF_SUMZZ    = OFF_SUMZ + 16384;          // 16384
constexpr size_t OFF_ADJH     = OFF_SUMZZ + 16384;
constexpr size_t OFF_ADJL     = OFF_ADJH + 8388608;
constexpr size_t OFF_XTH      = OFF_ADJL + 8388608;
constexpr size_t OFF_XTL      = OFF_XTH  + 1048576;
constexpr size_t OFF_QH       = OFF_XTL  + 1048576;
constexpr size_t OFF_QL       = OFF_QH   + 524288;
constexpr size_t OFF_KH       = OFF_QL   + 524288;
constexpr size_t OFF_KL       = OFF_KH   + 524288;
constexpr size_t OFF_TTH      = OFF_KL   + 524288;
constexpr size_t OFF_TTL      = OFF_TTH  + 1048576;

typedef __attribute__((ext_vector_type(8))) short bfrag;
typedef __attribute__((ext_vector_type(4))) float f32x4;

__device__ inline ushort f2bf(float f) {
  unsigned u = __float_as_uint(f);
  unsigned r = (u + 0x7FFFu + ((u >> 16) & 1u)) >> 16;  // RNE
  return (ushort)r;
}
__device__ inline float bf2f(ushort h) { return __uint_as_float(((unsigned)h) << 16); }
} // namespace

// ---- 1. embedding gather partial sums: featpart[b][chunk64][e] ----
__global__ __launch_bounds__(256) void k_embsum(const int* __restrict__ data,
                                                const float* __restrict__ emb,
                                                float* __restrict__ featpart) {
  const int b = blockIdx.x, ch = blockIdx.y;   // 16 x 64
  const int e = threadIdx.x;                   // 256
  const int* row = data + b * (kMAXLEN + kPE) + ch * 16;
  float acc = 0.f;
#pragma unroll 4
  for (int l = 0; l < 16; ++l) {
    acc += emb[(size_t)row[l] * kEMB + e];
  }
  featpart[((b * 64 + ch) << 8) + e] = acc;
}

// ---- 2. BN over batch -> m1t (512,16). 16 blocks x 32 j, 8 lanes/j ----
__global__ __launch_bounds__(256) void k_bn_feat(const float* __restrict__ featpart,
                                                 const int* __restrict__ data,
                                                 const float* __restrict__ g1,
                                                 const float* __restrict__ b1,
                                                 float* __restrict__ m1t) {
  const int tid = threadIdx.x;
  const int jl = tid >> 3, part = tid & 7;
  const int j = blockIdx.x * 32 + jl;
  float v[kB];
  if (j < kPE) {
#pragma unroll
    for (int b = 0; b < kB; ++b) {
      float s = 0.f;
      const int ch0 = part * 8;
#pragma unroll
      for (int ch = 0; ch < 8; ++ch)
        s += featpart[((b * 64 + ch0 + ch) << 8) + j];
      v[b] = s;
    }
  } else {
#pragma unroll
    for (int b = 0; b < kB; ++b)
      v[b] = (part == 0) ? (float)data[b * (kMAXLEN + kPE) + kMAXLEN + (j - kPE)] : 0.f;
  }
#pragma unroll
  for (int m = 1; m < 8; m <<= 1) {
#pragma unroll
    for (int b = 0; b < kB; ++b) v[b] += __shfl_xor(v[b], m);
  }
  const float pe = (j < kPE) ? sinf((float)j) : sinf((float)(j - kPE));
#pragma unroll
  for (int b = 0; b < kB; ++b)
    v[b] = (j < kPE) ? (v[b] * (1.f / 1024.f) + pe) : (v[b] + pe);
  float s = 0.f;
#pragma unroll
  for (int b = 0; b < kB; ++b) s += v[b];
  const float mean = s * (1.f / kB);
  float s2 = 0.f;
#pragma unroll
  for (int b = 0; b < kB; ++b) { float d = v[b] - mean; s2 += d * d; }
  const float inv = rsqrtf(s2 * (1.f / kB) + kEPS);
  if (part == 0) {
    const float g = g1[j], bb = b1[j];
    float o[kB];
#pragma unroll
    for (int b = 0; b < kB; ++b) o[b] = (v[b] - mean) * inv * g + bb;
#pragma unroll
    for (int q = 0; q < 4; ++q)
      *reinterpret_cast<float4*>(&m1t[j * kB + q * 4]) =
          *reinterpret_cast<float4*>(&o[q * 4]);
  }
}

// ---- 3a. split-K GEMM, 4 k-slices (m1t via SGPR broadcast) ----
__global__ __launch_bounds__(256) void k_go_gemm2(const float* __restrict__ m1t,
                                                  const float* __restrict__ w_go,
                                                  float* __restrict__ part) {
  const int c0 = blockIdx.x * 1024 + threadIdx.x * 4;
  const int k0 = blockIdx.y * 128;
  float4 acc[kB];
#pragma unroll
  for (int b = 0; b < kB; ++b) acc[b] = make_float4(0.f, 0.f, 0.f, 0.f);
#pragma unroll 4
  for (int k = 0; k < 128; ++k) {
    const float4 w = *reinterpret_cast<const float4*>(&w_go[(size_t)(k0 + k) * 65536 + c0]);
    const float* mrow = m1t + (size_t)(k0 + k) * kB;
#pragma unroll
    for (int b = 0; b < kB; ++b) {
      const float m = mrow[b];
      acc[b].x += m * w.x; acc[b].y += m * w.y;
      acc[b].z += m * w.z; acc[b].w += m * w.w;
    }
  }
  const size_t kb16 = (size_t)blockIdx.y * kB;
#pragma unroll
  for (int b = 0; b < kB; ++b) {
    *reinterpret_cast<float4*>(&part[(kb16 + b) * 65536 + c0]) = acc[b];
  }
}

// ---- 3b+4 fused. per-node: reduce 4 go partials + bias/relu, nf concat, BN -> x ----
__global__ __launch_bounds__(256) void k_go_bn(const float* __restrict__ part,
                                               const float* __restrict__ b_go,
                                               const float* __restrict__ nf,
                                               const float* __restrict__ g3,
                                               const float* __restrict__ b3,
                                               float* __restrict__ x) {
  const int n = blockIdx.x;
  const int tid = threadIdx.x;
  __shared__ float nfs[64];
  if (tid < 64) nfs[tid] = nf[n * 64 + tid];
  float val[4];
  float s = 0.f, s2 = 0.f;
#pragma unroll
  for (int i = 0; i < 4; ++i) {
    const int e = i * 256 + tid;
    const int b = e >> 6, c = e & 63;
    float a = part[(size_t)b * 65536 + n * 64 + c];
#pragma unroll
    for (int kb = 1; kb < 4; ++kb)
      a += part[(size_t)(kb * kB + b) * 65536 + n * 64 + c];
    a = fmaxf(a + b_go[n * 64 + c], 0.f);
    val[i] = a;
    s += a; s2 += a * a;
  }
  __syncthreads();
  if (tid < 64) {
    const float v = nfs[tid];
    s += 16.f * v; s2 += 16.f * v * v;
  }
  for (int o = 32; o > 0; o >>= 1) { s += __shfl_down(s, o); s2 += __shfl_down(s2, o); }
  __shared__ float ls[4], ls2[4];
  __shared__ float sscale, sshift;
  const int w = tid >> 6;
  if ((tid & 63) == 0) { ls[w] = s; ls2[w] = s2; }
  __syncthreads();
  if (tid == 0) {
    float S = ls[0] + ls[1] + ls[2] + ls[3];
    float S2 = ls2[0] + ls2[1] + ls2[2] + ls2[3];
    float mean = S * (1.f / 2048.f);
    float var = fmaxf(S2 * (1.f / 2048.f) - mean * mean, 0.f);
    float inv = rsqrtf(var + kEPS);
    float gg = g3[n];
    sscale = inv * gg;
    sshift = b3[n] - mean * inv * gg;
  }
  __syncthreads();
  const float scale = sscale, shift = sshift;
#pragma unroll
  for (int i = 0; i < 4; ++i) {
    const int e = i * 256 + tid;
    const int b = e >> 6, c = e & 63;
    x[((size_t)(b * kN + n)) * kC + c] = val[i] * scale + shift;
  }
#pragma unroll
  for (int i = 0; i < 4; ++i) {
    const int e = i * 256 + tid;
    const int b = e >> 6, c = e & 63;
    x[((size_t)(b * kN + n)) * kC + 64 + c] = nfs[c] * scale + shift;
  }
}

// ---- 5. q/k projections -> bf16 hi/lo, [bn][64] layout ----
__global__ __launch_bounds__(256) void k_qkgen(const float* __restrict__ x,
                                               const float* __restrict__ wq,
                                               const float* __restrict__ wk,
                                               ushort* __restrict__ qh, ushort* __restrict__ ql,
                                               ushort* __restrict__ kh, ushort* __restrict__ kl) {
  __shared__ float a_s[32 * 68];
  __shared__ float w_s[32 * 128];
  const int row0 = blockIdx.x * 32;
  const int tid = threadIdx.x;
  const int tr = tid >> 5, tc = tid & 31;
  const int r0 = tr * 4, c0 = tc * 4;
  float acc[4][4] = {};
  for (int kc = 0; kc < 4; ++kc) {
    const int k0 = kc * 32;
    __syncthreads();
    {
      int r = tid >> 3, kk4 = tid & 7;
      float4 v = *reinterpret_cast<const float4*>(&x[(size_t)(row0 + r) * kC + k0 + kk4 * 4]);
      *reinterpret_cast<float4*>(&a_s[r * 68 + kk4 * 4]) = v;
    }
    for (int it = 0; it < 16; ++it) {
      int e = it * 256 + tid;
      int kk = e >> 7, h2 = e & 127;
      int c = k0 + kk;
      float v = (h2 < 64) ? wq[c * 64 + h2] : wk[c * 64 + (h2 - 64)];
      w_s[kk * 128 + h2] = v;
    }
    __syncthreads();
#pragma unroll 8
    for (int k = 0; k < 32; ++k) {
      float a[4];
#pragma unroll
      for (int i = 0; i < 4; ++i) a[i] = a_s[(r0 + i) * 68 + k];
      float4 b4 = *reinterpret_cast<float4*>(&w_s[k * 128 + c0]);
      float bj[4] = {b4.x, b4.y, b4.z, b4.w};
#pragma unroll
      for (int i = 0; i < 4; ++i)
#pragma unroll
        for (int j = 0; j < 4; ++j) acc[i][j] += a[i] * bj[j];
    }
  }
  const bool isq = (c0 < 64);
  const int h0 = isq ? c0 : (c0 - 64);
  ushort* oh = isq ? qh : kh;
  ushort* ol = isq ? ql : kl;
#pragma unroll
  for (int i = 0; i < 4; ++i) {
    ushort hs[4], ls[4];
#pragma unroll
    for (int j = 0; j < 4; ++j) {
      float v = acc[i][j];
      ushort h = f2bf(v);
      hs[j] = h;
      ls[j] = f2bf(v - bf2f(h));
    }
    const size_t o = (size_t)(row0 + r0 + i) * 64 + h0;
    *reinterpret_cast<ushort4*>(&oh[o]) = *reinterpret_cast<ushort4*>(hs);
    *reinterpret_cast<ushort4*>(&ol[o]) = *reinterpret_cast<ushort4*>(ls);
  }
}

// ---- 6. att sum-stats via MFMA (no max; logits bounded), mc-split over blockIdx.z ----
__global__ __launch_bounds__(512) void k_att_stats(const ushort* __restrict__ qh,
                                                   const ushort* __restrict__ ql,
                                                   const ushort* __restrict__ kh,
                                                   const ushort* __restrict__ kl,
                                                   float* __restrict__ psum) {
  const int nt = blockIdx.x, b = blockIdx.y;
  const int mc0 = blockIdx.z * 4;  // 2 halves x 4 chunks
  __shared__ uint4 smem4[3072];  // 48 KiB: Qh@0 Ql@8K Kh@16K Kl@32K
  char* smem = (char*)smem4;
  const int tid = threadIdx.x;
  const int lane = tid & 63, w = tid >> 6;
  const int l15 = lane & 15, lg = lane >> 4;

  {  // stage Q once
    const int r = tid >> 3, ch = tid & 7;
    const size_t g = (size_t)(b * kN + nt * 64 + r) * 64 + ch * 8;
    const unsigned off = (unsigned)(r * 128 + ch * 16) ^ (unsigned)((r & 7) << 4);
    *reinterpret_cast<uint4*>(smem + off) = *reinterpret_cast<const uint4*>(qh + g);
    *reinterpret_cast<uint4*>(smem + 8192 + off) = *reinterpret_cast<const uint4*>(ql + g);
  }

  const int c0s = tid >> 3, c1s = 64 + (tid >> 3);
  const int chs = tid & 7;
  const unsigned offK0 = (unsigned)(c0s * 128 + chs * 16) ^ (unsigned)((c0s & 7) << 4);
  const unsigned offK1 = (unsigned)(c1s * 128 + chs * 16) ^ (unsigned)((c1s & 7) << 4);
  const size_t gK0 = (size_t)(b * kN + mc0 * 128 + c0s) * 64 + chs * 8;
  const size_t gK1 = (size_t)(b * kN + mc0 * 128 + c1s) * 64 + chs * 8;

  uint4 ph0 = *reinterpret_cast<const uint4*>(kh + gK0);
  uint4 ph1 = *reinterpret_cast<const uint4*>(kh + gK1);
  uint4 pl0 = *reinterpret_cast<const uint4*>(kl + gK0);
  uint4 pl1 = *reinterpret_cast<const uint4*>(kl + gK1);

  for (int it = 0; it < 4; ++it) {
    const int mc = mc0 + it;
    __syncthreads();
    *reinterpret_cast<uint4*>(smem + 16384 + offK0) = ph0;
    *reinterpret_cast<uint4*>(smem + 16384 + offK1) = ph1;
    *reinterpret_cast<uint4*>(smem + 32768 + offK0) = pl0;
    *reinterpret_cast<uint4*>(smem + 32768 + offK1) = pl1;
    __syncthreads();
    if (it < 3) {
      const size_t k1 = (size_t)(it + 1) * 128 * 64;
      ph0 = *reinterpret_cast<const uint4*>(kh + gK0 + k1);
      ph1 = *reinterpret_cast<const uint4*>(kh + gK1 + k1);
      pl0 = *reinterpret_cast<const uint4*>(kl + gK0 + k1);
      pl1 = *reinterpret_cast<const uint4*>(kl + gK1 + k1);
    }
    f32x4 acc[4] = {{0.f,0.f,0.f,0.f},{0.f,0.f,0.f,0.f},{0.f,0.f,0.f,0.f},{0.f,0.f,0.f,0.f}};
#pragma unroll
    for (int ss = 0; ss < 2; ++ss) {
      const int r = w * 16 + l15;
      const unsigned aoff = (unsigned)(r * 128 + ss * 64 + lg * 16) ^ (unsigned)((r & 7) << 4);
      bfrag ah = *reinterpret_cast<const bfrag*>(smem + 16384 + aoff);
      bfrag al = *reinterpret_cast<const bfrag*>(smem + 32768 + aoff);
#pragma unroll
      for (int nf = 0; nf < 4; ++nf) {
        const int c = nf * 16 + l15;
        const unsigned boff = (unsigned)(c * 128 + ss * 64 + lg * 16) ^ (unsigned)((c & 7) << 4);
        bfrag bh = *reinterpret_cast<const bfrag*>(smem + boff);
        bfrag bl = *reinterpret_cast<const bfrag*>(smem + 8192 + boff);
        acc[nf] = __builtin_amdgcn_mfma_f32_16x16x32_bf16(ah, bh, acc[nf], 0, 0, 0);
        acc[nf] = __builtin_amdgcn_mfma_f32_16x16x32_bf16(ah, bl, acc[nf], 0, 0, 0);
        acc[nf] = __builtin_amdgcn_mfma_f32_16x16x32_bf16(al, bh, acc[nf], 0, 0, 0);
      }
    }
#pragma unroll
    for (int i = 0; i < 4; ++i) {
      float sm = __expf(acc[0][i] * 0.125f) + __expf(acc[1][i] * 0.125f)
               + __expf(acc[2][i] * 0.125f) + __expf(acc[3][i] * 0.125f);
#pragma unroll
      for (int msk = 1; msk < 16; msk <<= 1) sm += __shfl_xor(sm, msk);
      if (l15 == 0) {
        const int m = mc * 128 + w * 16 + lg * 4 + i;
        psum[(size_t)(b * 16 + nt) * kN + m] = sm;
      }
    }
  }
}

// ---- 8. adj emit: recompute Q·K^T, adj = go_adj + exp(s/8)*cinv (cinv inline) ----
__global__ __launch_bounds__(512) void k_adj_emit(const ushort* __restrict__ qh,
                                                  const ushort* __restrict__ ql,
                                                  const ushort* __restrict__ kh,
                                                  const ushort* __restrict__ kl,
                                                  const float* __restrict__ go_adj,
                                                  const float* __restrict__ psum,
                                                  ushort* __restrict__ adj_hi,
                                                  ushort* __restrict__ adj_lo) {
  const int mc = blockIdx.x, nt = blockIdx.y, b = blockIdx.z;
  __shared__ uint4 smem4[3072];
  __shared__ float cinvs[128];
  char* smem = (char*)smem4;
  float* c32 = (float*)smem4;
  const int tid = threadIdx.x;
  const int lane = tid & 63, w = tid >> 6;
  const int wr = w >> 2, wc = w & 3;
  const int l15 = lane & 15, lg = lane >> 4;

  if (tid < 128) {
    const int m = mc * 128 + tid;
    float S = 0.f;
#pragma unroll
    for (int c = 0; c < 16; ++c) S += psum[(size_t)(b * 16 + c) * kN + m];
    cinvs[tid] = 1.f / S;
  }
  {
    const int r = tid >> 3, ch = tid & 7;
    const size_t g = (size_t)(b * kN + nt * 64 + r) * 64 + ch * 8;
    const unsigned off = (unsigned)(r * 128 + ch * 16) ^ (unsigned)((r & 7) << 4);
    *reinterpret_cast<uint4*>(smem + off) = *reinterpret_cast<const uint4*>(qh + g);
    *reinterpret_cast<uint4*>(smem + 8192 + off) = *reinterpret_cast<const uint4*>(ql + g);
  }
#pragma unroll
  for (int p = 0; p < 2; ++p) {
    const int e = p * 512 + tid;
    const int c = e >> 3, ch = e & 7;
    const size_t g = (size_t)(b * kN + mc * 128 + c) * 64 + ch * 8;
    const unsigned off = (unsigned)(c * 128 + ch * 16) ^ (unsigned)((c & 7) << 4);
    *reinterpret_cast<uint4*>(smem + 16384 + off) = *reinterpret_cast<const uint4*>(kh + g);
    *reinterpret_cast<uint4*>(smem + 32768 + off) = *reinterpret_cast<const uint4*>(kl + g);
  }
  __syncthreads();
  f32x4 acc[2][2] = {{{0.f,0.f,0.f,0.f},{0.f,0.f,0.f,0.f}},
                     {{0.f,0.f,0.f,0.f},{0.f,0.f,0.f,0.f}}};
#pragma unroll
  for (int ss = 0; ss < 2; ++ss) {
    bfrag ah[2], al[2], bh[2], bl[2];
#pragma unroll
    for (int nf = 0; nf < 2; ++nf) {
      const int r = wr * 32 + nf * 16 + l15;
      const unsigned aoff = (unsigned)(r * 128 + ss * 64 + lg * 16) ^ (unsigned)((r & 7) << 4);
      ah[nf] = *reinterpret_cast<const bfrag*>(smem + aoff);
      al[nf] = *reinterpret_cast<const bfrag*>(smem + 8192 + aoff);
    }
#pragma unroll
    for (int mf = 0; mf < 2; ++mf) {
      const int c = wc * 32 + mf * 16 + l15;
      const unsigned boff = (unsigned)(c * 128 + ss * 64 + lg * 16) ^ (unsigned)((c & 7) << 4);
      bh[mf] = *reinterpret_cast<const bfrag*>(smem + 16384 + boff);
      bl[mf] = *reinterpret_cast<const bfrag*>(smem + 32768 + boff);
    }
#pragma unroll
    for (int nf = 0; nf < 2; ++nf)
#pragma unroll
      for (int mf = 0; mf < 2; ++mf) {
        acc[nf][mf] = __builtin_amdgcn_mfma_f32_16x16x32_bf16(ah[nf], bh[mf], acc[nf][mf], 0, 0, 0);
        acc[nf][mf] = __builtin_amdgcn_mfma_f32_16x16x32_bf16(ah[nf], bl[mf], acc[nf][mf], 0, 0, 0);
        acc[nf][mf] = __builtin_amdgcn_mfma_f32_16x16x32_bf16(al[nf], bh[mf], acc[nf][mf], 0, 0, 0);
      }
  }
  __syncthreads();
#pragma unroll
  for (int mf = 0; mf < 2; ++mf) {
    const int mLoc = wc * 32 + mf * 16 + l15;
    const float I = cinvs[mLoc];
#pragma unroll
    for (int nf = 0; nf < 2; ++nf) {
#pragma unroll
      for (int i = 0; i < 4; ++i) {
        const int nLoc = wr * 32 + nf * 16 + lg * 4 + i;
        c32[nLoc * 132 + mLoc] = __expf(acc[nf][mf][i] * 0.125f) * I;
      }
    }
  }
  __syncthreads();
#pragma unroll
  for (int p = 0; p < 2; ++p) {
    const int e = p * 512 + tid;
    const int n = e >> 4, m0 = (e & 15) * 8;
    const float* cr = &c32[n * 132 + m0];
    const float* ga = &go_adj[(size_t)(nt * 64 + n) * kN + mc * 128 + m0];
    ushort hs[8], ls[8];
#pragma unroll
    for (int j = 0; j < 8; ++j) {
      float v = cr[j] + ga[j];
      ushort h = f2bf(v);
      hs[j] = h;
      ls[j] = f2bf(v - bf2f(h));
    }
    const size_t o = (size_t)(b * kN + nt * 64 + n) * kN + mc * 128 + m0;
    *reinterpret_cast<uint4*>(&adj_hi[o]) = *reinterpret_cast<uint4*>(hs);
    *reinterpret_cast<uint4*>(&adj_lo[o]) = *reinterpret_cast<uint4*>(ls);
  }
}

// ---- T. transpose+split: f32 [16][1024][128] -> bf16 hi/lo [16][128][1024] ----
__global__ __launch_bounds__(256) void k_transp(const float* __restrict__ src,
                                                ushort* __restrict__ xt_hi,
                                                ushort* __restrict__ xt_lo) {
  const int nt = blockIdx.x, b = blockIdx.y;
  __shared__ float tile[64][133];
  const int tid = threadIdx.x;
#pragma unroll
  for (int it = 0; it < 8; ++it) {
    int e = it * 256 + tid;
    int r = e >> 5, c4 = e & 31;
    float4 v = *reinterpret_cast<const float4*>(&src[(size_t)(b * kN + nt * 64 + r) * kC + c4 * 4]);
    *reinterpret_cast<float4*>(&tile[r][c4 * 4]) = v;
  }
  __syncthreads();
  const int cl = tid >> 3;
  const int chunk = tid & 7;
  const int n0 = chunk * 8;
#pragma unroll
  for (int cg = 0; cg < 4; ++cg) {
    const int c = cg * 32 + cl;
    const size_t obase = (size_t)(b * kC + c) * kN + nt * 64 + n0;
    ushort hs[8], ls[8];
#pragma unroll
    for (int j = 0; j < 8; ++j) {
      float v = tile[n0 + j][c];
      ushort h = f2bf(v);
      hs[j] = h;
      ls[j] = f2bf(v - bf2f(h));
    }
    *reinterpret_cast<uint4*>(&xt_hi[obase]) = *reinterpret_cast<uint4*>(hs);
    *reinterpret_cast<uint4*>(&xt_lo[obase]) = *reinterpret_cast<uint4*>(ls);
  }
}

// ---- 9. Y = alpha * adj @ X (- Zsub); BM=64, grid 256, T14 prefetch ----
__global__ __launch_bounds__(512) void k_adjmm_mfma(const ushort* __restrict__ adj_hi,
                                                    const ushort* __restrict__ adj_lo,
                                                    const ushort* __restrict__ xt_hi,
                                                    const ushort* __restrict__ xt_lo,
                                                    const float* __restrict__ Zsub,
                                                    float* __restrict__ Y, float alpha,
                                                    ushort* __restrict__ yt_hi,
                                                    ushort* __restrict__ yt_lo) {
  const int bid = blockIdx.x;
  const int swz = (bid & 7) * 32 + (bid >> 3);
  const int b = swz >> 4, rb = swz & 15;
  __shared__ uint4 smem4[3072];
  char* smem = (char*)smem4;
  float* c32 = (float*)smem4;
  const int tid = threadIdx.x;
  const int lane = tid & 63, w = tid >> 6;
  const int wr = w >> 1, wc = w & 1;
  const int l15 = lane & 15, lg = lane >> 4;

  const int ra = tid >> 3, cha = tid & 7;
  const unsigned offA = (unsigned)(ra * 128 + cha * 16) ^ (unsigned)((ra & 7) << 4);
  const size_t gA = ((size_t)(b * kN + rb * 64 + ra)) * kN + cha * 8;
  const int cb0 = tid >> 3, cb1 = 64 + (tid >> 3);
  const unsigned offB0 = (unsigned)(cb0 * 128 + cha * 16) ^ (unsigned)((cb0 & 7) << 4);
  const unsigned offB1 = (unsigned)(cb1 * 128 + cha * 16) ^ (unsigned)((cb1 & 7) << 4);
  const size_t gB0 = ((size_t)b * kC + cb0) * kN + cha * 8;
  const size_t gB1 = ((size_t)b * kC + cb1) * kN + cha * 8;

  f32x4 acc[4] = {{0.f,0.f,0.f,0.f},{0.f,0.f,0.f,0.f},{0.f,0.f,0.f,0.f},{0.f,0.f,0.f,0.f}};

  uint4 pah  = *reinterpret_cast<const uint4*>(adj_hi + gA);
  uint4 pal  = *reinterpret_cast<const uint4*>(adj_lo + gA);
  uint4 pbh0 = *reinterpret_cast<const uint4*>(xt_hi + gB0);
  uint4 pbl0 = *reinterpret_cast<const uint4*>(xt_lo + gB0);
  uint4 pbh1 = *reinterpret_cast<const uint4*>(xt_hi + gB1);
  uint4 pbl1 = *reinterpret_cast<const uint4*>(xt_lo + gB1);

  for (int kt = 0; kt < 16; ++kt) {
    __syncthreads();
    *reinterpret_cast<uint4*>(smem + offA)          = pah;
    *reinterpret_cast<uint4*>(smem + 8192 + offA)   = pal;
    *reinterpret_cast<uint4*>(smem + 16384 + offB0) = pbh0;
    *reinterpret_cast<uint4*>(smem + 32768 + offB0) = pbl0;
    *reinterpret_cast<uint4*>(smem + 16384 + offB1) = pbh1;
    *reinterpret_cast<uint4*>(smem + 32768 + offB1) = pbl1;
    __syncthreads();
    if (kt < 15) {
      const int k1 = (kt + 1) * 64;
      pah  = *reinterpret_cast<const uint4*>(adj_hi + gA + k1);
      pal  = *reinterpret_cast<const uint4*>(adj_lo + gA + k1);
      pbh0 = *reinterpret_cast<const uint4*>(xt_hi + gB0 + k1);
      pbl0 = *reinterpret_cast<const uint4*>(xt_lo + gB0 + k1);
      pbh1 = *reinterpret_cast<const uint4*>(xt_hi + gB1 + k1);
      pbl1 = *reinterpret_cast<const uint4*>(xt_lo + gB1 + k1);
    }
#pragma unroll
    for (int ss = 0; ss < 2; ++ss) {
      const int r = wr * 16 + l15;
      const unsigned aoff = (unsigned)(r * 128 + ss * 64 + lg * 16) ^ (unsigned)((r & 7) << 4);
      bfrag ah = *reinterpret_cast<const bfrag*>(smem + aoff);
      bfrag al = *reinterpret_cast<const bfrag*>(smem + 8192 + aoff);
      bfrag bh[4], bl[4];
#pragma unroll
      for (int ct = 0; ct < 4; ++ct) {
        const int c = wc * 64 + ct * 16 + l15;
        const unsigned boff = (unsigned)(c * 128 + ss * 64 + lg * 16) ^ (unsigned)((c & 7) << 4);
        bh[ct] = *reinterpret_cast<const bfrag*>(smem + 16384 + boff);
        bl[ct] = *reinterpret_cast<const bfrag*>(smem + 32768 + boff);
      }
#pragma unroll
      for (int ct = 0; ct < 4; ++ct) {
        acc[ct] = __builtin_amdgcn_mfma_f32_16x16x32_bf16(ah, bh[ct], acc[ct], 0, 0, 0);
        acc[ct] = __builtin_amdgcn_mfma_f32_16x16x32_bf16(ah, bl[ct], acc[ct], 0, 0, 0);
        acc[ct] = __builtin_amdgcn_mfma_f32_16x16x32_bf16(al, bh[ct], acc[ct], 0, 0, 0);
      }
    }
  }
  const int orow = rb * 64 + wr * 16 + lg * 4;
  __syncthreads();
#pragma unroll
  for (int ct = 0; ct < 4; ++ct) {
    const int ocol = wc * 64 + ct * 16 + l15;
#pragma unroll
    for (int i = 0; i < 4; ++i) {
      const size_t idx = ((size_t)(b * kN + orow + i)) * kC + ocol;
      float v = alpha * acc[ct][i];
      if (Zsub) v -= Zsub[idx];
      Y[idx] = v;
      if (yt_hi) c32[(wr * 16 + lg * 4 + i) * 132 + ocol] = v;
    }
  }
  if (yt_hi) {
    __syncthreads();
    const int c = tid >> 2, nch = tid & 3;
    const int n0 = nch * 16;
    ushort hs[16], ls[16];
#pragma unroll
    for (int j = 0; j < 16; ++j) {
      float v = c32[(n0 + j) * 132 + c];
      ushort h = f2bf(v);
      hs[j] = h;
      ls[j] = f2bf(v - bf2f(h));
    }
    const size_t obase = (size_t)(b * kC + c) * kN + rb * 64 + n0;
    *reinterpret_cast<uint4*>(&yt_hi[obase]) = *reinterpret_cast<uint4*>(hs);
    *reinterpret_cast<uint4*>(&yt_hi[obase + 8]) = *reinterpret_cast<uint4*>(hs + 8);
    *reinterpret_cast<uint4*>(&yt_lo[obase]) = *reinterpret_cast<uint4*>(ls);
    *reinterpret_cast<uint4*>(&yt_lo[obase + 8]) = *reinterpret_cast<uint4*>(ls + 8);
  }
}

// ---- 10. z = x@th0 + tcur@th1 + tnext@th2 + x ; emits per-row sum/sumsq ----
__global__ __launch_bounds__(256) void k_theta(const float* __restrict__ x,
                                               const float* __restrict__ tcur,
                                               const float* __restrict__ tnext,
                                               const float* __restrict__ theta,
                                               float* __restrict__ z,
                                               float* __restrict__ sumz,
                                               float* __restrict__ sumzz) {
  __shared__ float a_s[32 * 68];
  __shared__ float w_s[32 * 128];
  const int row0 = blockIdx.x * 32;
  const int tid = threadIdx.x;
  const int tr = tid >> 5, tc = tid & 31;
  const int r0 = tr * 4, c0 = tc * 4;
  float acc[4][4] = {};
  const float* srcs[3] = {x, tcur, tnext};
  for (int s = 0; s < 3; ++s) {
    const float* A = srcs[s];
    for (int kc = 0; kc < 4; ++kc) {
      const int k0 = kc * 32;
      __syncthreads();
      {
        int r = tid >> 3, kk4 = tid & 7;
        float4 v = *reinterpret_cast<const float4*>(&A[(size_t)(row0 + r) * kC + k0 + kk4 * 4]);
        *reinterpret_cast<float4*>(&a_s[r * 68 + kk4 * 4]) = v;
      }
#pragma unroll
      for (int it = 0; it < 4; ++it) {
        int e4 = it * 256 + tid;
        int kk = e4 >> 5, d4 = e4 & 31;
        float4 v = *reinterpret_cast<const float4*>(
            &theta[(size_t)s * 16384 + (size_t)(k0 + kk) * kC + d4 * 4]);
        *reinterpret_cast<float4*>(&w_s[kk * 128 + d4 * 4]) = v;
      }
      __syncthreads();
#pragma unroll 8
      for (int k = 0; k < 32; ++k) {
        float a[4];
#pragma unroll
        for (int i = 0; i < 4; ++i) a[i] = a_s[(r0 + i) * 68 + k];
        float4 b4 = *reinterpret_cast<float4*>(&w_s[k * 128 + c0]);
        float bj[4] = {b4.x, b4.y, b4.z, b4.w};
#pragma unroll
        for (int i = 0; i < 4; ++i)
#pragma unroll
          for (int j = 0; j < 4; ++j) acc[i][j] += a[i] * bj[j];
      }
    }
  }
  float rs[4], rq[4];
#pragma unroll
  for (int i = 0; i < 4; ++i) {
    size_t idx = (size_t)(row0 + r0 + i) * kC + c0;
    float4 xv = *reinterpret_cast<const float4*>(&x[idx]);
    float4 o = {acc[i][0] + xv.x, acc[i][1] + xv.y, acc[i][2] + xv.z, acc[i][3] + xv.w};
    *reinterpret_cast<float4*>(&z[idx]) = o;
    rs[i] = o.x + o.y + o.z + o.w;
    rq[i] = o.x * o.x + o.y * o.y + o.z * o.z + o.w * o.w;
  }
#pragma unroll
  for (int m = 1; m < 32; m <<= 1) {
#pragma unroll
    for (int i = 0; i < 4; ++i) { rs[i] += __shfl_xor(rs[i], m); rq[i] += __shfl_xor(rq[i], m); }
  }
  if (tc == 0) {
#pragma unroll
    for (int i = 0; i < 4; ++i) {
      sumz[row0 + r0 + i] = rs[i];
      sumzz[row0 + r0 + i] = rq[i];
    }
  }
}

// ---- 11. per-node BN (stats precomputed) + relu + dot(w_out) -> out ----
__global__ __launch_bounds__(256) void k_final(const float* __restrict__ z,
                                               const float* __restrict__ sumz,
                                               const float* __restrict__ sumzz,
                                               const float* __restrict__ g4,
                                               const float* __restrict__ b4v,
                                               const float* __restrict__ w_out,
                                               const float* __restrict__ b_out,
                                               float* __restrict__ out) {
  const int n = blockIdx.x;
  const int tid = threadIdx.x;
  __shared__ float sscale, sshift;
  if (tid < 16) {
    float a = sumz[tid * kN + n];
    float q = sumzz[tid * kN + n];
#pragma unroll
    for (int m = 1; m < 16; m <<= 1) { a += __shfl_xor(a, m); q += __shfl_xor(q, m); }
    if (tid == 0) {
      float mean = a * (1.f / 2048.f);
      float var = fmaxf(q * (1.f / 2048.f) - mean * mean, 0.f);
      float inv = rsqrtf(var + kEPS);
      float gg = g4[n];
      sscale = inv * gg;
      sshift = b4v[n] - mean * inv * gg;
    }
  }
  __syncthreads();
  const float scale = sscale, shift = sshift;
  const int b = tid >> 4, c0 = (tid & 15) * 8;
  float p = 0.f;
#pragma unroll
  for (int j = 0; j < 8; ++j) {
    float v = z[(size_t)(b * kN + n) * kC + c0 + j] * scale + shift;
    v = fmaxf(v, 0.f);
    p += v * w_out[c0 + j];
  }
  for (int o = 8; o > 0; o >>= 1) p += __shfl_down(p, o, 16);
  if ((tid & 15) == 0) out[b * kN + n] = p + b_out[0];
}

extern "C" void kernel_launch(void* const* d_in, const int* in_sizes, int n_in,
                              void* d_out, int out_size, void* d_ws, size_t ws_size,
                              hipStream_t stream) {
  const int*   data = (const int*)d_in[0];
  const float* node_features = (const float*)d_in[1];
  const float* go_adj = (const float*)d_in[2];
  const float* emb  = (const float*)d_in[4];
  const float* w_go = (const float*)d_in[5];
  const float* b_go = (const float*)d_in[6];
  const float* wq   = (const float*)d_in[7];
  const float* wk   = (const float*)d_in[8];
  const float* theta= (const float*)d_in[9];
  const float* g1   = (const float*)d_in[10];
  const float* b1   = (const float*)d_in[11];
  const float* g3   = (const float*)d_in[12];
  const float* b3   = (const float*)d_in[13];
  const float* g4   = (const float*)d_in[14];
  const float* b4   = (const float*)d_in[15];
  const float* w_out= (const float*)d_in[16];
  const float* b_out= (const float*)d_in[17];

  float* ws = (float*)d_ws;
  float* featpart = ws + OFF_FEATPART;
  float* m1t   = ws + OFF_M1;
  float* x     = ws + OFF_X;
  float* z     = ws + OFF_Z;
  float* tcur  = ws + OFF_TCUR;
  float* tnext = ws + OFF_TNEXT;
  float* gopart= ws + OFF_GOPART;
  float* psum  = ws + OFF_PSUM;
  float* sumz  = ws + OFF_SUMZ;
  float* sumzz = ws + OFF_SUMZZ;
  ushort* adj_hi = (ushort*)(ws + OFF_ADJH);
  ushort* adj_lo = (ushort*)(ws + OFF_ADJL);
  ushort* xt_hi  = (ushort*)(ws + OFF_XTH);
  ushort* xt_lo  = (ushort*)(ws + OFF_XTL);
  ushort* qh     = (ushort*)(ws + OFF_QH);
  ushort* ql     = (ushort*)(ws + OFF_QL);
  ushort* kh     = (ushort*)(ws + OFF_KH);
  ushort* kl     = (ushort*)(ws + OFF_KL);
  ushort* tth    = (ushort*)(ws + OFF_TTH);
  ushort* ttl    = (ushort*)(ws + OFF_TTL);

  k_embsum<<<dim3(16, 64), 256, 0, stream>>>(data, emb, featpart);
  k_bn_feat<<<16, 256, 0, stream>>>(featpart, data, g1, b1, m1t);
  k_go_gemm2<<<dim3(64, 4), 256, 0, stream>>>(m1t, w_go, gopart);
  k_go_bn<<<1024, 256, 0, stream>>>(gopart, b_go, node_features, g3, b3, x);
  k_qkgen<<<512, 256, 0, stream>>>(x, wq, wk, qh, ql, kh, kl);
  k_att_stats<<<dim3(16, 16, 2), 512, 0, stream>>>(qh, ql, kh, kl, psum);
  k_adj_emit<<<dim3(8, 16, 16), 512, 0, stream>>>(qh, ql, kh, kl, go_adj, psum,
                                                  adj_hi, adj_lo);
  k_transp<<<dim3(16, 16), 256, 0, stream>>>(x, xt_hi, xt_lo);
  k_adjmm_mfma<<<256, 512, 0, stream>>>(adj_hi, adj_lo, xt_hi, xt_lo,
                                        nullptr, tcur, 1.0f, tth, ttl);
  k_adjmm_mfma<<<256, 512, 0, stream>>>(adj_hi, adj_lo, tth, ttl,
                                        x, tnext, 2.0f, nullptr, nullptr);
  k_theta<<<512, 256, 0, stream>>>(x, tcur, tnext, theta, z, sumz, sumzz);
  k_final<<<1024, 256, 0, stream>>>(z, sumz, sumzz, g4, b4, w_out, b_out, (float*)d_out);
}

// Round 14
// 184.336 us; speedup vs baseline: 1.8193x; 1.1930x over previous
//
#include <hip/hip_runtime.h>

namespace {
constexpr int kB = 16;
constexpr int kMAXLEN = 1024;
constexpr int kPE = 256;
constexpr int kN = 1024;
constexpr int kEMB = 256;
constexpr int kC = 128;
constexpr float kEPS = 1e-5f;

// workspace offsets in floats
constexpr size_t OFF_FEATPART = 0;                         // 16*64*256 = 262144
constexpr size_t OFF_M1       = 262144;                    // 512*16
constexpr size_t OFF_X        = 270336;                    // 16*1024*128
constexpr size_t OFF_Z        = OFF_X    + 2097152;
constexpr size_t OFF_TCUR     = OFF_Z    + 2097152;
constexpr size_t OFF_TNEXT    = OFF_TCUR + 2097152;
constexpr size_t OFF_GOPART   = OFF_TNEXT+ 2097152;        // 4*16*65536
constexpr size_t OFF_PSUM     = OFF_GOPART + 4194304;      // 16*16*1024
constexpr size_t OFF_SUMZ     = OFF_PSUM + 262144;
constexpr size_t OFF_SUMZZ    = OFF_SUMZ + 16384;
constexpr size_t OFF_ADJ      = OFF_SUMZZ + 16384;         // 16.8M bf16 = 8388608 fl
constexpr size_t OFF_XT       = OFF_ADJ  + 8388608;        // 2M bf16
constexpr size_t OFF_Q        = OFF_XT   + 1048576;        // 1M bf16
constexpr size_t OFF_K        = OFF_Q    + 524288;
constexpr size_t OFF_TT       = OFF_K    + 524288;         // tcur^T bf16

typedef __attribute__((ext_vector_type(8))) short bfrag;
typedef __attribute__((ext_vector_type(4))) float f32x4;

__device__ inline ushort f2bf(float f) {
  unsigned u = __float_as_uint(f);
  unsigned r = (u + 0x7FFFu + ((u >> 16) & 1u)) >> 16;  // RNE
  return (ushort)r;
}
} // namespace

// ---- 1. embedding gather partial sums: featpart[b][chunk64][e] ----
__global__ __launch_bounds__(256) void k_embsum(const int* __restrict__ data,
                                                const float* __restrict__ emb,
                                                float* __restrict__ featpart) {
  const int b = blockIdx.x, ch = blockIdx.y;   // 16 x 64
  const int e = threadIdx.x;                   // 256
  const int* row = data + b * (kMAXLEN + kPE) + ch * 16;
  float acc = 0.f;
#pragma unroll 4
  for (int l = 0; l < 16; ++l) {
    acc += emb[(size_t)row[l] * kEMB + e];
  }
  featpart[((b * 64 + ch) << 8) + e] = acc;
}

// ---- 2. BN over batch -> m1t (512,16). 16 blocks x 32 j, 8 lanes/j ----
__global__ __launch_bounds__(256) void k_bn_feat(const float* __restrict__ featpart,
                                                 const int* __restrict__ data,
                                                 const float* __restrict__ g1,
                                                 const float* __restrict__ b1,
                                                 float* __restrict__ m1t) {
  const int tid = threadIdx.x;
  const int jl = tid >> 3, part = tid & 7;
  const int j = blockIdx.x * 32 + jl;
  float v[kB];
  if (j < kPE) {
#pragma unroll
    for (int b = 0; b < kB; ++b) {
      float s = 0.f;
      const int ch0 = part * 8;
#pragma unroll
      for (int ch = 0; ch < 8; ++ch)
        s += featpart[((b * 64 + ch0 + ch) << 8) + j];
      v[b] = s;
    }
  } else {
#pragma unroll
    for (int b = 0; b < kB; ++b)
      v[b] = (part == 0) ? (float)data[b * (kMAXLEN + kPE) + kMAXLEN + (j - kPE)] : 0.f;
  }
#pragma unroll
  for (int m = 1; m < 8; m <<= 1) {
#pragma unroll
    for (int b = 0; b < kB; ++b) v[b] += __shfl_xor(v[b], m);
  }
  const float pe = (j < kPE) ? sinf((float)j) : sinf((float)(j - kPE));
#pragma unroll
  for (int b = 0; b < kB; ++b)
    v[b] = (j < kPE) ? (v[b] * (1.f / 1024.f) + pe) : (v[b] + pe);
  float s = 0.f;
#pragma unroll
  for (int b = 0; b < kB; ++b) s += v[b];
  const float mean = s * (1.f / kB);
  float s2 = 0.f;
#pragma unroll
  for (int b = 0; b < kB; ++b) { float d = v[b] - mean; s2 += d * d; }
  const float inv = rsqrtf(s2 * (1.f / kB) + kEPS);
  if (part == 0) {
    const float g = g1[j], bb = b1[j];
    float o[kB];
#pragma unroll
    for (int b = 0; b < kB; ++b) o[b] = (v[b] - mean) * inv * g + bb;
#pragma unroll
    for (int q = 0; q < 4; ++q)
      *reinterpret_cast<float4*>(&m1t[j * kB + q * 4]) =
          *reinterpret_cast<float4*>(&o[q * 4]);
  }
}

// ---- 3a. split-K GEMM, 4 k-slices (m1t via SGPR broadcast) ----
__global__ __launch_bounds__(256) void k_go_gemm2(const float* __restrict__ m1t,
                                                  const float* __restrict__ w_go,
                                                  float* __restrict__ part) {
  const int c0 = blockIdx.x * 1024 + threadIdx.x * 4;
  const int k0 = blockIdx.y * 128;
  float4 acc[kB];
#pragma unroll
  for (int b = 0; b < kB; ++b) acc[b] = make_float4(0.f, 0.f, 0.f, 0.f);
#pragma unroll 4
  for (int k = 0; k < 128; ++k) {
    const float4 w = *reinterpret_cast<const float4*>(&w_go[(size_t)(k0 + k) * 65536 + c0]);
    const float* mrow = m1t + (size_t)(k0 + k) * kB;
#pragma unroll
    for (int b = 0; b < kB; ++b) {
      const float m = mrow[b];
      acc[b].x += m * w.x; acc[b].y += m * w.y;
      acc[b].z += m * w.z; acc[b].w += m * w.w;
    }
  }
  const size_t kb16 = (size_t)blockIdx.y * kB;
#pragma unroll
  for (int b = 0; b < kB; ++b) {
    *reinterpret_cast<float4*>(&part[(kb16 + b) * 65536 + c0]) = acc[b];
  }
}

// ---- 3b+4 fused. per-node: reduce 4 go partials + bias/relu, nf concat, BN -> x ----
__global__ __launch_bounds__(256) void k_go_bn(const float* __restrict__ part,
                                               const float* __restrict__ b_go,
                                               const float* __restrict__ nf,
                                               const float* __restrict__ g3,
                                               const float* __restrict__ b3,
                                               float* __restrict__ x) {
  const int n = blockIdx.x;
  const int tid = threadIdx.x;
  __shared__ float nfs[64];
  if (tid < 64) nfs[tid] = nf[n * 64 + tid];
  float val[4];
  float s = 0.f, s2 = 0.f;
#pragma unroll
  for (int i = 0; i < 4; ++i) {
    const int e = i * 256 + tid;
    const int b = e >> 6, c = e & 63;
    float a = part[(size_t)b * 65536 + n * 64 + c];
#pragma unroll
    for (int kb = 1; kb < 4; ++kb)
      a += part[(size_t)(kb * kB + b) * 65536 + n * 64 + c];
    a = fmaxf(a + b_go[n * 64 + c], 0.f);
    val[i] = a;
    s += a; s2 += a * a;
  }
  __syncthreads();
  if (tid < 64) {
    const float v = nfs[tid];
    s += 16.f * v; s2 += 16.f * v * v;
  }
  for (int o = 32; o > 0; o >>= 1) { s += __shfl_down(s, o); s2 += __shfl_down(s2, o); }
  __shared__ float ls[4], ls2[4];
  __shared__ float sscale, sshift;
  const int w = tid >> 6;
  if ((tid & 63) == 0) { ls[w] = s; ls2[w] = s2; }
  __syncthreads();
  if (tid == 0) {
    float S = ls[0] + ls[1] + ls[2] + ls[3];
    float S2 = ls2[0] + ls2[1] + ls2[2] + ls2[3];
    float mean = S * (1.f / 2048.f);
    float var = fmaxf(S2 * (1.f / 2048.f) - mean * mean, 0.f);
    float inv = rsqrtf(var + kEPS);
    float gg = g3[n];
    sscale = inv * gg;
    sshift = b3[n] - mean * inv * gg;
  }
  __syncthreads();
  const float scale = sscale, shift = sshift;
#pragma unroll
  for (int i = 0; i < 4; ++i) {
    const int e = i * 256 + tid;
    const int b = e >> 6, c = e & 63;
    x[((size_t)(b * kN + n)) * kC + c] = val[i] * scale + shift;
  }
#pragma unroll
  for (int i = 0; i < 4; ++i) {
    const int e = i * 256 + tid;
    const int b = e >> 6, c = e & 63;
    x[((size_t)(b * kN + n)) * kC + 64 + c] = nfs[c] * scale + shift;
  }
}

// ---- 5. q/k projections -> single bf16, [bn][64] layout ----
__global__ __launch_bounds__(256) void k_qkgen(const float* __restrict__ x,
                                               const float* __restrict__ wq,
                                               const float* __restrict__ wk,
                                               ushort* __restrict__ qb,
                                               ushort* __restrict__ kb) {
  __shared__ float a_s[32 * 68];
  __shared__ float w_s[32 * 128];
  const int row0 = blockIdx.x * 32;
  const int tid = threadIdx.x;
  const int tr = tid >> 5, tc = tid & 31;
  const int r0 = tr * 4, c0 = tc * 4;
  float acc[4][4] = {};
  for (int kc = 0; kc < 4; ++kc) {
    const int k0 = kc * 32;
    __syncthreads();
    {
      int r = tid >> 3, kk4 = tid & 7;
      float4 v = *reinterpret_cast<const float4*>(&x[(size_t)(row0 + r) * kC + k0 + kk4 * 4]);
      *reinterpret_cast<float4*>(&a_s[r * 68 + kk4 * 4]) = v;
    }
    for (int it = 0; it < 16; ++it) {
      int e = it * 256 + tid;
      int kk = e >> 7, h2 = e & 127;
      int c = k0 + kk;
      float v = (h2 < 64) ? wq[c * 64 + h2] : wk[c * 64 + (h2 - 64)];
      w_s[kk * 128 + h2] = v;
    }
    __syncthreads();
#pragma unroll 8
    for (int k = 0; k < 32; ++k) {
      float a[4];
#pragma unroll
      for (int i = 0; i < 4; ++i) a[i] = a_s[(r0 + i) * 68 + k];
      float4 b4 = *reinterpret_cast<float4*>(&w_s[k * 128 + c0]);
      float bj[4] = {b4.x, b4.y, b4.z, b4.w};
#pragma unroll
      for (int i = 0; i < 4; ++i)
#pragma unroll
        for (int j = 0; j < 4; ++j) acc[i][j] += a[i] * bj[j];
    }
  }
  const bool isq = (c0 < 64);
  const int h0 = isq ? c0 : (c0 - 64);
  ushort* oh = isq ? qb : kb;
#pragma unroll
  for (int i = 0; i < 4; ++i) {
    ushort hs[4];
#pragma unroll
    for (int j = 0; j < 4; ++j) hs[j] = f2bf(acc[i][j]);
    const size_t o = (size_t)(row0 + r0 + i) * 64 + h0;
    *reinterpret_cast<ushort4*>(&oh[o]) = *reinterpret_cast<ushort4*>(hs);
  }
}

// ---- 6. att sum-stats via MFMA (single bf16), mc-split over blockIdx.z ----
__global__ __launch_bounds__(512) void k_att_stats(const ushort* __restrict__ qb,
                                                   const ushort* __restrict__ kb,
                                                   float* __restrict__ psum) {
  const int nt = blockIdx.x, b = blockIdx.y;
  const int mc0 = blockIdx.z * 4;
  __shared__ uint4 smem4[1536];  // 24 KiB: Q@0 (8K), K@8192 (16K)
  char* smem = (char*)smem4;
  const int tid = threadIdx.x;
  const int lane = tid & 63, w = tid >> 6;
  const int l15 = lane & 15, lg = lane >> 4;

  {  // stage Q once: 64 rows x 64 bf16 (128 B/row)
    const int r = tid >> 3, ch = tid & 7;
    const size_t g = (size_t)(b * kN + nt * 64 + r) * 64 + ch * 8;
    const unsigned off = (unsigned)(r * 128 + ch * 16) ^ (unsigned)((r & 7) << 4);
    *reinterpret_cast<uint4*>(smem + off) = *reinterpret_cast<const uint4*>(qb + g);
  }

  const int c0s = tid >> 3, c1s = 64 + (tid >> 3);
  const int chs = tid & 7;
  const unsigned offK0 = (unsigned)(c0s * 128 + chs * 16) ^ (unsigned)((c0s & 7) << 4);
  const unsigned offK1 = (unsigned)(c1s * 128 + chs * 16) ^ (unsigned)((c1s & 7) << 4);
  const size_t gK0 = (size_t)(b * kN + mc0 * 128 + c0s) * 64 + chs * 8;
  const size_t gK1 = (size_t)(b * kN + mc0 * 128 + c1s) * 64 + chs * 8;

  uint4 ph0 = *reinterpret_cast<const uint4*>(kb + gK0);
  uint4 ph1 = *reinterpret_cast<const uint4*>(kb + gK1);

  for (int it = 0; it < 4; ++it) {
    const int mc = mc0 + it;
    __syncthreads();
    *reinterpret_cast<uint4*>(smem + 8192 + offK0) = ph0;
    *reinterpret_cast<uint4*>(smem + 8192 + offK1) = ph1;
    __syncthreads();
    if (it < 3) {
      const size_t k1 = (size_t)(it + 1) * 128 * 64;
      ph0 = *reinterpret_cast<const uint4*>(kb + gK0 + k1);
      ph1 = *reinterpret_cast<const uint4*>(kb + gK1 + k1);
    }
    f32x4 acc[4] = {{0.f,0.f,0.f,0.f},{0.f,0.f,0.f,0.f},{0.f,0.f,0.f,0.f},{0.f,0.f,0.f,0.f}};
#pragma unroll
    for (int ss = 0; ss < 2; ++ss) {
      const int r = w * 16 + l15;  // m-row within chunk
      const unsigned aoff = (unsigned)(r * 128 + ss * 64 + lg * 16) ^ (unsigned)((r & 7) << 4);
      bfrag ah = *reinterpret_cast<const bfrag*>(smem + 8192 + aoff);
#pragma unroll
      for (int nf = 0; nf < 4; ++nf) {
        const int c = nf * 16 + l15;
        const unsigned boff = (unsigned)(c * 128 + ss * 64 + lg * 16) ^ (unsigned)((c & 7) << 4);
        bfrag bh = *reinterpret_cast<const bfrag*>(smem + boff);
        acc[nf] = __builtin_amdgcn_mfma_f32_16x16x32_bf16(ah, bh, acc[nf], 0, 0, 0);
      }
    }
#pragma unroll
    for (int i = 0; i < 4; ++i) {
      float sm = __expf(acc[0][i] * 0.125f) + __expf(acc[1][i] * 0.125f)
               + __expf(acc[2][i] * 0.125f) + __expf(acc[3][i] * 0.125f);
#pragma unroll
      for (int msk = 1; msk < 16; msk <<= 1) sm += __shfl_xor(sm, msk);
      if (l15 == 0) {
        const int m = mc * 128 + w * 16 + lg * 4 + i;
        psum[(size_t)(b * 16 + nt) * kN + m] = sm;
      }
    }
  }
}

// ---- 8. adj emit: recompute Q·K^T, adj = go_adj + exp(s/8)*cinv -> single bf16 ----
__global__ __launch_bounds__(512) void k_adj_emit(const ushort* __restrict__ qb,
                                                  const ushort* __restrict__ kb,
                                                  const float* __restrict__ go_adj,
                                                  const float* __restrict__ psum,
                                                  ushort* __restrict__ adj) {
  const int mc = blockIdx.x, nt = blockIdx.y, b = blockIdx.z;
  __shared__ uint4 smem4[2304];  // 36 KiB: Q@0 (8K), K@8192 (16K); c32 overlay
  __shared__ float cinvs[128];
  char* smem = (char*)smem4;
  float* c32 = (float*)smem4;
  const int tid = threadIdx.x;
  const int lane = tid & 63, w = tid >> 6;
  const int wr = w >> 2, wc = w & 3;
  const int l15 = lane & 15, lg = lane >> 4;

  if (tid < 128) {
    const int m = mc * 128 + tid;
    float S = 0.f;
#pragma unroll
    for (int c = 0; c < 16; ++c) S += psum[(size_t)(b * 16 + c) * kN + m];
    cinvs[tid] = 1.f / S;
  }
  {
    const int r = tid >> 3, ch = tid & 7;
    const size_t g = (size_t)(b * kN + nt * 64 + r) * 64 + ch * 8;
    const unsigned off = (unsigned)(r * 128 + ch * 16) ^ (unsigned)((r & 7) << 4);
    *reinterpret_cast<uint4*>(smem + off) = *reinterpret_cast<const uint4*>(qb + g);
  }
#pragma unroll
  for (int p = 0; p < 2; ++p) {
    const int e = p * 512 + tid;
    const int c = e >> 3, ch = e & 7;
    const size_t g = (size_t)(b * kN + mc * 128 + c) * 64 + ch * 8;
    const unsigned off = (unsigned)(c * 128 + ch * 16) ^ (unsigned)((c & 7) << 4);
    *reinterpret_cast<uint4*>(smem + 8192 + off) = *reinterpret_cast<const uint4*>(kb + g);
  }
  __syncthreads();
  f32x4 acc[2][2] = {{{0.f,0.f,0.f,0.f},{0.f,0.f,0.f,0.f}},
                     {{0.f,0.f,0.f,0.f},{0.f,0.f,0.f,0.f}}};
#pragma unroll
  for (int ss = 0; ss < 2; ++ss) {
    bfrag ah[2], bh[2];
#pragma unroll
    for (int nf = 0; nf < 2; ++nf) {
      const int r = wr * 32 + nf * 16 + l15;
      const unsigned aoff = (unsigned)(r * 128 + ss * 64 + lg * 16) ^ (unsigned)((r & 7) << 4);
      ah[nf] = *reinterpret_cast<const bfrag*>(smem + aoff);
    }
#pragma unroll
    for (int mf = 0; mf < 2; ++mf) {
      const int c = wc * 32 + mf * 16 + l15;
      const unsigned boff = (unsigned)(c * 128 + ss * 64 + lg * 16) ^ (unsigned)((c & 7) << 4);
      bh[mf] = *reinterpret_cast<const bfrag*>(smem + 8192 + boff);
    }
#pragma unroll
    for (int nf = 0; nf < 2; ++nf)
#pragma unroll
      for (int mf = 0; mf < 2; ++mf)
        acc[nf][mf] = __builtin_amdgcn_mfma_f32_16x16x32_bf16(ah[nf], bh[mf], acc[nf][mf], 0, 0, 0);
  }
  __syncthreads();
#pragma unroll
  for (int mf = 0; mf < 2; ++mf) {
    const int mLoc = wc * 32 + mf * 16 + l15;
    const float I = cinvs[mLoc];
#pragma unroll
    for (int nf = 0; nf < 2; ++nf) {
#pragma unroll
      for (int i = 0; i < 4; ++i) {
        const int nLoc = wr * 32 + nf * 16 + lg * 4 + i;
        c32[nLoc * 132 + mLoc] = __expf(acc[nf][mf][i] * 0.125f) * I;
      }
    }
  }
  __syncthreads();
#pragma unroll
  for (int p = 0; p < 2; ++p) {
    const int e = p * 512 + tid;
    const int n = e >> 4, m0 = (e & 15) * 8;
    const float* cr = &c32[n * 132 + m0];
    const float* ga = &go_adj[(size_t)(nt * 64 + n) * kN + mc * 128 + m0];
    ushort hs[8];
#pragma unroll
    for (int j = 0; j < 8; ++j) hs[j] = f2bf(cr[j] + ga[j]);
    const size_t o = (size_t)(b * kN + nt * 64 + n) * kN + mc * 128 + m0;
    *reinterpret_cast<uint4*>(&adj[o]) = *reinterpret_cast<uint4*>(hs);
  }
}

// ---- T. transpose: f32 [16][1024][128] -> single bf16 [16][128][1024] ----
__global__ __launch_bounds__(256) void k_transp(const float* __restrict__ src,
                                                ushort* __restrict__ xt) {
  const int nt = blockIdx.x, b = blockIdx.y;
  __shared__ float tile[64][133];
  const int tid = threadIdx.x;
#pragma unroll
  for (int it = 0; it < 8; ++it) {
    int e = it * 256 + tid;
    int r = e >> 5, c4 = e & 31;
    float4 v = *reinterpret_cast<const float4*>(&src[(size_t)(b * kN + nt * 64 + r) * kC + c4 * 4]);
    *reinterpret_cast<float4*>(&tile[r][c4 * 4]) = v;
  }
  __syncthreads();
  const int cl = tid >> 3;
  const int chunk = tid & 7;
  const int n0 = chunk * 8;
#pragma unroll
  for (int cg = 0; cg < 4; ++cg) {
    const int c = cg * 32 + cl;
    const size_t obase = (size_t)(b * kC + c) * kN + nt * 64 + n0;
    ushort hs[8];
#pragma unroll
    for (int j = 0; j < 8; ++j) hs[j] = f2bf(tile[n0 + j][c]);
    *reinterpret_cast<uint4*>(&xt[obase]) = *reinterpret_cast<uint4*>(hs);
  }
}

// ---- 9. Y = alpha * adj @ X (- Zsub); single bf16, BM=64, T14 prefetch ----
__global__ __launch_bounds__(512) void k_adjmm_mfma(const ushort* __restrict__ adj,
                                                    const ushort* __restrict__ xt,
                                                    const float* __restrict__ Zsub,
                                                    float* __restrict__ Y, float alpha,
                                                    ushort* __restrict__ yt) {
  const int bid = blockIdx.x;
  const int swz = (bid & 7) * 32 + (bid >> 3);
  const int b = swz >> 4, rb = swz & 15;
  __shared__ uint4 smem4[2304];  // 36 KiB: A@0 (8K), B@8192 (16K); c32 overlay
  char* smem = (char*)smem4;
  float* c32 = (float*)smem4;
  const int tid = threadIdx.x;
  const int lane = tid & 63, w = tid >> 6;
  const int wr = w >> 1, wc = w & 1;
  const int l15 = lane & 15, lg = lane >> 4;

  const int ra = tid >> 3, cha = tid & 7;
  const unsigned offA = (unsigned)(ra * 128 + cha * 16) ^ (unsigned)((ra & 7) << 4);
  const size_t gA = ((size_t)(b * kN + rb * 64 + ra)) * kN + cha * 8;
  const int cb0 = tid >> 3, cb1 = 64 + (tid >> 3);
  const unsigned offB0 = (unsigned)(cb0 * 128 + cha * 16) ^ (unsigned)((cb0 & 7) << 4);
  const unsigned offB1 = (unsigned)(cb1 * 128 + cha * 16) ^ (unsigned)((cb1 & 7) << 4);
  const size_t gB0 = ((size_t)b * kC + cb0) * kN + cha * 8;
  const size_t gB1 = ((size_t)b * kC + cb1) * kN + cha * 8;

  f32x4 acc[4] = {{0.f,0.f,0.f,0.f},{0.f,0.f,0.f,0.f},{0.f,0.f,0.f,0.f},{0.f,0.f,0.f,0.f}};

  uint4 pa  = *reinterpret_cast<const uint4*>(adj + gA);
  uint4 pb0 = *reinterpret_cast<const uint4*>(xt + gB0);
  uint4 pb1 = *reinterpret_cast<const uint4*>(xt + gB1);

  for (int kt = 0; kt < 16; ++kt) {
    __syncthreads();
    *reinterpret_cast<uint4*>(smem + offA)         = pa;
    *reinterpret_cast<uint4*>(smem + 8192 + offB0) = pb0;
    *reinterpret_cast<uint4*>(smem + 8192 + offB1) = pb1;
    __syncthreads();
    if (kt < 15) {
      const int k1 = (kt + 1) * 64;
      pa  = *reinterpret_cast<const uint4*>(adj + gA + k1);
      pb0 = *reinterpret_cast<const uint4*>(xt + gB0 + k1);
      pb1 = *reinterpret_cast<const uint4*>(xt + gB1 + k1);
    }
#pragma unroll
    for (int ss = 0; ss < 2; ++ss) {
      const int r = wr * 16 + l15;
      const unsigned aoff = (unsigned)(r * 128 + ss * 64 + lg * 16) ^ (unsigned)((r & 7) << 4);
      bfrag ah = *reinterpret_cast<const bfrag*>(smem + aoff);
      bfrag bh[4];
#pragma unroll
      for (int ct = 0; ct < 4; ++ct) {
        const int c = wc * 64 + ct * 16 + l15;
        const unsigned boff = (unsigned)(c * 128 + ss * 64 + lg * 16) ^ (unsigned)((c & 7) << 4);
        bh[ct] = *reinterpret_cast<const bfrag*>(smem + 8192 + boff);
      }
#pragma unroll
      for (int ct = 0; ct < 4; ++ct)
        acc[ct] = __builtin_amdgcn_mfma_f32_16x16x32_bf16(ah, bh[ct], acc[ct], 0, 0, 0);
    }
  }
  const int orow = rb * 64 + wr * 16 + lg * 4;
  __syncthreads();  // all LDS reads done before c32 overlay
#pragma unroll
  for (int ct = 0; ct < 4; ++ct) {
    const int ocol = wc * 64 + ct * 16 + l15;
#pragma unroll
    for (int i = 0; i < 4; ++i) {
      const size_t idx = ((size_t)(b * kN + orow + i)) * kC + ocol;
      float v = alpha * acc[ct][i];
      if (Zsub) v -= Zsub[idx];
      Y[idx] = v;
      if (yt) c32[(wr * 16 + lg * 4 + i) * 132 + ocol] = v;
    }
  }
  if (yt) {
    __syncthreads();
    const int c = tid >> 2, nch = tid & 3;
    const int n0 = nch * 16;
    ushort hs[16];
#pragma unroll
    for (int j = 0; j < 16; ++j) hs[j] = f2bf(c32[(n0 + j) * 132 + c]);
    const size_t obase = (size_t)(b * kC + c) * kN + rb * 64 + n0;
    *reinterpret_cast<uint4*>(&yt[obase]) = *reinterpret_cast<uint4*>(hs);
    *reinterpret_cast<uint4*>(&yt[obase + 8]) = *reinterpret_cast<uint4*>(hs + 8);
  }
}

// ---- 10. z = x@th0 + tcur@th1 + tnext@th2 + x ; emits per-row sum/sumsq ----
__global__ __launch_bounds__(256) void k_theta(const float* __restrict__ x,
                                               const float* __restrict__ tcur,
                                               const float* __restrict__ tnext,
                                               const float* __restrict__ theta,
                                               float* __restrict__ z,
                                               float* __restrict__ sumz,
                                               float* __restrict__ sumzz) {
  __shared__ float a_s[32 * 68];
  __shared__ float w_s[32 * 128];
  const int row0 = blockIdx.x * 32;
  const int tid = threadIdx.x;
  const int tr = tid >> 5, tc = tid & 31;
  const int r0 = tr * 4, c0 = tc * 4;
  float acc[4][4] = {};
  const float* srcs[3] = {x, tcur, tnext};
  for (int s = 0; s < 3; ++s) {
    const float* A = srcs[s];
    for (int kc = 0; kc < 4; ++kc) {
      const int k0 = kc * 32;
      __syncthreads();
      {
        int r = tid >> 3, kk4 = tid & 7;
        float4 v = *reinterpret_cast<const float4*>(&A[(size_t)(row0 + r) * kC + k0 + kk4 * 4]);
        *reinterpret_cast<float4*>(&a_s[r * 68 + kk4 * 4]) = v;
      }
#pragma unroll
      for (int it = 0; it < 4; ++it) {
        int e4 = it * 256 + tid;
        int kk = e4 >> 5, d4 = e4 & 31;
        float4 v = *reinterpret_cast<const float4*>(
            &theta[(size_t)s * 16384 + (size_t)(k0 + kk) * kC + d4 * 4]);
        *reinterpret_cast<float4*>(&w_s[kk * 128 + d4 * 4]) = v;
      }
      __syncthreads();
#pragma unroll 8
      for (int k = 0; k < 32; ++k) {
        float a[4];
#pragma unroll
        for (int i = 0; i < 4; ++i) a[i] = a_s[(r0 + i) * 68 + k];
        float4 b4 = *reinterpret_cast<float4*>(&w_s[k * 128 + c0]);
        float bj[4] = {b4.x, b4.y, b4.z, b4.w};
#pragma unroll
        for (int i = 0; i < 4; ++i)
#pragma unroll
          for (int j = 0; j < 4; ++j) acc[i][j] += a[i] * bj[j];
      }
    }
  }
  float rs[4], rq[4];
#pragma unroll
  for (int i = 0; i < 4; ++i) {
    size_t idx = (size_t)(row0 + r0 + i) * kC + c0;
    float4 xv = *reinterpret_cast<const float4*>(&x[idx]);
    float4 o = {acc[i][0] + xv.x, acc[i][1] + xv.y, acc[i][2] + xv.z, acc[i][3] + xv.w};
    *reinterpret_cast<float4*>(&z[idx]) = o;
    rs[i] = o.x + o.y + o.z + o.w;
    rq[i] = o.x * o.x + o.y * o.y + o.z * o.z + o.w * o.w;
  }
#pragma unroll
  for (int m = 1; m < 32; m <<= 1) {
#pragma unroll
    for (int i = 0; i < 4; ++i) { rs[i] += __shfl_xor(rs[i], m); rq[i] += __shfl_xor(rq[i], m); }
  }
  if (tc == 0) {
#pragma unroll
    for (int i = 0; i < 4; ++i) {
      sumz[row0 + r0 + i] = rs[i];
      sumzz[row0 + r0 + i] = rq[i];
    }
  }
}

// ---- 11. per-node BN (stats precomputed) + relu + dot(w_out) -> out ----
__global__ __launch_bounds__(256) void k_final(const float* __restrict__ z,
                                               const float* __restrict__ sumz,
                                               const float* __restrict__ sumzz,
                                               const float* __restrict__ g4,
                                               const float* __restrict__ b4v,
                                               const float* __restrict__ w_out,
                                               const float* __restrict__ b_out,
                                               float* __restrict__ out) {
  const int n = blockIdx.x;
  const int tid = threadIdx.x;
  __shared__ float sscale, sshift;
  if (tid < 16) {
    float a = sumz[tid * kN + n];
    float q = sumzz[tid * kN + n];
#pragma unroll
    for (int m = 1; m < 16; m <<= 1) { a += __shfl_xor(a, m); q += __shfl_xor(q, m); }
    if (tid == 0) {
      float mean = a * (1.f / 2048.f);
      float var = fmaxf(q * (1.f / 2048.f) - mean * mean, 0.f);
      float inv = rsqrtf(var + kEPS);
      float gg = g4[n];
      sscale = inv * gg;
      sshift = b4v[n] - mean * inv * gg;
    }
  }
  __syncthreads();
  const float scale = sscale, shift = sshift;
  const int b = tid >> 4, c0 = (tid & 15) * 8;
  float p = 0.f;
#pragma unroll
  for (int j = 0; j < 8; ++j) {
    float v = z[(size_t)(b * kN + n) * kC + c0 + j] * scale + shift;
    v = fmaxf(v, 0.f);
    p += v * w_out[c0 + j];
  }
  for (int o = 8; o > 0; o >>= 1) p += __shfl_down(p, o, 16);
  if ((tid & 15) == 0) out[b * kN + n] = p + b_out[0];
}

extern "C" void kernel_launch(void* const* d_in, const int* in_sizes, int n_in,
                              void* d_out, int out_size, void* d_ws, size_t ws_size,
                              hipStream_t stream) {
  const int*   data = (const int*)d_in[0];
  const float* node_features = (const float*)d_in[1];
  const float* go_adj = (const float*)d_in[2];
  const float* emb  = (const float*)d_in[4];
  const float* w_go = (const float*)d_in[5];
  const float* b_go = (const float*)d_in[6];
  const float* wq   = (const float*)d_in[7];
  const float* wk   = (const float*)d_in[8];
  const float* theta= (const float*)d_in[9];
  const float* g1   = (const float*)d_in[10];
  const float* b1   = (const float*)d_in[11];
  const float* g3   = (const float*)d_in[12];
  const float* b3   = (const float*)d_in[13];
  const float* g4   = (const float*)d_in[14];
  const float* b4   = (const float*)d_in[15];
  const float* w_out= (const float*)d_in[16];
  const float* b_out= (const float*)d_in[17];

  float* ws = (float*)d_ws;
  float* featpart = ws + OFF_FEATPART;
  float* m1t   = ws + OFF_M1;
  float* x     = ws + OFF_X;
  float* z     = ws + OFF_Z;
  float* tcur  = ws + OFF_TCUR;
  float* tnext = ws + OFF_TNEXT;
  float* gopart= ws + OFF_GOPART;
  float* psum  = ws + OFF_PSUM;
  float* sumz  = ws + OFF_SUMZ;
  float* sumzz = ws + OFF_SUMZZ;
  ushort* adj  = (ushort*)(ws + OFF_ADJ);
  ushort* xt   = (ushort*)(ws + OFF_XT);
  ushort* qb   = (ushort*)(ws + OFF_Q);
  ushort* kb   = (ushort*)(ws + OFF_K);
  ushort* tt   = (ushort*)(ws + OFF_TT);

  k_embsum<<<dim3(16, 64), 256, 0, stream>>>(data, emb, featpart);
  k_bn_feat<<<16, 256, 0, stream>>>(featpart, data, g1, b1, m1t);
  k_go_gemm2<<<dim3(64, 4), 256, 0, stream>>>(m1t, w_go, gopart);
  k_go_bn<<<1024, 256, 0, stream>>>(gopart, b_go, node_features, g3, b3, x);
  k_qkgen<<<512, 256, 0, stream>>>(x, wq, wk, qb, kb);
  k_att_stats<<<dim3(16, 16, 2), 512, 0, stream>>>(qb, kb, psum);
  k_adj_emit<<<dim3(8, 16, 16), 512, 0, stream>>>(qb, kb, go_adj, psum, adj);
  k_transp<<<dim3(16, 16), 256, 0, stream>>>(x, xt);
  k_adjmm_mfma<<<256, 512, 0, stream>>>(adj, xt, nullptr, tcur, 1.0f, tt);
  k_adjmm_mfma<<<256, 512, 0, stream>>>(adj, tt, x, tnext, 2.0f, nullptr);
  k_theta<<<512, 256, 0, stream>>>(x, tcur, tnext, theta, z, sumz, sumzz);
  k_final<<<1024, 256, 0, stream>>>(z, sumz, sumzz, g4, b4, w_out, b_out, (float*)d_out);
}

// Round 15
// 178.341 us; speedup vs baseline: 1.8805x; 1.0336x over previous
//
#include <hip/hip_runtime.h>

namespace {
constexpr int kB = 16;
constexpr int kMAXLEN = 1024;
constexpr int kPE = 256;
constexpr int kN = 1024;
constexpr int kEMB = 256;
constexpr int kC = 128;
constexpr float kEPS = 1e-5f;

// workspace offsets in floats
constexpr size_t OFF_FEATPART = 0;                         // 16*64*256 = 262144
constexpr size_t OFF_M1       = 262144;                    // 512*16
constexpr size_t OFF_X        = 270336;                    // 16*1024*128
constexpr size_t OFF_Z        = OFF_X    + 2097152;
constexpr size_t OFF_TCUR     = OFF_Z    + 2097152;
constexpr size_t OFF_TNEXT    = OFF_TCUR + 2097152;
constexpr size_t OFF_GOPART   = OFF_TNEXT+ 2097152;        // 4*16*65536
constexpr size_t OFF_PSUM     = OFF_GOPART + 4194304;      // 16*16*1024
constexpr size_t OFF_SUMZ     = OFF_PSUM + 262144;
constexpr size_t OFF_SUMZZ    = OFF_SUMZ + 16384;
constexpr size_t OFF_ADJ      = OFF_SUMZZ + 16384;         // 16.8M bf16
constexpr size_t OFF_XT       = OFF_ADJ  + 8388608;
constexpr size_t OFF_Q        = OFF_XT   + 1048576;
constexpr size_t OFF_K        = OFF_Q    + 524288;
constexpr size_t OFF_TT       = OFF_K    + 524288;

typedef __attribute__((ext_vector_type(8))) short bfrag;
typedef __attribute__((ext_vector_type(4))) float f32x4;

__device__ inline ushort f2bf(float f) {
  unsigned u = __float_as_uint(f);
  unsigned r = (u + 0x7FFFu + ((u >> 16) & 1u)) >> 16;  // RNE
  return (ushort)r;
}
} // namespace

// ---- 1. embedding gather partial sums: featpart[b][chunk64][e] ----
__global__ __launch_bounds__(256) void k_embsum(const int* __restrict__ data,
                                                const float* __restrict__ emb,
                                                float* __restrict__ featpart) {
  const int b = blockIdx.x, ch = blockIdx.y;   // 16 x 64
  const int e = threadIdx.x;                   // 256
  const int* row = data + b * (kMAXLEN + kPE) + ch * 16;
  float acc = 0.f;
#pragma unroll 4
  for (int l = 0; l < 16; ++l) {
    acc += emb[(size_t)row[l] * kEMB + e];
  }
  featpart[((b * 64 + ch) << 8) + e] = acc;
}

// ---- 2. BN over batch -> m1t (512,16). 16 blocks x 32 j, 8 lanes/j ----
__global__ __launch_bounds__(256) void k_bn_feat(const float* __restrict__ featpart,
                                                 const int* __restrict__ data,
                                                 const float* __restrict__ g1,
                                                 const float* __restrict__ b1,
                                                 float* __restrict__ m1t) {
  const int tid = threadIdx.x;
  const int jl = tid >> 3, part = tid & 7;
  const int j = blockIdx.x * 32 + jl;
  float v[kB];
  if (j < kPE) {
#pragma unroll
    for (int b = 0; b < kB; ++b) {
      float s = 0.f;
      const int ch0 = part * 8;
#pragma unroll
      for (int ch = 0; ch < 8; ++ch)
        s += featpart[((b * 64 + ch0 + ch) << 8) + j];
      v[b] = s;
    }
  } else {
#pragma unroll
    for (int b = 0; b < kB; ++b)
      v[b] = (part == 0) ? (float)data[b * (kMAXLEN + kPE) + kMAXLEN + (j - kPE)] : 0.f;
  }
#pragma unroll
  for (int m = 1; m < 8; m <<= 1) {
#pragma unroll
    for (int b = 0; b < kB; ++b) v[b] += __shfl_xor(v[b], m);
  }
  const float pe = (j < kPE) ? sinf((float)j) : sinf((float)(j - kPE));
#pragma unroll
  for (int b = 0; b < kB; ++b)
    v[b] = (j < kPE) ? (v[b] * (1.f / 1024.f) + pe) : (v[b] + pe);
  float s = 0.f;
#pragma unroll
  for (int b = 0; b < kB; ++b) s += v[b];
  const float mean = s * (1.f / kB);
  float s2 = 0.f;
#pragma unroll
  for (int b = 0; b < kB; ++b) { float d = v[b] - mean; s2 += d * d; }
  const float inv = rsqrtf(s2 * (1.f / kB) + kEPS);
  if (part == 0) {
    const float g = g1[j], bb = b1[j];
    float o[kB];
#pragma unroll
    for (int b = 0; b < kB; ++b) o[b] = (v[b] - mean) * inv * g + bb;
#pragma unroll
    for (int q = 0; q < 4; ++q)
      *reinterpret_cast<float4*>(&m1t[j * kB + q * 4]) =
          *reinterpret_cast<float4*>(&o[q * 4]);
  }
}

// ---- 3a. split-K GEMM, 4 k-slices (m1t via SGPR broadcast) ----
__global__ __launch_bounds__(256) void k_go_gemm2(const float* __restrict__ m1t,
                                                  const float* __restrict__ w_go,
                                                  float* __restrict__ part) {
  const int c0 = blockIdx.x * 1024 + threadIdx.x * 4;
  const int k0 = blockIdx.y * 128;
  float4 acc[kB];
#pragma unroll
  for (int b = 0; b < kB; ++b) acc[b] = make_float4(0.f, 0.f, 0.f, 0.f);
#pragma unroll 4
  for (int k = 0; k < 128; ++k) {
    const float4 w = *reinterpret_cast<const float4*>(&w_go[(size_t)(k0 + k) * 65536 + c0]);
    const float* mrow = m1t + (size_t)(k0 + k) * kB;
#pragma unroll
    for (int b = 0; b < kB; ++b) {
      const float m = mrow[b];
      acc[b].x += m * w.x; acc[b].y += m * w.y;
      acc[b].z += m * w.z; acc[b].w += m * w.w;
    }
  }
  const size_t kb16 = (size_t)blockIdx.y * kB;
#pragma unroll
  for (int b = 0; b < kB; ++b) {
    *reinterpret_cast<float4*>(&part[(kb16 + b) * 65536 + c0]) = acc[b];
  }
}

// ---- 3b+4 fused. per-node: reduce 4 go partials + bias/relu, nf concat, BN -> x ----
__global__ __launch_bounds__(256) void k_go_bn(const float* __restrict__ part,
                                               const float* __restrict__ b_go,
                                               const float* __restrict__ nf,
                                               const float* __restrict__ g3,
                                               const float* __restrict__ b3,
                                               float* __restrict__ x) {
  const int n = blockIdx.x;
  const int tid = threadIdx.x;
  __shared__ float nfs[64];
  if (tid < 64) nfs[tid] = nf[n * 64 + tid];
  float val[4];
  float s = 0.f, s2 = 0.f;
#pragma unroll
  for (int i = 0; i < 4; ++i) {
    const int e = i * 256 + tid;
    const int b = e >> 6, c = e & 63;
    float a = part[(size_t)b * 65536 + n * 64 + c];
#pragma unroll
    for (int kb = 1; kb < 4; ++kb)
      a += part[(size_t)(kb * kB + b) * 65536 + n * 64 + c];
    a = fmaxf(a + b_go[n * 64 + c], 0.f);
    val[i] = a;
    s += a; s2 += a * a;
  }
  __syncthreads();
  if (tid < 64) {
    const float v = nfs[tid];
    s += 16.f * v; s2 += 16.f * v * v;
  }
  for (int o = 32; o > 0; o >>= 1) { s += __shfl_down(s, o); s2 += __shfl_down(s2, o); }
  __shared__ float ls[4], ls2[4];
  __shared__ float sscale, sshift;
  const int w = tid >> 6;
  if ((tid & 63) == 0) { ls[w] = s; ls2[w] = s2; }
  __syncthreads();
  if (tid == 0) {
    float S = ls[0] + ls[1] + ls[2] + ls[3];
    float S2 = ls2[0] + ls2[1] + ls2[2] + ls2[3];
    float mean = S * (1.f / 2048.f);
    float var = fmaxf(S2 * (1.f / 2048.f) - mean * mean, 0.f);
    float inv = rsqrtf(var + kEPS);
    float gg = g3[n];
    sscale = inv * gg;
    sshift = b3[n] - mean * inv * gg;
  }
  __syncthreads();
  const float scale = sscale, shift = sshift;
#pragma unroll
  for (int i = 0; i < 4; ++i) {
    const int e = i * 256 + tid;
    const int b = e >> 6, c = e & 63;
    x[((size_t)(b * kN + n)) * kC + c] = val[i] * scale + shift;
  }
#pragma unroll
  for (int i = 0; i < 4; ++i) {
    const int e = i * 256 + tid;
    const int b = e >> 6, c = e & 63;
    x[((size_t)(b * kN + n)) * kC + 64 + c] = nfs[c] * scale + shift;
  }
}

// ---- 5. q/k projections -> single bf16, [bn][64] layout ----
__global__ __launch_bounds__(256) void k_qkgen(const float* __restrict__ x,
                                               const float* __restrict__ wq,
                                               const float* __restrict__ wk,
                                               ushort* __restrict__ qb,
                                               ushort* __restrict__ kb) {
  __shared__ float a_s[32 * 68];
  __shared__ float w_s[32 * 128];
  const int row0 = blockIdx.x * 32;
  const int tid = threadIdx.x;
  const int tr = tid >> 5, tc = tid & 31;
  const int r0 = tr * 4, c0 = tc * 4;
  float acc[4][4] = {};
  for (int kc = 0; kc < 4; ++kc) {
    const int k0 = kc * 32;
    __syncthreads();
    {
      int r = tid >> 3, kk4 = tid & 7;
      float4 v = *reinterpret_cast<const float4*>(&x[(size_t)(row0 + r) * kC + k0 + kk4 * 4]);
      *reinterpret_cast<float4*>(&a_s[r * 68 + kk4 * 4]) = v;
    }
    for (int it = 0; it < 16; ++it) {
      int e = it * 256 + tid;
      int kk = e >> 7, h2 = e & 127;
      int c = k0 + kk;
      float v = (h2 < 64) ? wq[c * 64 + h2] : wk[c * 64 + (h2 - 64)];
      w_s[kk * 128 + h2] = v;
    }
    __syncthreads();
#pragma unroll 8
    for (int k = 0; k < 32; ++k) {
      float a[4];
#pragma unroll
      for (int i = 0; i < 4; ++i) a[i] = a_s[(r0 + i) * 68 + k];
      float4 b4 = *reinterpret_cast<float4*>(&w_s[k * 128 + c0]);
      float bj[4] = {b4.x, b4.y, b4.z, b4.w};
#pragma unroll
      for (int i = 0; i < 4; ++i)
#pragma unroll
        for (int j = 0; j < 4; ++j) acc[i][j] += a[i] * bj[j];
    }
  }
  const bool isq = (c0 < 64);
  const int h0 = isq ? c0 : (c0 - 64);
  ushort* oh = isq ? qb : kb;
#pragma unroll
  for (int i = 0; i < 4; ++i) {
    ushort hs[4];
#pragma unroll
    for (int j = 0; j < 4; ++j) hs[j] = f2bf(acc[i][j]);
    const size_t o = (size_t)(row0 + r0 + i) * 64 + h0;
    *reinterpret_cast<ushort4*>(&oh[o]) = *reinterpret_cast<ushort4*>(hs);
  }
}

// ---- 6. att sum-stats via MFMA (single bf16), K double-buffered LDS ----
__global__ __launch_bounds__(512) void k_att_stats(const ushort* __restrict__ qb,
                                                   const ushort* __restrict__ kb,
                                                   float* __restrict__ psum) {
  const int nt = blockIdx.x, b = blockIdx.y;
  const int mc0 = blockIdx.z * 4;
  __shared__ uint4 smem4[2560];  // 40 KiB: Q@0 (8K), K bufs @8192 + sel*16384
  char* smem = (char*)smem4;
  const int tid = threadIdx.x;
  const int lane = tid & 63, w = tid >> 6;
  const int l15 = lane & 15, lg = lane >> 4;

  {  // stage Q once
    const int r = tid >> 3, ch = tid & 7;
    const size_t g = (size_t)(b * kN + nt * 64 + r) * 64 + ch * 8;
    const unsigned off = (unsigned)(r * 128 + ch * 16) ^ (unsigned)((r & 7) << 4);
    *reinterpret_cast<uint4*>(smem + off) = *reinterpret_cast<const uint4*>(qb + g);
  }

  const int c0s = tid >> 3, c1s = 64 + (tid >> 3);
  const int chs = tid & 7;
  const unsigned offK0 = (unsigned)(c0s * 128 + chs * 16) ^ (unsigned)((c0s & 7) << 4);
  const unsigned offK1 = (unsigned)(c1s * 128 + chs * 16) ^ (unsigned)((c1s & 7) << 4);
  const size_t gK0 = (size_t)(b * kN + mc0 * 128 + c0s) * 64 + chs * 8;
  const size_t gK1 = (size_t)(b * kN + mc0 * 128 + c1s) * 64 + chs * 8;

  // prologue: chunk 0 -> buf0, prefetch chunk 1 into regs
  uint4 ph0 = *reinterpret_cast<const uint4*>(kb + gK0);
  uint4 ph1 = *reinterpret_cast<const uint4*>(kb + gK1);
  *reinterpret_cast<uint4*>(smem + 8192 + offK0) = ph0;
  *reinterpret_cast<uint4*>(smem + 8192 + offK1) = ph1;
  {
    const size_t k1 = (size_t)128 * 64;
    ph0 = *reinterpret_cast<const uint4*>(kb + gK0 + k1);
    ph1 = *reinterpret_cast<const uint4*>(kb + gK1 + k1);
  }
  __syncthreads();

  for (int it = 0; it < 4; ++it) {
    const int mc = mc0 + it;
    const unsigned bufC = 8192 + (unsigned)(it & 1) * 16384;
    const unsigned bufN = 8192 + (unsigned)((it + 1) & 1) * 16384;
    if (it < 3) {  // write next chunk (regs) into other buffer; prefetch it+2
      *reinterpret_cast<uint4*>(smem + bufN + offK0) = ph0;
      *reinterpret_cast<uint4*>(smem + bufN + offK1) = ph1;
      if (it < 2) {
        const size_t k2 = (size_t)(it + 2) * 128 * 64;
        ph0 = *reinterpret_cast<const uint4*>(kb + gK0 + k2);
        ph1 = *reinterpret_cast<const uint4*>(kb + gK1 + k2);
      }
    }
    f32x4 acc[4] = {{0.f,0.f,0.f,0.f},{0.f,0.f,0.f,0.f},{0.f,0.f,0.f,0.f},{0.f,0.f,0.f,0.f}};
#pragma unroll
    for (int ss = 0; ss < 2; ++ss) {
      const int r = w * 16 + l15;
      const unsigned aoff = ((unsigned)(r * 128 + ss * 64 + lg * 16) ^ (unsigned)((r & 7) << 4)) + bufC;
      bfrag ah = *reinterpret_cast<const bfrag*>(smem + aoff);
#pragma unroll
      for (int nf = 0; nf < 4; ++nf) {
        const int c = nf * 16 + l15;
        const unsigned boff = (unsigned)(c * 128 + ss * 64 + lg * 16) ^ (unsigned)((c & 7) << 4);
        bfrag bh = *reinterpret_cast<const bfrag*>(smem + boff);
        acc[nf] = __builtin_amdgcn_mfma_f32_16x16x32_bf16(ah, bh, acc[nf], 0, 0, 0);
      }
    }
#pragma unroll
    for (int i = 0; i < 4; ++i) {
      float sm = __expf(acc[0][i] * 0.125f) + __expf(acc[1][i] * 0.125f)
               + __expf(acc[2][i] * 0.125f) + __expf(acc[3][i] * 0.125f);
#pragma unroll
      for (int msk = 1; msk < 16; msk <<= 1) sm += __shfl_xor(sm, msk);
      if (l15 == 0) {
        const int m = mc * 128 + w * 16 + lg * 4 + i;
        psum[(size_t)(b * 16 + nt) * kN + m] = sm;
      }
    }
    __syncthreads();
  }
}

// ---- 8. adj emit: recompute Q·K^T, adj = go_adj + exp(s/8)*cinv -> single bf16 ----
__global__ __launch_bounds__(512) void k_adj_emit(const ushort* __restrict__ qb,
                                                  const ushort* __restrict__ kb,
                                                  const float* __restrict__ go_adj,
                                                  const float* __restrict__ psum,
                                                  ushort* __restrict__ adj) {
  const int mc = blockIdx.x, nt = blockIdx.y, b = blockIdx.z;
  __shared__ uint4 smem4[2304];  // 36 KiB: Q@0 (8K), K@8192 (16K); c32 overlay
  __shared__ float cinvs[128];
  char* smem = (char*)smem4;
  float* c32 = (float*)smem4;
  const int tid = threadIdx.x;
  const int lane = tid & 63, w = tid >> 6;
  const int wr = w >> 2, wc = w & 3;
  const int l15 = lane & 15, lg = lane >> 4;

  if (tid < 128) {
    const int m = mc * 128 + tid;
    float S = 0.f;
#pragma unroll
    for (int c = 0; c < 16; ++c) S += psum[(size_t)(b * 16 + c) * kN + m];
    cinvs[tid] = 1.f / S;
  }
  {
    const int r = tid >> 3, ch = tid & 7;
    const size_t g = (size_t)(b * kN + nt * 64 + r) * 64 + ch * 8;
    const unsigned off = (unsigned)(r * 128 + ch * 16) ^ (unsigned)((r & 7) << 4);
    *reinterpret_cast<uint4*>(smem + off) = *reinterpret_cast<const uint4*>(qb + g);
  }
#pragma unroll
  for (int p = 0; p < 2; ++p) {
    const int e = p * 512 + tid;
    const int c = e >> 3, ch = e & 7;
    const size_t g = (size_t)(b * kN + mc * 128 + c) * 64 + ch * 8;
    const unsigned off = (unsigned)(c * 128 + ch * 16) ^ (unsigned)((c & 7) << 4);
    *reinterpret_cast<uint4*>(smem + 8192 + off) = *reinterpret_cast<const uint4*>(kb + g);
  }
  __syncthreads();
  f32x4 acc[2][2] = {{{0.f,0.f,0.f,0.f},{0.f,0.f,0.f,0.f}},
                     {{0.f,0.f,0.f,0.f},{0.f,0.f,0.f,0.f}}};
#pragma unroll
  for (int ss = 0; ss < 2; ++ss) {
    bfrag ah[2], bh[2];
#pragma unroll
    for (int nf = 0; nf < 2; ++nf) {
      const int r = wr * 32 + nf * 16 + l15;
      const unsigned aoff = (unsigned)(r * 128 + ss * 64 + lg * 16) ^ (unsigned)((r & 7) << 4);
      ah[nf] = *reinterpret_cast<const bfrag*>(smem + aoff);
    }
#pragma unroll
    for (int mf = 0; mf < 2; ++mf) {
      const int c = wc * 32 + mf * 16 + l15;
      const unsigned boff = (unsigned)(c * 128 + ss * 64 + lg * 16) ^ (unsigned)((c & 7) << 4);
      bh[mf] = *reinterpret_cast<const bfrag*>(smem + 8192 + boff);
    }
#pragma unroll
    for (int nf = 0; nf < 2; ++nf)
#pragma unroll
      for (int mf = 0; mf < 2; ++mf)
        acc[nf][mf] = __builtin_amdgcn_mfma_f32_16x16x32_bf16(ah[nf], bh[mf], acc[nf][mf], 0, 0, 0);
  }
  __syncthreads();
#pragma unroll
  for (int mf = 0; mf < 2; ++mf) {
    const int mLoc = wc * 32 + mf * 16 + l15;
    const float I = cinvs[mLoc];
#pragma unroll
    for (int nf = 0; nf < 2; ++nf) {
#pragma unroll
      for (int i = 0; i < 4; ++i) {
        const int nLoc = wr * 32 + nf * 16 + lg * 4 + i;
        c32[nLoc * 132 + mLoc] = __expf(acc[nf][mf][i] * 0.125f) * I;
      }
    }
  }
  __syncthreads();
#pragma unroll
  for (int p = 0; p < 2; ++p) {
    const int e = p * 512 + tid;
    const int n = e >> 4, m0 = (e & 15) * 8;
    const float* cr = &c32[n * 132 + m0];
    const float* ga = &go_adj[(size_t)(nt * 64 + n) * kN + mc * 128 + m0];
    ushort hs[8];
#pragma unroll
    for (int j = 0; j < 8; ++j) hs[j] = f2bf(cr[j] + ga[j]);
    const size_t o = (size_t)(b * kN + nt * 64 + n) * kN + mc * 128 + m0;
    *reinterpret_cast<uint4*>(&adj[o]) = *reinterpret_cast<uint4*>(hs);
  }
}

// ---- T. transpose: f32 [16][1024][128] -> single bf16 [16][128][1024] ----
__global__ __launch_bounds__(256) void k_transp(const float* __restrict__ src,
                                                ushort* __restrict__ xt) {
  const int nt = blockIdx.x, b = blockIdx.y;
  __shared__ float tile[64][133];
  const int tid = threadIdx.x;
#pragma unroll
  for (int it = 0; it < 8; ++it) {
    int e = it * 256 + tid;
    int r = e >> 5, c4 = e & 31;
    float4 v = *reinterpret_cast<const float4*>(&src[(size_t)(b * kN + nt * 64 + r) * kC + c4 * 4]);
    *reinterpret_cast<float4*>(&tile[r][c4 * 4]) = v;
  }
  __syncthreads();
  const int cl = tid >> 3;
  const int chunk = tid & 7;
  const int n0 = chunk * 8;
#pragma unroll
  for (int cg = 0; cg < 4; ++cg) {
    const int c = cg * 32 + cl;
    const size_t obase = (size_t)(b * kC + c) * kN + nt * 64 + n0;
    ushort hs[8];
#pragma unroll
    for (int j = 0; j < 8; ++j) hs[j] = f2bf(tile[n0 + j][c]);
    *reinterpret_cast<uint4*>(&xt[obase]) = *reinterpret_cast<uint4*>(hs);
  }
}

// ---- 9. Y = alpha * adj @ X (- Zsub); single bf16, double-buffered LDS ----
__global__ __launch_bounds__(512) void k_adjmm_mfma(const ushort* __restrict__ adj,
                                                    const ushort* __restrict__ xt,
                                                    const float* __restrict__ Zsub,
                                                    float* __restrict__ Y, float alpha,
                                                    ushort* __restrict__ yt) {
  const int bid = blockIdx.x;
  const int swz = (bid & 7) * 32 + (bid >> 3);
  const int b = swz >> 4, rb = swz & 15;
  __shared__ uint4 smem4[3072];  // 48 KiB: buf[s] = {A@s*24576 (8K), B@s*24576+8192 (16K)}
  char* smem = (char*)smem4;
  float* c32 = (float*)smem4;    // epilogue overlay
  const int tid = threadIdx.x;
  const int lane = tid & 63, w = tid >> 6;
  const int wr = w >> 1, wc = w & 1;
  const int l15 = lane & 15, lg = lane >> 4;

  const int ra = tid >> 3, cha = tid & 7;
  const unsigned offA = (unsigned)(ra * 128 + cha * 16) ^ (unsigned)((ra & 7) << 4);
  const size_t gA = ((size_t)(b * kN + rb * 64 + ra)) * kN + cha * 8;
  const int cb0 = tid >> 3, cb1 = 64 + (tid >> 3);
  const unsigned offB0 = (unsigned)(cb0 * 128 + cha * 16) ^ (unsigned)((cb0 & 7) << 4);
  const unsigned offB1 = (unsigned)(cb1 * 128 + cha * 16) ^ (unsigned)((cb1 & 7) << 4);
  const size_t gB0 = ((size_t)b * kC + cb0) * kN + cha * 8;
  const size_t gB1 = ((size_t)b * kC + cb1) * kN + cha * 8;

  f32x4 acc[4] = {{0.f,0.f,0.f,0.f},{0.f,0.f,0.f,0.f},{0.f,0.f,0.f,0.f},{0.f,0.f,0.f,0.f}};

  // prologue: tile0 -> buf0; prefetch tile1 into regs
  uint4 pa  = *reinterpret_cast<const uint4*>(adj + gA);
  uint4 pb0 = *reinterpret_cast<const uint4*>(xt + gB0);
  uint4 pb1 = *reinterpret_cast<const uint4*>(xt + gB1);
  *reinterpret_cast<uint4*>(smem + offA)         = pa;
  *reinterpret_cast<uint4*>(smem + 8192 + offB0) = pb0;
  *reinterpret_cast<uint4*>(smem + 8192 + offB1) = pb1;
  pa  = *reinterpret_cast<const uint4*>(adj + gA + 64);
  pb0 = *reinterpret_cast<const uint4*>(xt + gB0 + 64);
  pb1 = *reinterpret_cast<const uint4*>(xt + gB1 + 64);
  __syncthreads();

  for (int kt = 0; kt < 16; ++kt) {
    const unsigned bufC = (unsigned)(kt & 1) * 24576;
    const unsigned bufN = (unsigned)((kt + 1) & 1) * 24576;
    if (kt < 15) {  // write next tile into the other buffer; prefetch kt+2
      *reinterpret_cast<uint4*>(smem + bufN + offA)         = pa;
      *reinterpret_cast<uint4*>(smem + bufN + 8192 + offB0) = pb0;
      *reinterpret_cast<uint4*>(smem + bufN + 8192 + offB1) = pb1;
      if (kt < 14) {
        const int k2 = (kt + 2) * 64;
        pa  = *reinterpret_cast<const uint4*>(adj + gA + k2);
        pb0 = *reinterpret_cast<const uint4*>(xt + gB0 + k2);
        pb1 = *reinterpret_cast<const uint4*>(xt + gB1 + k2);
      }
    }
#pragma unroll
    for (int ss = 0; ss < 2; ++ss) {
      const int r = wr * 16 + l15;
      const unsigned aoff = ((unsigned)(r * 128 + ss * 64 + lg * 16) ^ (unsigned)((r & 7) << 4)) + bufC;
      bfrag ah = *reinterpret_cast<const bfrag*>(smem + aoff);
      bfrag bh[4];
#pragma unroll
      for (int ct = 0; ct < 4; ++ct) {
        const int c = wc * 64 + ct * 16 + l15;
        const unsigned boff = ((unsigned)(c * 128 + ss * 64 + lg * 16) ^ (unsigned)((c & 7) << 4)) + bufC;
        bh[ct] = *reinterpret_cast<const bfrag*>(smem + 8192 + boff);
      }
#pragma unroll
      for (int ct = 0; ct < 4; ++ct)
        acc[ct] = __builtin_amdgcn_mfma_f32_16x16x32_bf16(ah, bh[ct], acc[ct], 0, 0, 0);
    }
    __syncthreads();
  }
  const int orow = rb * 64 + wr * 16 + lg * 4;
#pragma unroll
  for (int ct = 0; ct < 4; ++ct) {
    const int ocol = wc * 64 + ct * 16 + l15;
#pragma unroll
    for (int i = 0; i < 4; ++i) {
      const size_t idx = ((size_t)(b * kN + orow + i)) * kC + ocol;
      float v = alpha * acc[ct][i];
      if (Zsub) v -= Zsub[idx];
      Y[idx] = v;
      if (yt) c32[(wr * 16 + lg * 4 + i) * 132 + ocol] = v;
    }
  }
  if (yt) {
    __syncthreads();
    const int c = tid >> 2, nch = tid & 3;
    const int n0 = nch * 16;
    ushort hs[16];
#pragma unroll
    for (int j = 0; j < 16; ++j) hs[j] = f2bf(c32[(n0 + j) * 132 + c]);
    const size_t obase = (size_t)(b * kC + c) * kN + rb * 64 + n0;
    *reinterpret_cast<uint4*>(&yt[obase]) = *reinterpret_cast<uint4*>(hs);
    *reinterpret_cast<uint4*>(&yt[obase + 8]) = *reinterpret_cast<uint4*>(hs + 8);
  }
}

// ---- 10. z = x@th0 + tcur@th1 + tnext@th2 + x ; emits per-row sum/sumsq ----
__global__ __launch_bounds__(256) void k_theta(const float* __restrict__ x,
                                               const float* __restrict__ tcur,
                                               const float* __restrict__ tnext,
                                               const float* __restrict__ theta,
                                               float* __restrict__ z,
                                               float* __restrict__ sumz,
                                               float* __restrict__ sumzz) {
  __shared__ float a_s[32 * 68];
  __shared__ float w_s[32 * 128];
  const int row0 = blockIdx.x * 32;
  const int tid = threadIdx.x;
  const int tr = tid >> 5, tc = tid & 31;
  const int r0 = tr * 4, c0 = tc * 4;
  float acc[4][4] = {};
  const float* srcs[3] = {x, tcur, tnext};
  for (int s = 0; s < 3; ++s) {
    const float* A = srcs[s];
    for (int kc = 0; kc < 4; ++kc) {
      const int k0 = kc * 32;
      __syncthreads();
      {
        int r = tid >> 3, kk4 = tid & 7;
        float4 v = *reinterpret_cast<const float4*>(&A[(size_t)(row0 + r) * kC + k0 + kk4 * 4]);
        *reinterpret_cast<float4*>(&a_s[r * 68 + kk4 * 4]) = v;
      }
#pragma unroll
      for (int it = 0; it < 4; ++it) {
        int e4 = it * 256 + tid;
        int kk = e4 >> 5, d4 = e4 & 31;
        float4 v = *reinterpret_cast<const float4*>(
            &theta[(size_t)s * 16384 + (size_t)(k0 + kk) * kC + d4 * 4]);
        *reinterpret_cast<float4*>(&w_s[kk * 128 + d4 * 4]) = v;
      }
      __syncthreads();
#pragma unroll 8
      for (int k = 0; k < 32; ++k) {
        float a[4];
#pragma unroll
        for (int i = 0; i < 4; ++i) a[i] = a_s[(r0 + i) * 68 + k];
        float4 b4 = *reinterpret_cast<float4*>(&w_s[k * 128 + c0]);
        float bj[4] = {b4.x, b4.y, b4.z, b4.w};
#pragma unroll
        for (int i = 0; i < 4; ++i)
#pragma unroll
          for (int j = 0; j < 4; ++j) acc[i][j] += a[i] * bj[j];
      }
    }
  }
  float rs[4], rq[4];
#pragma unroll
  for (int i = 0; i < 4; ++i) {
    size_t idx = (size_t)(row0 + r0 + i) * kC + c0;
    float4 xv = *reinterpret_cast<const float4*>(&x[idx]);
    float4 o = {acc[i][0] + xv.x, acc[i][1] + xv.y, acc[i][2] + xv.z, acc[i][3] + xv.w};
    *reinterpret_cast<float4*>(&z[idx]) = o;
    rs[i] = o.x + o.y + o.z + o.w;
    rq[i] = o.x * o.x + o.y * o.y + o.z * o.z + o.w * o.w;
  }
#pragma unroll
  for (int m = 1; m < 32; m <<= 1) {
#pragma unroll
    for (int i = 0; i < 4; ++i) { rs[i] += __shfl_xor(rs[i], m); rq[i] += __shfl_xor(rq[i], m); }
  }
  if (tc == 0) {
#pragma unroll
    for (int i = 0; i < 4; ++i) {
      sumz[row0 + r0 + i] = rs[i];
      sumzz[row0 + r0 + i] = rq[i];
    }
  }
}

// ---- 11. per-node BN (stats precomputed) + relu + dot(w_out) -> out ----
__global__ __launch_bounds__(256) void k_final(const float* __restrict__ z,
                                               const float* __restrict__ sumz,
                                               const float* __restrict__ sumzz,
                                               const float* __restrict__ g4,
                                               const float* __restrict__ b4v,
                                               const float* __restrict__ w_out,
                                               const float* __restrict__ b_out,
                                               float* __restrict__ out) {
  const int n = blockIdx.x;
  const int tid = threadIdx.x;
  __shared__ float sscale, sshift;
  if (tid < 16) {
    float a = sumz[tid * kN + n];
    float q = sumzz[tid * kN + n];
#pragma unroll
    for (int m = 1; m < 16; m <<= 1) { a += __shfl_xor(a, m); q += __shfl_xor(q, m); }
    if (tid == 0) {
      float mean = a * (1.f / 2048.f);
      float var = fmaxf(q * (1.f / 2048.f) - mean * mean, 0.f);
      float inv = rsqrtf(var + kEPS);
      float gg = g4[n];
      sscale = inv * gg;
      sshift = b4v[n] - mean * inv * gg;
    }
  }
  __syncthreads();
  const float scale = sscale, shift = sshift;
  const int b = tid >> 4, c0 = (tid & 15) * 8;
  float p = 0.f;
#pragma unroll
  for (int j = 0; j < 8; ++j) {
    float v = z[(size_t)(b * kN + n) * kC + c0 + j] * scale + shift;
    v = fmaxf(v, 0.f);
    p += v * w_out[c0 + j];
  }
  for (int o = 8; o > 0; o >>= 1) p += __shfl_down(p, o, 16);
  if ((tid & 15) == 0) out[b * kN + n] = p + b_out[0];
}

extern "C" void kernel_launch(void* const* d_in, const int* in_sizes, int n_in,
                              void* d_out, int out_size, void* d_ws, size_t ws_size,
                              hipStream_t stream) {
  const int*   data = (const int*)d_in[0];
  const float* node_features = (const float*)d_in[1];
  const float* go_adj = (const float*)d_in[2];
  const float* emb  = (const float*)d_in[4];
  const float* w_go = (const float*)d_in[5];
  const float* b_go = (const float*)d_in[6];
  const float* wq   = (const float*)d_in[7];
  const float* wk   = (const float*)d_in[8];
  const float* theta= (const float*)d_in[9];
  const float* g1   = (const float*)d_in[10];
  const float* b1   = (const float*)d_in[11];
  const float* g3   = (const float*)d_in[12];
  const float* b3   = (const float*)d_in[13];
  const float* g4   = (const float*)d_in[14];
  const float* b4   = (const float*)d_in[15];
  const float* w_out= (const float*)d_in[16];
  const float* b_out= (const float*)d_in[17];

  float* ws = (float*)d_ws;
  float* featpart = ws + OFF_FEATPART;
  float* m1t   = ws + OFF_M1;
  float* x     = ws + OFF_X;
  float* z     = ws + OFF_Z;
  float* tcur  = ws + OFF_TCUR;
  float* tnext = ws + OFF_TNEXT;
  float* gopart= ws + OFF_GOPART;
  float* psum  = ws + OFF_PSUM;
  float* sumz  = ws + OFF_SUMZ;
  float* sumzz = ws + OFF_SUMZZ;
  ushort* adj  = (ushort*)(ws + OFF_ADJ);
  ushort* xt   = (ushort*)(ws + OFF_XT);
  ushort* qb   = (ushort*)(ws + OFF_Q);
  ushort* kb   = (ushort*)(ws + OFF_K);
  ushort* tt   = (ushort*)(ws + OFF_TT);

  k_embsum<<<dim3(16, 64), 256, 0, stream>>>(data, emb, featpart);
  k_bn_feat<<<16, 256, 0, stream>>>(featpart, data, g1, b1, m1t);
  k_go_gemm2<<<dim3(64, 4), 256, 0, stream>>>(m1t, w_go, gopart);
  k_go_bn<<<1024, 256, 0, stream>>>(gopart, b_go, node_features, g3, b3, x);
  k_qkgen<<<512, 256, 0, stream>>>(x, wq, wk, qb, kb);
  k_att_stats<<<dim3(16, 16, 2), 512, 0, stream>>>(qb, kb, psum);
  k_adj_emit<<<dim3(8, 16, 16), 512, 0, stream>>>(qb, kb, go_adj, psum, adj);
  k_transp<<<dim3(16, 16), 256, 0, stream>>>(x, xt);
  k_adjmm_mfma<<<256, 512, 0, stream>>>(adj, xt, nullptr, tcur, 1.0f, tt);
  k_adjmm_mfma<<<256, 512, 0, stream>>>(adj, tt, x, tnext, 2.0f, nullptr);
  k_theta<<<512, 256, 0, stream>>>(x, tcur, tnext, theta, z, sumz, sumzz);
  k_final<<<1024, 256, 0, stream>>>(z, sumz, sumzz, g4, b4, w_out, b_out, (float*)d_out);
}

// Round 16
// 173.736 us; speedup vs baseline: 1.9303x; 1.0265x over previous
//
#include <hip/hip_runtime.h>

namespace {
constexpr int kB = 16;
constexpr int kMAXLEN = 1024;
constexpr int kPE = 256;
constexpr int kN = 1024;
constexpr int kEMB = 256;
constexpr int kC = 128;
constexpr float kEPS = 1e-5f;

// workspace offsets in floats
constexpr size_t OFF_FEATPART = 0;                         // 16*64*256 = 262144
constexpr size_t OFF_M1       = 262144;                    // 512*16
constexpr size_t OFF_X        = 270336;                    // 16*1024*128
constexpr size_t OFF_Z        = OFF_X    + 2097152;
constexpr size_t OFF_TCUR     = OFF_Z    + 2097152;
constexpr size_t OFF_TNEXT    = OFF_TCUR + 2097152;
constexpr size_t OFF_GOPART   = OFF_TNEXT+ 2097152;        // 4*16*65536
constexpr size_t OFF_PSUM     = OFF_GOPART + 4194304;      // 16*16*1024
constexpr size_t OFF_SUMZ     = OFF_PSUM + 262144;
constexpr size_t OFF_SUMZZ    = OFF_SUMZ + 16384;
constexpr size_t OFF_ADJ      = OFF_SUMZZ + 16384;         // 16.8M bf16
constexpr size_t OFF_XT       = OFF_ADJ  + 8388608;
constexpr size_t OFF_Q        = OFF_XT   + 1048576;
constexpr size_t OFF_K        = OFF_Q    + 524288;
constexpr size_t OFF_TT       = OFF_K    + 524288;

typedef __attribute__((ext_vector_type(8))) short bfrag;
typedef __attribute__((ext_vector_type(4))) float f32x4;

__device__ inline ushort f2bf(float f) {
  unsigned u = __float_as_uint(f);
  unsigned r = (u + 0x7FFFu + ((u >> 16) & 1u)) >> 16;  // RNE
  return (ushort)r;
}
} // namespace

// ---- 1. embedding gather partial sums: featpart[b][chunk64][e] ----
__global__ __launch_bounds__(256) void k_embsum(const int* __restrict__ data,
                                                const float* __restrict__ emb,
                                                float* __restrict__ featpart) {
  const int b = blockIdx.x, ch = blockIdx.y;   // 16 x 64
  const int e = threadIdx.x;                   // 256
  const int* row = data + b * (kMAXLEN + kPE) + ch * 16;
  float acc = 0.f;
#pragma unroll 4
  for (int l = 0; l < 16; ++l) {
    acc += emb[(size_t)row[l] * kEMB + e];
  }
  featpart[((b * 64 + ch) << 8) + e] = acc;
}

// ---- 2. BN over batch -> m1t (512,16). 16 blocks x 32 j, 8 lanes/j ----
__global__ __launch_bounds__(256) void k_bn_feat(const float* __restrict__ featpart,
                                                 const int* __restrict__ data,
                                                 const float* __restrict__ g1,
                                                 const float* __restrict__ b1,
                                                 float* __restrict__ m1t) {
  const int tid = threadIdx.x;
  const int jl = tid >> 3, part = tid & 7;
  const int j = blockIdx.x * 32 + jl;
  float v[kB];
  if (j < kPE) {
#pragma unroll
    for (int b = 0; b < kB; ++b) {
      float s = 0.f;
      const int ch0 = part * 8;
#pragma unroll
      for (int ch = 0; ch < 8; ++ch)
        s += featpart[((b * 64 + ch0 + ch) << 8) + j];
      v[b] = s;
    }
  } else {
#pragma unroll
    for (int b = 0; b < kB; ++b)
      v[b] = (part == 0) ? (float)data[b * (kMAXLEN + kPE) + kMAXLEN + (j - kPE)] : 0.f;
  }
#pragma unroll
  for (int m = 1; m < 8; m <<= 1) {
#pragma unroll
    for (int b = 0; b < kB; ++b) v[b] += __shfl_xor(v[b], m);
  }
  const float pe = (j < kPE) ? sinf((float)j) : sinf((float)(j - kPE));
#pragma unroll
  for (int b = 0; b < kB; ++b)
    v[b] = (j < kPE) ? (v[b] * (1.f / 1024.f) + pe) : (v[b] + pe);
  float s = 0.f;
#pragma unroll
  for (int b = 0; b < kB; ++b) s += v[b];
  const float mean = s * (1.f / kB);
  float s2 = 0.f;
#pragma unroll
  for (int b = 0; b < kB; ++b) { float d = v[b] - mean; s2 += d * d; }
  const float inv = rsqrtf(s2 * (1.f / kB) + kEPS);
  if (part == 0) {
    const float g = g1[j], bb = b1[j];
    float o[kB];
#pragma unroll
    for (int b = 0; b < kB; ++b) o[b] = (v[b] - mean) * inv * g + bb;
#pragma unroll
    for (int q = 0; q < 4; ++q)
      *reinterpret_cast<float4*>(&m1t[j * kB + q * 4]) =
          *reinterpret_cast<float4*>(&o[q * 4]);
  }
}

// ---- 3a. split-K GEMM, 4 k-slices (m1t via SGPR broadcast) ----
__global__ __launch_bounds__(256) void k_go_gemm2(const float* __restrict__ m1t,
                                                  const float* __restrict__ w_go,
                                                  float* __restrict__ part) {
  const int c0 = blockIdx.x * 1024 + threadIdx.x * 4;
  const int k0 = blockIdx.y * 128;
  float4 acc[kB];
#pragma unroll
  for (int b = 0; b < kB; ++b) acc[b] = make_float4(0.f, 0.f, 0.f, 0.f);
#pragma unroll 4
  for (int k = 0; k < 128; ++k) {
    const float4 w = *reinterpret_cast<const float4*>(&w_go[(size_t)(k0 + k) * 65536 + c0]);
    const float* mrow = m1t + (size_t)(k0 + k) * kB;
#pragma unroll
    for (int b = 0; b < kB; ++b) {
      const float m = mrow[b];
      acc[b].x += m * w.x; acc[b].y += m * w.y;
      acc[b].z += m * w.z; acc[b].w += m * w.w;
    }
  }
  const size_t kb16 = (size_t)blockIdx.y * kB;
#pragma unroll
  for (int b = 0; b < kB; ++b) {
    *reinterpret_cast<float4*>(&part[(kb16 + b) * 65536 + c0]) = acc[b];
  }
}

// ---- 3b+4 fused. per-node: reduce 4 go partials + bias/relu, nf concat, BN -> x ----
__global__ __launch_bounds__(256) void k_go_bn(const float* __restrict__ part,
                                               const float* __restrict__ b_go,
                                               const float* __restrict__ nf,
                                               const float* __restrict__ g3,
                                               const float* __restrict__ b3,
                                               float* __restrict__ x) {
  const int n = blockIdx.x;
  const int tid = threadIdx.x;
  __shared__ float nfs[64];
  if (tid < 64) nfs[tid] = nf[n * 64 + tid];
  float val[4];
  float s = 0.f, s2 = 0.f;
#pragma unroll
  for (int i = 0; i < 4; ++i) {
    const int e = i * 256 + tid;
    const int b = e >> 6, c = e & 63;
    float a = part[(size_t)b * 65536 + n * 64 + c];
#pragma unroll
    for (int kb = 1; kb < 4; ++kb)
      a += part[(size_t)(kb * kB + b) * 65536 + n * 64 + c];
    a = fmaxf(a + b_go[n * 64 + c], 0.f);
    val[i] = a;
    s += a; s2 += a * a;
  }
  __syncthreads();
  if (tid < 64) {
    const float v = nfs[tid];
    s += 16.f * v; s2 += 16.f * v * v;
  }
  for (int o = 32; o > 0; o >>= 1) { s += __shfl_down(s, o); s2 += __shfl_down(s2, o); }
  __shared__ float ls[4], ls2[4];
  __shared__ float sscale, sshift;
  const int w = tid >> 6;
  if ((tid & 63) == 0) { ls[w] = s; ls2[w] = s2; }
  __syncthreads();
  if (tid == 0) {
    float S = ls[0] + ls[1] + ls[2] + ls[3];
    float S2 = ls2[0] + ls2[1] + ls2[2] + ls2[3];
    float mean = S * (1.f / 2048.f);
    float var = fmaxf(S2 * (1.f / 2048.f) - mean * mean, 0.f);
    float inv = rsqrtf(var + kEPS);
    float gg = g3[n];
    sscale = inv * gg;
    sshift = b3[n] - mean * inv * gg;
  }
  __syncthreads();
  const float scale = sscale, shift = sshift;
#pragma unroll
  for (int i = 0; i < 4; ++i) {
    const int e = i * 256 + tid;
    const int b = e >> 6, c = e & 63;
    x[((size_t)(b * kN + n)) * kC + c] = val[i] * scale + shift;
  }
#pragma unroll
  for (int i = 0; i < 4; ++i) {
    const int e = i * 256 + tid;
    const int b = e >> 6, c = e & 63;
    x[((size_t)(b * kN + n)) * kC + 64 + c] = nfs[c] * scale + shift;
  }
}

// ---- 5. q/k projections + fused x^T bf16 emit ----
__global__ __launch_bounds__(256) void k_qkgen(const float* __restrict__ x,
                                               const float* __restrict__ wq,
                                               const float* __restrict__ wk,
                                               ushort* __restrict__ qb,
                                               ushort* __restrict__ kb,
                                               ushort* __restrict__ xt) {
  __shared__ float a_s[32 * 68];
  __shared__ float w_s[32 * 128];
  const int row0 = blockIdx.x * 32;
  const int bb = row0 >> 10, n0 = row0 & 1023;
  const int tid = threadIdx.x;
  const int tr = tid >> 5, tc = tid & 31;
  const int r0 = tr * 4, c0 = tc * 4;
  float acc[4][4] = {};
  for (int kc = 0; kc < 4; ++kc) {
    const int k0 = kc * 32;
    __syncthreads();
    {
      int r = tid >> 3, kk4 = tid & 7;
      float4 v = *reinterpret_cast<const float4*>(&x[(size_t)(row0 + r) * kC + k0 + kk4 * 4]);
      *reinterpret_cast<float4*>(&a_s[r * 68 + kk4 * 4]) = v;
    }
    for (int it = 0; it < 16; ++it) {
      int e = it * 256 + tid;
      int kk = e >> 7, h2 = e & 127;
      int c = k0 + kk;
      float v = (h2 < 64) ? wq[c * 64 + h2] : wk[c * 64 + (h2 - 64)];
      w_s[kk * 128 + h2] = v;
    }
    __syncthreads();
    // fused transpose emit: xt[b][k0+kk][n0+r] = bf16(a_s[r][kk])
#pragma unroll
    for (int q = 0; q < 4; ++q) {
      const int e = q * 256 + tid;
      const int kk = e >> 5, r = e & 31;
      xt[(size_t)(bb * kC + k0 + kk) * kN + n0 + r] = f2bf(a_s[r * 68 + kk]);
    }
#pragma unroll 8
    for (int k = 0; k < 32; ++k) {
      float a[4];
#pragma unroll
      for (int i = 0; i < 4; ++i) a[i] = a_s[(r0 + i) * 68 + k];
      float4 b4 = *reinterpret_cast<float4*>(&w_s[k * 128 + c0]);
      float bj[4] = {b4.x, b4.y, b4.z, b4.w};
#pragma unroll
      for (int i = 0; i < 4; ++i)
#pragma unroll
        for (int j = 0; j < 4; ++j) acc[i][j] += a[i] * bj[j];
    }
  }
  const bool isq = (c0 < 64);
  const int h0 = isq ? c0 : (c0 - 64);
  ushort* oh = isq ? qb : kb;
#pragma unroll
  for (int i = 0; i < 4; ++i) {
    ushort hs[4];
#pragma unroll
    for (int j = 0; j < 4; ++j) hs[j] = f2bf(acc[i][j]);
    const size_t o = (size_t)(row0 + r0 + i) * 64 + h0;
    *reinterpret_cast<ushort4*>(&oh[o]) = *reinterpret_cast<ushort4*>(hs);
  }
}

// ---- 6. att sum-stats via MFMA (single bf16), K double-buffered LDS ----
__global__ __launch_bounds__(512) void k_att_stats(const ushort* __restrict__ qb,
                                                   const ushort* __restrict__ kb,
                                                   float* __restrict__ psum) {
  const int nt = blockIdx.x, b = blockIdx.y;
  const int mc0 = blockIdx.z * 4;
  __shared__ uint4 smem4[2560];  // 40 KiB: Q@0 (8K), K bufs @8192 + sel*16384
  char* smem = (char*)smem4;
  const int tid = threadIdx.x;
  const int lane = tid & 63, w = tid >> 6;
  const int l15 = lane & 15, lg = lane >> 4;

  {  // stage Q once
    const int r = tid >> 3, ch = tid & 7;
    const size_t g = (size_t)(b * kN + nt * 64 + r) * 64 + ch * 8;
    const unsigned off = (unsigned)(r * 128 + ch * 16) ^ (unsigned)((r & 7) << 4);
    *reinterpret_cast<uint4*>(smem + off) = *reinterpret_cast<const uint4*>(qb + g);
  }

  const int c0s = tid >> 3, c1s = 64 + (tid >> 3);
  const int chs = tid & 7;
  const unsigned offK0 = (unsigned)(c0s * 128 + chs * 16) ^ (unsigned)((c0s & 7) << 4);
  const unsigned offK1 = (unsigned)(c1s * 128 + chs * 16) ^ (unsigned)((c1s & 7) << 4);
  const size_t gK0 = (size_t)(b * kN + mc0 * 128 + c0s) * 64 + chs * 8;
  const size_t gK1 = (size_t)(b * kN + mc0 * 128 + c1s) * 64 + chs * 8;

  uint4 ph0 = *reinterpret_cast<const uint4*>(kb + gK0);
  uint4 ph1 = *reinterpret_cast<const uint4*>(kb + gK1);
  *reinterpret_cast<uint4*>(smem + 8192 + offK0) = ph0;
  *reinterpret_cast<uint4*>(smem + 8192 + offK1) = ph1;
  {
    const size_t k1 = (size_t)128 * 64;
    ph0 = *reinterpret_cast<const uint4*>(kb + gK0 + k1);
    ph1 = *reinterpret_cast<const uint4*>(kb + gK1 + k1);
  }
  __syncthreads();

  for (int it = 0; it < 4; ++it) {
    const int mc = mc0 + it;
    const unsigned bufC = 8192 + (unsigned)(it & 1) * 16384;
    const unsigned bufN = 8192 + (unsigned)((it + 1) & 1) * 16384;
    if (it < 3) {
      *reinterpret_cast<uint4*>(smem + bufN + offK0) = ph0;
      *reinterpret_cast<uint4*>(smem + bufN + offK1) = ph1;
      if (it < 2) {
        const size_t k2 = (size_t)(it + 2) * 128 * 64;
        ph0 = *reinterpret_cast<const uint4*>(kb + gK0 + k2);
        ph1 = *reinterpret_cast<const uint4*>(kb + gK1 + k2);
      }
    }
    f32x4 acc[4] = {{0.f,0.f,0.f,0.f},{0.f,0.f,0.f,0.f},{0.f,0.f,0.f,0.f},{0.f,0.f,0.f,0.f}};
#pragma unroll
    for (int ss = 0; ss < 2; ++ss) {
      const int r = w * 16 + l15;
      const unsigned aoff = ((unsigned)(r * 128 + ss * 64 + lg * 16) ^ (unsigned)((r & 7) << 4)) + bufC;
      bfrag ah = *reinterpret_cast<const bfrag*>(smem + aoff);
#pragma unroll
      for (int nf = 0; nf < 4; ++nf) {
        const int c = nf * 16 + l15;
        const unsigned boff = (unsigned)(c * 128 + ss * 64 + lg * 16) ^ (unsigned)((c & 7) << 4);
        bfrag bh = *reinterpret_cast<const bfrag*>(smem + boff);
        acc[nf] = __builtin_amdgcn_mfma_f32_16x16x32_bf16(ah, bh, acc[nf], 0, 0, 0);
      }
    }
#pragma unroll
    for (int i = 0; i < 4; ++i) {
      float sm = __expf(acc[0][i] * 0.125f) + __expf(acc[1][i] * 0.125f)
               + __expf(acc[2][i] * 0.125f) + __expf(acc[3][i] * 0.125f);
#pragma unroll
      for (int msk = 1; msk < 16; msk <<= 1) sm += __shfl_xor(sm, msk);
      if (l15 == 0) {
        const int m = mc * 128 + w * 16 + lg * 4 + i;
        psum[(size_t)(b * 16 + nt) * kN + m] = sm;
      }
    }
    __syncthreads();
  }
}

// ---- 8. adj emit: recompute Q·K^T, adj = go_adj + exp(s/8)*cinv -> single bf16 ----
__global__ __launch_bounds__(512) void k_adj_emit(const ushort* __restrict__ qb,
                                                  const ushort* __restrict__ kb,
                                                  const float* __restrict__ go_adj,
                                                  const float* __restrict__ psum,
                                                  ushort* __restrict__ adj) {
  const int mc = blockIdx.x, nt = blockIdx.y, b = blockIdx.z;
  __shared__ uint4 smem4[2304];  // 36 KiB: Q@0 (8K), K@8192 (16K); c32 overlay
  __shared__ float cinvs[128];
  char* smem = (char*)smem4;
  float* c32 = (float*)smem4;
  const int tid = threadIdx.x;
  const int lane = tid & 63, w = tid >> 6;
  const int wr = w >> 2, wc = w & 3;
  const int l15 = lane & 15, lg = lane >> 4;

  if (tid < 128) {
    const int m = mc * 128 + tid;
    float S = 0.f;
#pragma unroll
    for (int c = 0; c < 16; ++c) S += psum[(size_t)(b * 16 + c) * kN + m];
    cinvs[tid] = 1.f / S;
  }
  {
    const int r = tid >> 3, ch = tid & 7;
    const size_t g = (size_t)(b * kN + nt * 64 + r) * 64 + ch * 8;
    const unsigned off = (unsigned)(r * 128 + ch * 16) ^ (unsigned)((r & 7) << 4);
    *reinterpret_cast<uint4*>(smem + off) = *reinterpret_cast<const uint4*>(qb + g);
  }
#pragma unroll
  for (int p = 0; p < 2; ++p) {
    const int e = p * 512 + tid;
    const int c = e >> 3, ch = e & 7;
    const size_t g = (size_t)(b * kN + mc * 128 + c) * 64 + ch * 8;
    const unsigned off = (unsigned)(c * 128 + ch * 16) ^ (unsigned)((c & 7) << 4);
    *reinterpret_cast<uint4*>(smem + 8192 + off) = *reinterpret_cast<const uint4*>(kb + g);
  }
  __syncthreads();
  f32x4 acc[2][2] = {{{0.f,0.f,0.f,0.f},{0.f,0.f,0.f,0.f}},
                     {{0.f,0.f,0.f,0.f},{0.f,0.f,0.f,0.f}}};
#pragma unroll
  for (int ss = 0; ss < 2; ++ss) {
    bfrag ah[2], bh[2];
#pragma unroll
    for (int nf = 0; nf < 2; ++nf) {
      const int r = wr * 32 + nf * 16 + l15;
      const unsigned aoff = (unsigned)(r * 128 + ss * 64 + lg * 16) ^ (unsigned)((r & 7) << 4);
      ah[nf] = *reinterpret_cast<const bfrag*>(smem + aoff);
    }
#pragma unroll
    for (int mf = 0; mf < 2; ++mf) {
      const int c = wc * 32 + mf * 16 + l15;
      const unsigned boff = (unsigned)(c * 128 + ss * 64 + lg * 16) ^ (unsigned)((c & 7) << 4);
      bh[mf] = *reinterpret_cast<const bfrag*>(smem + 8192 + boff);
    }
#pragma unroll
    for (int nf = 0; nf < 2; ++nf)
#pragma unroll
      for (int mf = 0; mf < 2; ++mf)
        acc[nf][mf] = __builtin_amdgcn_mfma_f32_16x16x32_bf16(ah[nf], bh[mf], acc[nf][mf], 0, 0, 0);
  }
  __syncthreads();
#pragma unroll
  for (int mf = 0; mf < 2; ++mf) {
    const int mLoc = wc * 32 + mf * 16 + l15;
    const float I = cinvs[mLoc];
#pragma unroll
    for (int nf = 0; nf < 2; ++nf) {
#pragma unroll
      for (int i = 0; i < 4; ++i) {
        const int nLoc = wr * 32 + nf * 16 + lg * 4 + i;
        c32[nLoc * 132 + mLoc] = __expf(acc[nf][mf][i] * 0.125f) * I;
      }
    }
  }
  __syncthreads();
#pragma unroll
  for (int p = 0; p < 2; ++p) {
    const int e = p * 512 + tid;
    const int n = e >> 4, m0 = (e & 15) * 8;
    const float* cr = &c32[n * 132 + m0];
    const float* ga = &go_adj[(size_t)(nt * 64 + n) * kN + mc * 128 + m0];
    ushort hs[8];
#pragma unroll
    for (int j = 0; j < 8; ++j) hs[j] = f2bf(cr[j] + ga[j]);
    const size_t o = (size_t)(b * kN + nt * 64 + n) * kN + mc * 128 + m0;
    *reinterpret_cast<uint4*>(&adj[o]) = *reinterpret_cast<uint4*>(hs);
  }
}

// ---- 9. Y = alpha * adj @ X (- Zsub); single bf16, double-buffered LDS ----
__global__ __launch_bounds__(512) void k_adjmm_mfma(const ushort* __restrict__ adj,
                                                    const ushort* __restrict__ xt,
                                                    const float* __restrict__ Zsub,
                                                    float* __restrict__ Y, float alpha,
                                                    ushort* __restrict__ yt) {
  const int bid = blockIdx.x;
  const int swz = (bid & 7) * 32 + (bid >> 3);
  const int b = swz >> 4, rb = swz & 15;
  __shared__ uint4 smem4[3072];  // 48 KiB: buf[s] = {A@s*24576 (8K), B@s*24576+8192 (16K)}
  char* smem = (char*)smem4;
  float* c32 = (float*)smem4;    // epilogue overlay
  const int tid = threadIdx.x;
  const int lane = tid & 63, w = tid >> 6;
  const int wr = w >> 1, wc = w & 1;
  const int l15 = lane & 15, lg = lane >> 4;

  const int ra = tid >> 3, cha = tid & 7;
  const unsigned offA = (unsigned)(ra * 128 + cha * 16) ^ (unsigned)((ra & 7) << 4);
  const size_t gA = ((size_t)(b * kN + rb * 64 + ra)) * kN + cha * 8;
  const int cb0 = tid >> 3, cb1 = 64 + (tid >> 3);
  const unsigned offB0 = (unsigned)(cb0 * 128 + cha * 16) ^ (unsigned)((cb0 & 7) << 4);
  const unsigned offB1 = (unsigned)(cb1 * 128 + cha * 16) ^ (unsigned)((cb1 & 7) << 4);
  const size_t gB0 = ((size_t)b * kC + cb0) * kN + cha * 8;
  const size_t gB1 = ((size_t)b * kC + cb1) * kN + cha * 8;

  f32x4 acc[4] = {{0.f,0.f,0.f,0.f},{0.f,0.f,0.f,0.f},{0.f,0.f,0.f,0.f},{0.f,0.f,0.f,0.f}};

  uint4 pa  = *reinterpret_cast<const uint4*>(adj + gA);
  uint4 pb0 = *reinterpret_cast<const uint4*>(xt + gB0);
  uint4 pb1 = *reinterpret_cast<const uint4*>(xt + gB1);
  *reinterpret_cast<uint4*>(smem + offA)         = pa;
  *reinterpret_cast<uint4*>(smem + 8192 + offB0) = pb0;
  *reinterpret_cast<uint4*>(smem + 8192 + offB1) = pb1;
  pa  = *reinterpret_cast<const uint4*>(adj + gA + 64);
  pb0 = *reinterpret_cast<const uint4*>(xt + gB0 + 64);
  pb1 = *reinterpret_cast<const uint4*>(xt + gB1 + 64);
  __syncthreads();

  for (int kt = 0; kt < 16; ++kt) {
    const unsigned bufC = (unsigned)(kt & 1) * 24576;
    const unsigned bufN = (unsigned)((kt + 1) & 1) * 24576;
    if (kt < 15) {
      *reinterpret_cast<uint4*>(smem + bufN + offA)         = pa;
      *reinterpret_cast<uint4*>(smem + bufN + 8192 + offB0) = pb0;
      *reinterpret_cast<uint4*>(smem + bufN + 8192 + offB1) = pb1;
      if (kt < 14) {
        const int k2 = (kt + 2) * 64;
        pa  = *reinterpret_cast<const uint4*>(adj + gA + k2);
        pb0 = *reinterpret_cast<const uint4*>(xt + gB0 + k2);
        pb1 = *reinterpret_cast<const uint4*>(xt + gB1 + k2);
      }
    }
#pragma unroll
    for (int ss = 0; ss < 2; ++ss) {
      const int r = wr * 16 + l15;
      const unsigned aoff = ((unsigned)(r * 128 + ss * 64 + lg * 16) ^ (unsigned)((r & 7) << 4)) + bufC;
      bfrag ah = *reinterpret_cast<const bfrag*>(smem + aoff);
      bfrag bh[4];
#pragma unroll
      for (int ct = 0; ct < 4; ++ct) {
        const int c = wc * 64 + ct * 16 + l15;
        const unsigned boff = ((unsigned)(c * 128 + ss * 64 + lg * 16) ^ (unsigned)((c & 7) << 4)) + bufC;
        bh[ct] = *reinterpret_cast<const bfrag*>(smem + 8192 + boff);
      }
#pragma unroll
      for (int ct = 0; ct < 4; ++ct)
        acc[ct] = __builtin_amdgcn_mfma_f32_16x16x32_bf16(ah, bh[ct], acc[ct], 0, 0, 0);
    }
    __syncthreads();
  }
  const int orow = rb * 64 + wr * 16 + lg * 4;
#pragma unroll
  for (int ct = 0; ct < 4; ++ct) {
    const int ocol = wc * 64 + ct * 16 + l15;
#pragma unroll
    for (int i = 0; i < 4; ++i) {
      const size_t idx = ((size_t)(b * kN + orow + i)) * kC + ocol;
      float v = alpha * acc[ct][i];
      if (Zsub) v -= Zsub[idx];
      Y[idx] = v;
      if (yt) c32[(wr * 16 + lg * 4 + i) * 132 + ocol] = v;
    }
  }
  if (yt) {
    __syncthreads();
    const int c = tid >> 2, nch = tid & 3;
    const int n0 = nch * 16;
    ushort hs[16];
#pragma unroll
    for (int j = 0; j < 16; ++j) hs[j] = f2bf(c32[(n0 + j) * 132 + c]);
    const size_t obase = (size_t)(b * kC + c) * kN + rb * 64 + n0;
    *reinterpret_cast<uint4*>(&yt[obase]) = *reinterpret_cast<uint4*>(hs);
    *reinterpret_cast<uint4*>(&yt[obase + 8]) = *reinterpret_cast<uint4*>(hs + 8);
  }
}

// ---- 10. z = x@th0 + tcur@th1 + tnext@th2 + x ; emits per-row sum/sumsq ----
__global__ __launch_bounds__(256) void k_theta(const float* __restrict__ x,
                                               const float* __restrict__ tcur,
                                               const float* __restrict__ tnext,
                                               const float* __restrict__ theta,
                                               float* __restrict__ z,
                                               float* __restrict__ sumz,
                                               float* __restrict__ sumzz) {
  __shared__ float a_s[32 * 68];
  __shared__ float w_s[32 * 128];
  const int row0 = blockIdx.x * 32;
  const int tid = threadIdx.x;
  const int tr = tid >> 5, tc = tid & 31;
  const int r0 = tr * 4, c0 = tc * 4;
  float acc[4][4] = {};
  const float* srcs[3] = {x, tcur, tnext};
  for (int s = 0; s < 3; ++s) {
    const float* A = srcs[s];
    for (int kc = 0; kc < 4; ++kc) {
      const int k0 = kc * 32;
      __syncthreads();
      {
        int r = tid >> 3, kk4 = tid & 7;
        float4 v = *reinterpret_cast<const float4*>(&A[(size_t)(row0 + r) * kC + k0 + kk4 * 4]);
        *reinterpret_cast<float4*>(&a_s[r * 68 + kk4 * 4]) = v;
      }
#pragma unroll
      for (int it = 0; it < 4; ++it) {
        int e4 = it * 256 + tid;
        int kk = e4 >> 5, d4 = e4 & 31;
        float4 v = *reinterpret_cast<const float4*>(
            &theta[(size_t)s * 16384 + (size_t)(k0 + kk) * kC + d4 * 4]);
        *reinterpret_cast<float4*>(&w_s[kk * 128 + d4 * 4]) = v;
      }
      __syncthreads();
#pragma unroll 8
      for (int k = 0; k < 32; ++k) {
        float a[4];
#pragma unroll
        for (int i = 0; i < 4; ++i) a[i] = a_s[(r0 + i) * 68 + k];
        float4 b4 = *reinterpret_cast<float4*>(&w_s[k * 128 + c0]);
        float bj[4] = {b4.x, b4.y, b4.z, b4.w};
#pragma unroll
        for (int i = 0; i < 4; ++i)
#pragma unroll
          for (int j = 0; j < 4; ++j) acc[i][j] += a[i] * bj[j];
      }
    }
  }
  float rs[4], rq[4];
#pragma unroll
  for (int i = 0; i < 4; ++i) {
    size_t idx = (size_t)(row0 + r0 + i) * kC + c0;
    float4 xv = *reinterpret_cast<const float4*>(&x[idx]);
    float4 o = {acc[i][0] + xv.x, acc[i][1] + xv.y, acc[i][2] + xv.z, acc[i][3] + xv.w};
    *reinterpret_cast<float4*>(&z[idx]) = o;
    rs[i] = o.x + o.y + o.z + o.w;
    rq[i] = o.x * o.x + o.y * o.y + o.z * o.z + o.w * o.w;
  }
#pragma unroll
  for (int m = 1; m < 32; m <<= 1) {
#pragma unroll
    for (int i = 0; i < 4; ++i) { rs[i] += __shfl_xor(rs[i], m); rq[i] += __shfl_xor(rq[i], m); }
  }
  if (tc == 0) {
#pragma unroll
    for (int i = 0; i < 4; ++i) {
      sumz[row0 + r0 + i] = rs[i];
      sumzz[row0 + r0 + i] = rq[i];
    }
  }
}

// ---- 11. per-node BN (stats precomputed) + relu + dot(w_out) -> out ----
__global__ __launch_bounds__(256) void k_final(const float* __restrict__ z,
                                               const float* __restrict__ sumz,
                                               const float* __restrict__ sumzz,
                                               const float* __restrict__ g4,
                                               const float* __restrict__ b4v,
                                               const float* __restrict__ w_out,
                                               const float* __restrict__ b_out,
                                               float* __restrict__ out) {
  const int n = blockIdx.x;
  const int tid = threadIdx.x;
  __shared__ float sscale, sshift;
  if (tid < 16) {
    float a = sumz[tid * kN + n];
    float q = sumzz[tid * kN + n];
#pragma unroll
    for (int m = 1; m < 16; m <<= 1) { a += __shfl_xor(a, m); q += __shfl_xor(q, m); }
    if (tid == 0) {
      float mean = a * (1.f / 2048.f);
      float var = fmaxf(q * (1.f / 2048.f) - mean * mean, 0.f);
      float inv = rsqrtf(var + kEPS);
      float gg = g4[n];
      sscale = inv * gg;
      sshift = b4v[n] - mean * inv * gg;
    }
  }
  __syncthreads();
  const float scale = sscale, shift = sshift;
  const int b = tid >> 4, c0 = (tid & 15) * 8;
  float p = 0.f;
#pragma unroll
  for (int j = 0; j < 8; ++j) {
    float v = z[(size_t)(b * kN + n) * kC + c0 + j] * scale + shift;
    v = fmaxf(v, 0.f);
    p += v * w_out[c0 + j];
  }
  for (int o = 8; o > 0; o >>= 1) p += __shfl_down(p, o, 16);
  if ((tid & 15) == 0) out[b * kN + n] = p + b_out[0];
}

extern "C" void kernel_launch(void* const* d_in, const int* in_sizes, int n_in,
                              void* d_out, int out_size, void* d_ws, size_t ws_size,
                              hipStream_t stream) {
  const int*   data = (const int*)d_in[0];
  const float* node_features = (const float*)d_in[1];
  const float* go_adj = (const float*)d_in[2];
  const float* emb  = (const float*)d_in[4];
  const float* w_go = (const float*)d_in[5];
  const float* b_go = (const float*)d_in[6];
  const float* wq   = (const float*)d_in[7];
  const float* wk   = (const float*)d_in[8];
  const float* theta= (const float*)d_in[9];
  const float* g1   = (const float*)d_in[10];
  const float* b1   = (const float*)d_in[11];
  const float* g3   = (const float*)d_in[12];
  const float* b3   = (const float*)d_in[13];
  const float* g4   = (const float*)d_in[14];
  const float* b4   = (const float*)d_in[15];
  const float* w_out= (const float*)d_in[16];
  const float* b_out= (const float*)d_in[17];

  float* ws = (float*)d_ws;
  float* featpart = ws + OFF_FEATPART;
  float* m1t   = ws + OFF_M1;
  float* x     = ws + OFF_X;
  float* z     = ws + OFF_Z;
  float* tcur  = ws + OFF_TCUR;
  float* tnext = ws + OFF_TNEXT;
  float* gopart= ws + OFF_GOPART;
  float* psum  = ws + OFF_PSUM;
  float* sumz  = ws + OFF_SUMZ;
  float* sumzz = ws + OFF_SUMZZ;
  ushort* adj  = (ushort*)(ws + OFF_ADJ);
  ushort* xt   = (ushort*)(ws + OFF_XT);
  ushort* qb   = (ushort*)(ws + OFF_Q);
  ushort* kb   = (ushort*)(ws + OFF_K);
  ushort* tt   = (ushort*)(ws + OFF_TT);

  k_embsum<<<dim3(16, 64), 256, 0, stream>>>(data, emb, featpart);
  k_bn_feat<<<16, 256, 0, stream>>>(featpart, data, g1, b1, m1t);
  k_go_gemm2<<<dim3(64, 4), 256, 0, stream>>>(m1t, w_go, gopart);
  k_go_bn<<<1024, 256, 0, stream>>>(gopart, b_go, node_features, g3, b3, x);
  k_qkgen<<<512, 256, 0, stream>>>(x, wq, wk, qb, kb, xt);
  k_att_stats<<<dim3(16, 16, 2), 512, 0, stream>>>(qb, kb, psum);
  k_adj_emit<<<dim3(8, 16, 16), 512, 0, stream>>>(qb, kb, go_adj, psum, adj);
  k_adjmm_mfma<<<256, 512, 0, stream>>>(adj, xt, nullptr, tcur, 1.0f, tt);
  k_adjmm_mfma<<<256, 512, 0, stream>>>(adj, tt, x, tnext, 2.0f, nullptr);
  k_theta<<<512, 256, 0, stream>>>(x, tcur, tnext, theta, z, sumz, sumzz);
  k_final<<<1024, 256, 0, stream>>>(z, sumz, sumzz, g4, b4, w_out, b_out, (float*)d_out);
}

// Round 17
// 166.271 us; speedup vs baseline: 2.0170x; 1.0449x over previous
//
#include <hip/hip_runtime.h>

namespace {
constexpr int kB = 16;
constexpr int kMAXLEN = 1024;
constexpr int kPE = 256;
constexpr int kN = 1024;
constexpr int kEMB = 256;
constexpr int kC = 128;
constexpr float kEPS = 1e-5f;

// workspace offsets in floats
constexpr size_t OFF_FEATPART = 0;                         // 16*64*256 = 262144
constexpr size_t OFF_M1       = 262144;                    // 512*16
constexpr size_t OFF_X        = 270336;                    // 16*1024*128
constexpr size_t OFF_Z        = OFF_X    + 2097152;
constexpr size_t OFF_TCUR     = OFF_Z    + 2097152;
constexpr size_t OFF_TNEXT    = OFF_TCUR + 2097152;
constexpr size_t OFF_GOPART   = OFF_TNEXT+ 2097152;        // 4*16*65536
constexpr size_t OFF_PSUM     = OFF_GOPART + 4194304;      // 16*16*1024
constexpr size_t OFF_SUMZ     = OFF_PSUM + 262144;
constexpr size_t OFF_SUMZZ    = OFF_SUMZ + 16384;
constexpr size_t OFF_ADJ      = OFF_SUMZZ + 16384;         // 16.8M bf16
constexpr size_t OFF_XT       = OFF_ADJ  + 8388608;
constexpr size_t OFF_Q        = OFF_XT   + 1048576;
constexpr size_t OFF_K        = OFF_Q    + 524288;
constexpr size_t OFF_TT       = OFF_K    + 524288;
constexpr size_t OFF_THT      = OFF_TT   + 1048576;        // 3*128*128 bf16 = 24576 fl

typedef __attribute__((ext_vector_type(8))) short bfrag;
typedef __attribute__((ext_vector_type(4))) float f32x4;

__device__ inline ushort f2bf(float f) {
  unsigned u = __float_as_uint(f);
  unsigned r = (u + 0x7FFFu + ((u >> 16) & 1u)) >> 16;  // RNE
  return (ushort)r;
}
} // namespace

// ---- 1. embedding gather partial sums: featpart[b][chunk64][e] ----
__global__ __launch_bounds__(256) void k_embsum(const int* __restrict__ data,
                                                const float* __restrict__ emb,
                                                float* __restrict__ featpart) {
  const int b = blockIdx.x, ch = blockIdx.y;   // 16 x 64
  const int e = threadIdx.x;                   // 256
  const int* row = data + b * (kMAXLEN + kPE) + ch * 16;
  float acc = 0.f;
#pragma unroll 4
  for (int l = 0; l < 16; ++l) {
    acc += emb[(size_t)row[l] * kEMB + e];
  }
  featpart[((b * 64 + ch) << 8) + e] = acc;
}

// ---- 2. BN over batch -> m1t; also emits theta^T bf16 ----
__global__ __launch_bounds__(256) void k_bn_feat(const float* __restrict__ featpart,
                                                 const int* __restrict__ data,
                                                 const float* __restrict__ g1,
                                                 const float* __restrict__ b1,
                                                 const float* __restrict__ theta,
                                                 float* __restrict__ m1t,
                                                 ushort* __restrict__ thT) {
  const int tid = threadIdx.x;
  {  // theta^T: thT[(s*128+d)*128+c] = bf16(theta[(s*128+c)*128+d]); 4096 thr * 12
    const int gid = blockIdx.x * 256 + tid;
#pragma unroll
    for (int j = 0; j < 12; ++j) {
      const int idx = gid * 12 + j;
      const int s = idx >> 14, rem = idx & 16383;
      const int d = rem >> 7, c = rem & 127;
      thT[idx] = f2bf(theta[(size_t)(s * 128 + c) * 128 + d]);
    }
  }
  const int jl = tid >> 3, part = tid & 7;
  const int j = blockIdx.x * 32 + jl;
  float v[kB];
  if (j < kPE) {
#pragma unroll
    for (int b = 0; b < kB; ++b) {
      float s = 0.f;
      const int ch0 = part * 8;
#pragma unroll
      for (int ch = 0; ch < 8; ++ch)
        s += featpart[((b * 64 + ch0 + ch) << 8) + j];
      v[b] = s;
    }
  } else {
#pragma unroll
    for (int b = 0; b < kB; ++b)
      v[b] = (part == 0) ? (float)data[b * (kMAXLEN + kPE) + kMAXLEN + (j - kPE)] : 0.f;
  }
#pragma unroll
  for (int m = 1; m < 8; m <<= 1) {
#pragma unroll
    for (int b = 0; b < kB; ++b) v[b] += __shfl_xor(v[b], m);
  }
  const float pe = (j < kPE) ? sinf((float)j) : sinf((float)(j - kPE));
#pragma unroll
  for (int b = 0; b < kB; ++b)
    v[b] = (j < kPE) ? (v[b] * (1.f / 1024.f) + pe) : (v[b] + pe);
  float s = 0.f;
#pragma unroll
  for (int b = 0; b < kB; ++b) s += v[b];
  const float mean = s * (1.f / kB);
  float s2 = 0.f;
#pragma unroll
  for (int b = 0; b < kB; ++b) { float d = v[b] - mean; s2 += d * d; }
  const float inv = rsqrtf(s2 * (1.f / kB) + kEPS);
  if (part == 0) {
    const float g = g1[j], bb = b1[j];
    float o[kB];
#pragma unroll
    for (int b = 0; b < kB; ++b) o[b] = (v[b] - mean) * inv * g + bb;
#pragma unroll
    for (int q = 0; q < 4; ++q)
      *reinterpret_cast<float4*>(&m1t[j * kB + q * 4]) =
          *reinterpret_cast<float4*>(&o[q * 4]);
  }
}

// ---- 3a. split-K GEMM, 4 k-slices (m1t via SGPR broadcast) ----
__global__ __launch_bounds__(256) void k_go_gemm2(const float* __restrict__ m1t,
                                                  const float* __restrict__ w_go,
                                                  float* __restrict__ part) {
  const int c0 = blockIdx.x * 1024 + threadIdx.x * 4;
  const int k0 = blockIdx.y * 128;
  float4 acc[kB];
#pragma unroll
  for (int b = 0; b < kB; ++b) acc[b] = make_float4(0.f, 0.f, 0.f, 0.f);
#pragma unroll 4
  for (int k = 0; k < 128; ++k) {
    const float4 w = *reinterpret_cast<const float4*>(&w_go[(size_t)(k0 + k) * 65536 + c0]);
    const float* mrow = m1t + (size_t)(k0 + k) * kB;
#pragma unroll
    for (int b = 0; b < kB; ++b) {
      const float m = mrow[b];
      acc[b].x += m * w.x; acc[b].y += m * w.y;
      acc[b].z += m * w.z; acc[b].w += m * w.w;
    }
  }
  const size_t kb16 = (size_t)blockIdx.y * kB;
#pragma unroll
  for (int b = 0; b < kB; ++b) {
    *reinterpret_cast<float4*>(&part[(kb16 + b) * 65536 + c0]) = acc[b];
  }
}

// ---- 3b+4 fused. per-node: reduce 4 go partials + bias/relu, nf concat, BN -> x ----
__global__ __launch_bounds__(256) void k_go_bn(const float* __restrict__ part,
                                               const float* __restrict__ b_go,
                                               const float* __restrict__ nf,
                                               const float* __restrict__ g3,
                                               const float* __restrict__ b3,
                                               float* __restrict__ x) {
  const int n = blockIdx.x;
  const int tid = threadIdx.x;
  __shared__ float nfs[64];
  if (tid < 64) nfs[tid] = nf[n * 64 + tid];
  float val[4];
  float s = 0.f, s2 = 0.f;
#pragma unroll
  for (int i = 0; i < 4; ++i) {
    const int e = i * 256 + tid;
    const int b = e >> 6, c = e & 63;
    float a = part[(size_t)b * 65536 + n * 64 + c];
#pragma unroll
    for (int kb = 1; kb < 4; ++kb)
      a += part[(size_t)(kb * kB + b) * 65536 + n * 64 + c];
    a = fmaxf(a + b_go[n * 64 + c], 0.f);
    val[i] = a;
    s += a; s2 += a * a;
  }
  __syncthreads();
  if (tid < 64) {
    const float v = nfs[tid];
    s += 16.f * v; s2 += 16.f * v * v;
  }
  for (int o = 32; o > 0; o >>= 1) { s += __shfl_down(s, o); s2 += __shfl_down(s2, o); }
  __shared__ float ls[4], ls2[4];
  __shared__ float sscale, sshift;
  const int w = tid >> 6;
  if ((tid & 63) == 0) { ls[w] = s; ls2[w] = s2; }
  __syncthreads();
  if (tid == 0) {
    float S = ls[0] + ls[1] + ls[2] + ls[3];
    float S2 = ls2[0] + ls2[1] + ls2[2] + ls2[3];
    float mean = S * (1.f / 2048.f);
    float var = fmaxf(S2 * (1.f / 2048.f) - mean * mean, 0.f);
    float inv = rsqrtf(var + kEPS);
    float gg = g3[n];
    sscale = inv * gg;
    sshift = b3[n] - mean * inv * gg;
  }
  __syncthreads();
  const float scale = sscale, shift = sshift;
#pragma unroll
  for (int i = 0; i < 4; ++i) {
    const int e = i * 256 + tid;
    const int b = e >> 6, c = e & 63;
    x[((size_t)(b * kN + n)) * kC + c] = val[i] * scale + shift;
  }
#pragma unroll
  for (int i = 0; i < 4; ++i) {
    const int e = i * 256 + tid;
    const int b = e >> 6, c = e & 63;
    x[((size_t)(b * kN + n)) * kC + 64 + c] = nfs[c] * scale + shift;
  }
}

// ---- 5. q/k projections + fused x^T bf16 emit ----
__global__ __launch_bounds__(256) void k_qkgen(const float* __restrict__ x,
                                               const float* __restrict__ wq,
                                               const float* __restrict__ wk,
                                               ushort* __restrict__ qb,
                                               ushort* __restrict__ kb,
                                               ushort* __restrict__ xt) {
  __shared__ float a_s[32 * 68];
  __shared__ float w_s[32 * 128];
  const int row0 = blockIdx.x * 32;
  const int bb = row0 >> 10, n0 = row0 & 1023;
  const int tid = threadIdx.x;
  const int tr = tid >> 5, tc = tid & 31;
  const int r0 = tr * 4, c0 = tc * 4;
  float acc[4][4] = {};
  for (int kc = 0; kc < 4; ++kc) {
    const int k0 = kc * 32;
    __syncthreads();
    {
      int r = tid >> 3, kk4 = tid & 7;
      float4 v = *reinterpret_cast<const float4*>(&x[(size_t)(row0 + r) * kC + k0 + kk4 * 4]);
      *reinterpret_cast<float4*>(&a_s[r * 68 + kk4 * 4]) = v;
    }
    for (int it = 0; it < 16; ++it) {
      int e = it * 256 + tid;
      int kk = e >> 7, h2 = e & 127;
      int c = k0 + kk;
      float v = (h2 < 64) ? wq[c * 64 + h2] : wk[c * 64 + (h2 - 64)];
      w_s[kk * 128 + h2] = v;
    }
    __syncthreads();
#pragma unroll
    for (int q = 0; q < 4; ++q) {
      const int e = q * 256 + tid;
      const int kk = e >> 5, r = e & 31;
      xt[(size_t)(bb * kC + k0 + kk) * kN + n0 + r] = f2bf(a_s[r * 68 + kk]);
    }
#pragma unroll 8
    for (int k = 0; k < 32; ++k) {
      float a[4];
#pragma unroll
      for (int i = 0; i < 4; ++i) a[i] = a_s[(r0 + i) * 68 + k];
      float4 b4 = *reinterpret_cast<float4*>(&w_s[k * 128 + c0]);
      float bj[4] = {b4.x, b4.y, b4.z, b4.w};
#pragma unroll
      for (int i = 0; i < 4; ++i)
#pragma unroll
        for (int j = 0; j < 4; ++j) acc[i][j] += a[i] * bj[j];
    }
  }
  const bool isq = (c0 < 64);
  const int h0 = isq ? c0 : (c0 - 64);
  ushort* oh = isq ? qb : kb;
#pragma unroll
  for (int i = 0; i < 4; ++i) {
    ushort hs[4];
#pragma unroll
    for (int j = 0; j < 4; ++j) hs[j] = f2bf(acc[i][j]);
    const size_t o = (size_t)(row0 + r0 + i) * 64 + h0;
    *reinterpret_cast<ushort4*>(&oh[o]) = *reinterpret_cast<ushort4*>(hs);
  }
}

// ---- 6. att sum-stats via MFMA (single bf16), K double-buffered LDS ----
__global__ __launch_bounds__(512) void k_att_stats(const ushort* __restrict__ qb,
                                                   const ushort* __restrict__ kb,
                                                   float* __restrict__ psum) {
  const int nt = blockIdx.x, b = blockIdx.y;
  const int mc0 = blockIdx.z * 4;
  __shared__ uint4 smem4[2560];
  char* smem = (char*)smem4;
  const int tid = threadIdx.x;
  const int lane = tid & 63, w = tid >> 6;
  const int l15 = lane & 15, lg = lane >> 4;

  {
    const int r = tid >> 3, ch = tid & 7;
    const size_t g = (size_t)(b * kN + nt * 64 + r) * 64 + ch * 8;
    const unsigned off = (unsigned)(r * 128 + ch * 16) ^ (unsigned)((r & 7) << 4);
    *reinterpret_cast<uint4*>(smem + off) = *reinterpret_cast<const uint4*>(qb + g);
  }

  const int c0s = tid >> 3, c1s = 64 + (tid >> 3);
  const int chs = tid & 7;
  const unsigned offK0 = (unsigned)(c0s * 128 + chs * 16) ^ (unsigned)((c0s & 7) << 4);
  const unsigned offK1 = (unsigned)(c1s * 128 + chs * 16) ^ (unsigned)((c1s & 7) << 4);
  const size_t gK0 = (size_t)(b * kN + mc0 * 128 + c0s) * 64 + chs * 8;
  const size_t gK1 = (size_t)(b * kN + mc0 * 128 + c1s) * 64 + chs * 8;

  uint4 ph0 = *reinterpret_cast<const uint4*>(kb + gK0);
  uint4 ph1 = *reinterpret_cast<const uint4*>(kb + gK1);
  *reinterpret_cast<uint4*>(smem + 8192 + offK0) = ph0;
  *reinterpret_cast<uint4*>(smem + 8192 + offK1) = ph1;
  {
    const size_t k1 = (size_t)128 * 64;
    ph0 = *reinterpret_cast<const uint4*>(kb + gK0 + k1);
    ph1 = *reinterpret_cast<const uint4*>(kb + gK1 + k1);
  }
  __syncthreads();

  for (int it = 0; it < 4; ++it) {
    const int mc = mc0 + it;
    const unsigned bufC = 8192 + (unsigned)(it & 1) * 16384;
    const unsigned bufN = 8192 + (unsigned)((it + 1) & 1) * 16384;
    if (it < 3) {
      *reinterpret_cast<uint4*>(smem + bufN + offK0) = ph0;
      *reinterpret_cast<uint4*>(smem + bufN + offK1) = ph1;
      if (it < 2) {
        const size_t k2 = (size_t)(it + 2) * 128 * 64;
        ph0 = *reinterpret_cast<const uint4*>(kb + gK0 + k2);
        ph1 = *reinterpret_cast<const uint4*>(kb + gK1 + k2);
      }
    }
    f32x4 acc[4] = {{0.f,0.f,0.f,0.f},{0.f,0.f,0.f,0.f},{0.f,0.f,0.f,0.f},{0.f,0.f,0.f,0.f}};
#pragma unroll
    for (int ss = 0; ss < 2; ++ss) {
      const int r = w * 16 + l15;
      const unsigned aoff = ((unsigned)(r * 128 + ss * 64 + lg * 16) ^ (unsigned)((r & 7) << 4)) + bufC;
      bfrag ah = *reinterpret_cast<const bfrag*>(smem + aoff);
#pragma unroll
      for (int nf = 0; nf < 4; ++nf) {
        const int c = nf * 16 + l15;
        const unsigned boff = (unsigned)(c * 128 + ss * 64 + lg * 16) ^ (unsigned)((c & 7) << 4);
        bfrag bh = *reinterpret_cast<const bfrag*>(smem + boff);
        acc[nf] = __builtin_amdgcn_mfma_f32_16x16x32_bf16(ah, bh, acc[nf], 0, 0, 0);
      }
    }
#pragma unroll
    for (int i = 0; i < 4; ++i) {
      float sm = __expf(acc[0][i] * 0.125f) + __expf(acc[1][i] * 0.125f)
               + __expf(acc[2][i] * 0.125f) + __expf(acc[3][i] * 0.125f);
#pragma unroll
      for (int msk = 1; msk < 16; msk <<= 1) sm += __shfl_xor(sm, msk);
      if (l15 == 0) {
        const int m = mc * 128 + w * 16 + lg * 4 + i;
        psum[(size_t)(b * 16 + nt) * kN + m] = sm;
      }
    }
    __syncthreads();
  }
}

// ---- 8. adj emit: recompute Q·K^T, adj = go_adj + exp(s/8)*cinv -> single bf16 ----
__global__ __launch_bounds__(512) void k_adj_emit(const ushort* __restrict__ qb,
                                                  const ushort* __restrict__ kb,
                                                  const float* __restrict__ go_adj,
                                                  const float* __restrict__ psum,
                                                  ushort* __restrict__ adj) {
  const int mc = blockIdx.x, nt = blockIdx.y, b = blockIdx.z;
  __shared__ uint4 smem4[2304];
  __shared__ float cinvs[128];
  char* smem = (char*)smem4;
  float* c32 = (float*)smem4;
  const int tid = threadIdx.x;
  const int lane = tid & 63, w = tid >> 6;
  const int wr = w >> 2, wc = w & 3;
  const int l15 = lane & 15, lg = lane >> 4;

  if (tid < 128) {
    const int m = mc * 128 + tid;
    float S = 0.f;
#pragma unroll
    for (int c = 0; c < 16; ++c) S += psum[(size_t)(b * 16 + c) * kN + m];
    cinvs[tid] = 1.f / S;
  }
  {
    const int r = tid >> 3, ch = tid & 7;
    const size_t g = (size_t)(b * kN + nt * 64 + r) * 64 + ch * 8;
    const unsigned off = (unsigned)(r * 128 + ch * 16) ^ (unsigned)((r & 7) << 4);
    *reinterpret_cast<uint4*>(smem + off) = *reinterpret_cast<const uint4*>(qb + g);
  }
#pragma unroll
  for (int p = 0; p < 2; ++p) {
    const int e = p * 512 + tid;
    const int c = e >> 3, ch = e & 7;
    const size_t g = (size_t)(b * kN + mc * 128 + c) * 64 + ch * 8;
    const unsigned off = (unsigned)(c * 128 + ch * 16) ^ (unsigned)((c & 7) << 4);
    *reinterpret_cast<uint4*>(smem + 8192 + off) = *reinterpret_cast<const uint4*>(kb + g);
  }
  __syncthreads();
  f32x4 acc[2][2] = {{{0.f,0.f,0.f,0.f},{0.f,0.f,0.f,0.f}},
                     {{0.f,0.f,0.f,0.f},{0.f,0.f,0.f,0.f}}};
#pragma unroll
  for (int ss = 0; ss < 2; ++ss) {
    bfrag ah[2], bh[2];
#pragma unroll
    for (int nf = 0; nf < 2; ++nf) {
      const int r = wr * 32 + nf * 16 + l15;
      const unsigned aoff = (unsigned)(r * 128 + ss * 64 + lg * 16) ^ (unsigned)((r & 7) << 4);
      ah[nf] = *reinterpret_cast<const bfrag*>(smem + aoff);
    }
#pragma unroll
    for (int mf = 0; mf < 2; ++mf) {
      const int c = wc * 32 + mf * 16 + l15;
      const unsigned boff = (unsigned)(c * 128 + ss * 64 + lg * 16) ^ (unsigned)((c & 7) << 4);
      bh[mf] = *reinterpret_cast<const bfrag*>(smem + 8192 + boff);
    }
#pragma unroll
    for (int nf = 0; nf < 2; ++nf)
#pragma unroll
      for (int mf = 0; mf < 2; ++mf)
        acc[nf][mf] = __builtin_amdgcn_mfma_f32_16x16x32_bf16(ah[nf], bh[mf], acc[nf][mf], 0, 0, 0);
  }
  __syncthreads();
#pragma unroll
  for (int mf = 0; mf < 2; ++mf) {
    const int mLoc = wc * 32 + mf * 16 + l15;
    const float I = cinvs[mLoc];
#pragma unroll
    for (int nf = 0; nf < 2; ++nf) {
#pragma unroll
      for (int i = 0; i < 4; ++i) {
        const int nLoc = wr * 32 + nf * 16 + lg * 4 + i;
        c32[nLoc * 132 + mLoc] = __expf(acc[nf][mf][i] * 0.125f) * I;
      }
    }
  }
  __syncthreads();
#pragma unroll
  for (int p = 0; p < 2; ++p) {
    const int e = p * 512 + tid;
    const int n = e >> 4, m0 = (e & 15) * 8;
    const float* cr = &c32[n * 132 + m0];
    const float* ga = &go_adj[(size_t)(nt * 64 + n) * kN + mc * 128 + m0];
    ushort hs[8];
#pragma unroll
    for (int j = 0; j < 8; ++j) hs[j] = f2bf(cr[j] + ga[j]);
    const size_t o = (size_t)(b * kN + nt * 64 + n) * kN + mc * 128 + m0;
    *reinterpret_cast<uint4*>(&adj[o]) = *reinterpret_cast<uint4*>(hs);
  }
}

// ---- 9. Y = alpha * adj @ X (- Zsub); single bf16, double-buffered LDS ----
__global__ __launch_bounds__(512) void k_adjmm_mfma(const ushort* __restrict__ adj,
                                                    const ushort* __restrict__ xt,
                                                    const float* __restrict__ Zsub,
                                                    float* __restrict__ Y, float alpha,
                                                    ushort* __restrict__ yt) {
  const int bid = blockIdx.x;
  const int swz = (bid & 7) * 32 + (bid >> 3);
  const int b = swz >> 4, rb = swz & 15;
  __shared__ uint4 smem4[3072];
  char* smem = (char*)smem4;
  float* c32 = (float*)smem4;
  const int tid = threadIdx.x;
  const int lane = tid & 63, w = tid >> 6;
  const int wr = w >> 1, wc = w & 1;
  const int l15 = lane & 15, lg = lane >> 4;

  const int ra = tid >> 3, cha = tid & 7;
  const unsigned offA = (unsigned)(ra * 128 + cha * 16) ^ (unsigned)((ra & 7) << 4);
  const size_t gA = ((size_t)(b * kN + rb * 64 + ra)) * kN + cha * 8;
  const int cb0 = tid >> 3, cb1 = 64 + (tid >> 3);
  const unsigned offB0 = (unsigned)(cb0 * 128 + cha * 16) ^ (unsigned)((cb0 & 7) << 4);
  const unsigned offB1 = (unsigned)(cb1 * 128 + cha * 16) ^ (unsigned)((cb1 & 7) << 4);
  const size_t gB0 = ((size_t)b * kC + cb0) * kN + cha * 8;
  const size_t gB1 = ((size_t)b * kC + cb1) * kN + cha * 8;

  f32x4 acc[4] = {{0.f,0.f,0.f,0.f},{0.f,0.f,0.f,0.f},{0.f,0.f,0.f,0.f},{0.f,0.f,0.f,0.f}};

  uint4 pa  = *reinterpret_cast<const uint4*>(adj + gA);
  uint4 pb0 = *reinterpret_cast<const uint4*>(xt + gB0);
  uint4 pb1 = *reinterpret_cast<const uint4*>(xt + gB1);
  *reinterpret_cast<uint4*>(smem + offA)         = pa;
  *reinterpret_cast<uint4*>(smem + 8192 + offB0) = pb0;
  *reinterpret_cast<uint4*>(smem + 8192 + offB1) = pb1;
  pa  = *reinterpret_cast<const uint4*>(adj + gA + 64);
  pb0 = *reinterpret_cast<const uint4*>(xt + gB0 + 64);
  pb1 = *reinterpret_cast<const uint4*>(xt + gB1 + 64);
  __syncthreads();

  for (int kt = 0; kt < 16; ++kt) {
    const unsigned bufC = (unsigned)(kt & 1) * 24576;
    const unsigned bufN = (unsigned)((kt + 1) & 1) * 24576;
    if (kt < 15) {
      *reinterpret_cast<uint4*>(smem + bufN + offA)         = pa;
      *reinterpret_cast<uint4*>(smem + bufN + 8192 + offB0) = pb0;
      *reinterpret_cast<uint4*>(smem + bufN + 8192 + offB1) = pb1;
      if (kt < 14) {
        const int k2 = (kt + 2) * 64;
        pa  = *reinterpret_cast<const uint4*>(adj + gA + k2);
        pb0 = *reinterpret_cast<const uint4*>(xt + gB0 + k2);
        pb1 = *reinterpret_cast<const uint4*>(xt + gB1 + k2);
      }
    }
#pragma unroll
    for (int ss = 0; ss < 2; ++ss) {
      const int r = wr * 16 + l15;
      const unsigned aoff = ((unsigned)(r * 128 + ss * 64 + lg * 16) ^ (unsigned)((r & 7) << 4)) + bufC;
      bfrag ah = *reinterpret_cast<const bfrag*>(smem + aoff);
      bfrag bh[4];
#pragma unroll
      for (int ct = 0; ct < 4; ++ct) {
        const int c = wc * 64 + ct * 16 + l15;
        const unsigned boff = ((unsigned)(c * 128 + ss * 64 + lg * 16) ^ (unsigned)((c & 7) << 4)) + bufC;
        bh[ct] = *reinterpret_cast<const bfrag*>(smem + 8192 + boff);
      }
#pragma unroll
      for (int ct = 0; ct < 4; ++ct)
        acc[ct] = __builtin_amdgcn_mfma_f32_16x16x32_bf16(ah, bh[ct], acc[ct], 0, 0, 0);
    }
    __syncthreads();
  }
  const int orow = rb * 64 + wr * 16 + lg * 4;
#pragma unroll
  for (int ct = 0; ct < 4; ++ct) {
    const int ocol = wc * 64 + ct * 16 + l15;
#pragma unroll
    for (int i = 0; i < 4; ++i) {
      const size_t idx = ((size_t)(b * kN + orow + i)) * kC + ocol;
      float v = alpha * acc[ct][i];
      if (Zsub) v -= Zsub[idx];
      Y[idx] = v;
      if (yt) c32[(wr * 16 + lg * 4 + i) * 132 + ocol] = v;
    }
  }
  if (yt) {
    __syncthreads();
    const int c = tid >> 2, nch = tid & 3;
    const int n0 = nch * 16;
    ushort hs[16];
#pragma unroll
    for (int j = 0; j < 16; ++j) hs[j] = f2bf(c32[(n0 + j) * 132 + c]);
    const size_t obase = (size_t)(b * kC + c) * kN + rb * 64 + n0;
    *reinterpret_cast<uint4*>(&yt[obase]) = *reinterpret_cast<uint4*>(hs);
    *reinterpret_cast<uint4*>(&yt[obase + 8]) = *reinterpret_cast<uint4*>(hs + 8);
  }
}

// ---- 10. z = x@th0 + tcur@th1 + tnext@th2 + x via MFMA; emits row sums ----
__global__ __launch_bounds__(512) void k_theta_mfma(const float* __restrict__ x,
                                                    const float* __restrict__ tcur,
                                                    const float* __restrict__ tnext,
                                                    const ushort* __restrict__ thT,
                                                    float* __restrict__ z,
                                                    float* __restrict__ sumz,
                                                    float* __restrict__ sumzz) {
  const int rb = blockIdx.x, b = blockIdx.y;
  const int tid = threadIdx.x;
  const int lane = tid & 63, w = tid >> 6;
  const int wr = w >> 1, wc = w & 1;
  const int l15 = lane & 15, lg = lane >> 4;
  __shared__ float rsS[2][64], rqS[2][64];

  f32x4 acc[4] = {{0.f,0.f,0.f,0.f},{0.f,0.f,0.f,0.f},{0.f,0.f,0.f,0.f},{0.f,0.f,0.f,0.f}};
  const float* srcs[3] = {x, tcur, tnext};
  const size_t arow = ((size_t)(b * kN + rb * 64 + wr * 16 + l15)) * kC;
  for (int s = 0; s < 3; ++s) {
    const float* A = srcs[s] + arow;
    const ushort* TH = thT + (size_t)s * 16384;
#pragma unroll
    for (int ss = 0; ss < 4; ++ss) {
      const int k0 = ss * 32 + lg * 8;
      float4 a0 = *reinterpret_cast<const float4*>(A + k0);
      float4 a1 = *reinterpret_cast<const float4*>(A + k0 + 4);
      ushort av[8] = {f2bf(a0.x), f2bf(a0.y), f2bf(a0.z), f2bf(a0.w),
                      f2bf(a1.x), f2bf(a1.y), f2bf(a1.z), f2bf(a1.w)};
      bfrag af = *reinterpret_cast<bfrag*>(av);
#pragma unroll
      for (int ct = 0; ct < 4; ++ct) {
        const int d = wc * 64 + ct * 16 + l15;
        bfrag bf = *reinterpret_cast<const bfrag*>(TH + (size_t)d * 128 + k0);
        acc[ct] = __builtin_amdgcn_mfma_f32_16x16x32_bf16(af, bf, acc[ct], 0, 0, 0);
      }
    }
  }
  // epilogue: z = acc + x; row sums (C/D layout: col=l15-based, row=lg*4+i)
  float rs[4] = {0.f, 0.f, 0.f, 0.f}, rq[4] = {0.f, 0.f, 0.f, 0.f};
  const int nBase = rb * 64 + wr * 16 + lg * 4;
#pragma unroll
  for (int ct = 0; ct < 4; ++ct) {
    const int ocol = wc * 64 + ct * 16 + l15;
#pragma unroll
    for (int i = 0; i < 4; ++i) {
      const size_t idx = ((size_t)(b * kN + nBase + i)) * kC + ocol;
      float v = acc[ct][i] + x[idx];
      z[idx] = v;
      rs[i] += v; rq[i] += v * v;
    }
  }
#pragma unroll
  for (int m = 1; m < 16; m <<= 1) {
#pragma unroll
    for (int i = 0; i < 4; ++i) { rs[i] += __shfl_xor(rs[i], m); rq[i] += __shfl_xor(rq[i], m); }
  }
  if (l15 == 0) {
#pragma unroll
    for (int i = 0; i < 4; ++i) {
      rsS[wc][wr * 16 + lg * 4 + i] = rs[i];
      rqS[wc][wr * 16 + lg * 4 + i] = rq[i];
    }
  }
  __syncthreads();
  if (tid < 64) {
    const int n = rb * 64 + tid;
    sumz[(size_t)b * kN + n] = rsS[0][tid] + rsS[1][tid];
    sumzz[(size_t)b * kN + n] = rqS[0][tid] + rqS[1][tid];
  }
}

// ---- 11. per-node BN (stats precomputed) + relu + dot(w_out) -> out ----
__global__ __launch_bounds__(256) void k_final(const float* __restrict__ z,
                                               const float* __restrict__ sumz,
                                               const float* __restrict__ sumzz,
                                               const float* __restrict__ g4,
                                               const float* __restrict__ b4v,
                                               const float* __restrict__ w_out,
                                               const float* __restrict__ b_out,
                                               float* __restrict__ out) {
  const int n = blockIdx.x;
  const int tid = threadIdx.x;
  __shared__ float sscale, sshift;
  if (tid < 16) {
    float a = sumz[tid * kN + n];
    float q = sumzz[tid * kN + n];
#pragma unroll
    for (int m = 1; m < 16; m <<= 1) { a += __shfl_xor(a, m); q += __shfl_xor(q, m); }
    if (tid == 0) {
      float mean = a * (1.f / 2048.f);
      float var = fmaxf(q * (1.f / 2048.f) - mean * mean, 0.f);
      float inv = rsqrtf(var + kEPS);
      float gg = g4[n];
      sscale = inv * gg;
      sshift = b4v[n] - mean * inv * gg;
    }
  }
  __syncthreads();
  const float scale = sscale, shift = sshift;
  const int b = tid >> 4, c0 = (tid & 15) * 8;
  float p = 0.f;
#pragma unroll
  for (int j = 0; j < 8; ++j) {
    float v = z[(size_t)(b * kN + n) * kC + c0 + j] * scale + shift;
    v = fmaxf(v, 0.f);
    p += v * w_out[c0 + j];
  }
  for (int o = 8; o > 0; o >>= 1) p += __shfl_down(p, o, 16);
  if ((tid & 15) == 0) out[b * kN + n] = p + b_out[0];
}

extern "C" void kernel_launch(void* const* d_in, const int* in_sizes, int n_in,
                              void* d_out, int out_size, void* d_ws, size_t ws_size,
                              hipStream_t stream) {
  const int*   data = (const int*)d_in[0];
  const float* node_features = (const float*)d_in[1];
  const float* go_adj = (const float*)d_in[2];
  const float* emb  = (const float*)d_in[4];
  const float* w_go = (const float*)d_in[5];
  const float* b_go = (const float*)d_in[6];
  const float* wq   = (const float*)d_in[7];
  const float* wk   = (const float*)d_in[8];
  const float* theta= (const float*)d_in[9];
  const float* g1   = (const float*)d_in[10];
  const float* b1   = (const float*)d_in[11];
  const float* g3   = (const float*)d_in[12];
  const float* b3   = (const float*)d_in[13];
  const float* g4   = (const float*)d_in[14];
  const float* b4   = (const float*)d_in[15];
  const float* w_out= (const float*)d_in[16];
  const float* b_out= (const float*)d_in[17];

  float* ws = (float*)d_ws;
  float* featpart = ws + OFF_FEATPART;
  float* m1t   = ws + OFF_M1;
  float* x     = ws + OFF_X;
  float* z     = ws + OFF_Z;
  float* tcur  = ws + OFF_TCUR;
  float* tnext = ws + OFF_TNEXT;
  float* gopart= ws + OFF_GOPART;
  float* psum  = ws + OFF_PSUM;
  float* sumz  = ws + OFF_SUMZ;
  float* sumzz = ws + OFF_SUMZZ;
  ushort* adj  = (ushort*)(ws + OFF_ADJ);
  ushort* xt   = (ushort*)(ws + OFF_XT);
  ushort* qb   = (ushort*)(ws + OFF_Q);
  ushort* kb   = (ushort*)(ws + OFF_K);
  ushort* tt   = (ushort*)(ws + OFF_TT);
  ushort* thT  = (ushort*)(ws + OFF_THT);

  k_embsum<<<dim3(16, 64), 256, 0, stream>>>(data, emb, featpart);
  k_bn_feat<<<16, 256, 0, stream>>>(featpart, data, g1, b1, theta, m1t, thT);
  k_go_gemm2<<<dim3(64, 4), 256, 0, stream>>>(m1t, w_go, gopart);
  k_go_bn<<<1024, 256, 0, stream>>>(gopart, b_go, node_features, g3, b3, x);
  k_qkgen<<<512, 256, 0, stream>>>(x, wq, wk, qb, kb, xt);
  k_att_stats<<<dim3(16, 16, 2), 512, 0, stream>>>(qb, kb, psum);
  k_adj_emit<<<dim3(8, 16, 16), 512, 0, stream>>>(qb, kb, go_adj, psum, adj);
  k_adjmm_mfma<<<256, 512, 0, stream>>>(adj, xt, nullptr, tcur, 1.0f, tt);
  k_adjmm_mfma<<<256, 512, 0, stream>>>(adj, tt, x, tnext, 2.0f, nullptr);
  k_theta_mfma<<<dim3(16, 16), 512, 0, stream>>>(x, tcur, tnext, thT, z, sumz, sumzz);
  k_final<<<1024, 256, 0, stream>>>(z, sumz, sumzz, g4, b4, w_out, b_out, (float*)d_out);
}

// Round 19
// 162.665 us; speedup vs baseline: 2.0617x; 1.0222x over previous
//
#include <hip/hip_runtime.h>

namespace {
constexpr int kB = 16;
constexpr int kMAXLEN = 1024;
constexpr int kPE = 256;
constexpr int kN = 1024;
constexpr int kEMB = 256;
constexpr int kC = 128;
constexpr float kEPS = 1e-5f;

// workspace offsets in floats
constexpr size_t OFF_FEATPART = 0;                         // 16*64*256 = 262144
constexpr size_t OFF_M1       = 262144;                    // 512*16
constexpr size_t OFF_X        = 270336;                    // 16*1024*128
constexpr size_t OFF_Z        = OFF_X    + 2097152;
constexpr size_t OFF_TCB      = OFF_Z    + 2097152;        // tcur bf16 rows: 2M ushort = 1048576 fl
constexpr size_t OFF_TNB      = OFF_TCB  + 1048576;        // tnext bf16 rows: 1048576 fl
constexpr size_t OFF_GOPART   = OFF_TNB  + 1048576;        // 4*16*65536
constexpr size_t OFF_PSUM     = OFF_GOPART + 4194304;      // 16*16*1024
constexpr size_t OFF_SUMZ     = OFF_PSUM + 262144;
constexpr size_t OFF_SUMZZ    = OFF_SUMZ + 16384;
constexpr size_t OFF_ADJ      = OFF_SUMZZ + 16384;         // 16.8M bf16
constexpr size_t OFF_XT       = OFF_ADJ  + 8388608;
constexpr size_t OFF_Q        = OFF_XT   + 1048576;
constexpr size_t OFF_K        = OFF_Q    + 524288;
constexpr size_t OFF_TT       = OFF_K    + 524288;
constexpr size_t OFF_THT      = OFF_TT   + 1048576;        // 3*128*128 bf16

typedef __attribute__((ext_vector_type(8))) short bfrag;
typedef __attribute__((ext_vector_type(4))) float f32x4;

__device__ inline ushort f2bf(float f) {
  unsigned u = __float_as_uint(f);
  unsigned r = (u + 0x7FFFu + ((u >> 16) & 1u)) >> 16;  // RNE
  return (ushort)r;
}
} // namespace

// ---- 1. embedding gather partial sums: featpart[b][chunk64][e] ----
__global__ __launch_bounds__(256) void k_embsum(const int* __restrict__ data,
                                                const float* __restrict__ emb,
                                                float* __restrict__ featpart) {
  const int b = blockIdx.x, ch = blockIdx.y;   // 16 x 64
  const int e = threadIdx.x;                   // 256
  const int* row = data + b * (kMAXLEN + kPE) + ch * 16;
  float acc = 0.f;
#pragma unroll 4
  for (int l = 0; l < 16; ++l) {
    acc += emb[(size_t)row[l] * kEMB + e];
  }
  featpart[((b * 64 + ch) << 8) + e] = acc;
}

// ---- 2. BN over batch -> m1t; also emits theta^T bf16 ----
__global__ __launch_bounds__(256) void k_bn_feat(const float* __restrict__ featpart,
                                                 const int* __restrict__ data,
                                                 const float* __restrict__ g1,
                                                 const float* __restrict__ b1,
                                                 const float* __restrict__ theta,
                                                 float* __restrict__ m1t,
                                                 ushort* __restrict__ thT) {
  const int tid = threadIdx.x;
  {
    const int gid = blockIdx.x * 256 + tid;
#pragma unroll
    for (int j = 0; j < 12; ++j) {
      const int idx = gid * 12 + j;
      const int s = idx >> 14, rem = idx & 16383;
      const int d = rem >> 7, c = rem & 127;
      thT[idx] = f2bf(theta[(size_t)(s * 128 + c) * 128 + d]);
    }
  }
  const int jl = tid >> 3, part = tid & 7;
  const int j = blockIdx.x * 32 + jl;
  float v[kB];
  if (j < kPE) {
#pragma unroll
    for (int b = 0; b < kB; ++b) {
      float s = 0.f;
      const int ch0 = part * 8;
#pragma unroll
      for (int ch = 0; ch < 8; ++ch)
        s += featpart[((b * 64 + ch0 + ch) << 8) + j];
      v[b] = s;
    }
  } else {
#pragma unroll
    for (int b = 0; b < kB; ++b)
      v[b] = (part == 0) ? (float)data[b * (kMAXLEN + kPE) + kMAXLEN + (j - kPE)] : 0.f;
  }
#pragma unroll
  for (int m = 1; m < 8; m <<= 1) {
#pragma unroll
    for (int b = 0; b < kB; ++b) v[b] += __shfl_xor(v[b], m);
  }
  const float pe = (j < kPE) ? sinf((float)j) : sinf((float)(j - kPE));
#pragma unroll
  for (int b = 0; b < kB; ++b)
    v[b] = (j < kPE) ? (v[b] * (1.f / 1024.f) + pe) : (v[b] + pe);
  float s = 0.f;
#pragma unroll
  for (int b = 0; b < kB; ++b) s += v[b];
  const float mean = s * (1.f / kB);
  float s2 = 0.f;
#pragma unroll
  for (int b = 0; b < kB; ++b) { float d = v[b] - mean; s2 += d * d; }
  const float inv = rsqrtf(s2 * (1.f / kB) + kEPS);
  if (part == 0) {
    const float g = g1[j], bb = b1[j];
    float o[kB];
#pragma unroll
    for (int b = 0; b < kB; ++b) o[b] = (v[b] - mean) * inv * g + bb;
#pragma unroll
    for (int q = 0; q < 4; ++q)
      *reinterpret_cast<float4*>(&m1t[j * kB + q * 4]) =
          *reinterpret_cast<float4*>(&o[q * 4]);
  }
}

// ---- 3a. split-K GEMM, 4 k-slices (m1t via SGPR broadcast) ----
__global__ __launch_bounds__(256) void k_go_gemm2(const float* __restrict__ m1t,
                                                  const float* __restrict__ w_go,
                                                  float* __restrict__ part) {
  const int c0 = blockIdx.x * 1024 + threadIdx.x * 4;
  const int k0 = blockIdx.y * 128;
  float4 acc[kB];
#pragma unroll
  for (int b = 0; b < kB; ++b) acc[b] = make_float4(0.f, 0.f, 0.f, 0.f);
#pragma unroll 4
  for (int k = 0; k < 128; ++k) {
    const float4 w = *reinterpret_cast<const float4*>(&w_go[(size_t)(k0 + k) * 65536 + c0]);
    const float* mrow = m1t + (size_t)(k0 + k) * kB;
#pragma unroll
    for (int b = 0; b < kB; ++b) {
      const float m = mrow[b];
      acc[b].x += m * w.x; acc[b].y += m * w.y;
      acc[b].z += m * w.z; acc[b].w += m * w.w;
    }
  }
  const size_t kb16 = (size_t)blockIdx.y * kB;
#pragma unroll
  for (int b = 0; b < kB; ++b) {
    *reinterpret_cast<float4*>(&part[(kb16 + b) * 65536 + c0]) = acc[b];
  }
}

// ---- 3b+4 fused. per-node: reduce 4 go partials + bias/relu, nf concat, BN -> x ----
__global__ __launch_bounds__(256) void k_go_bn(const float* __restrict__ part,
                                               const float* __restrict__ b_go,
                                               const float* __restrict__ nf,
                                               const float* __restrict__ g3,
                                               const float* __restrict__ b3,
                                               float* __restrict__ x) {
  const int n = blockIdx.x;
  const int tid = threadIdx.x;
  __shared__ float nfs[64];
  if (tid < 64) nfs[tid] = nf[n * 64 + tid];
  float val[4];
  float s = 0.f, s2 = 0.f;
#pragma unroll
  for (int i = 0; i < 4; ++i) {
    const int e = i * 256 + tid;
    const int b = e >> 6, c = e & 63;
    float a = part[(size_t)b * 65536 + n * 64 + c];
#pragma unroll
    for (int kb = 1; kb < 4; ++kb)
      a += part[(size_t)(kb * kB + b) * 65536 + n * 64 + c];
    a = fmaxf(a + b_go[n * 64 + c], 0.f);
    val[i] = a;
    s += a; s2 += a * a;
  }
  __syncthreads();
  if (tid < 64) {
    const float v = nfs[tid];
    s += 16.f * v; s2 += 16.f * v * v;
  }
  for (int o = 32; o > 0; o >>= 1) { s += __shfl_down(s, o); s2 += __shfl_down(s2, o); }
  __shared__ float ls[4], ls2[4];
  __shared__ float sscale, sshift;
  const int w = tid >> 6;
  if ((tid & 63) == 0) { ls[w] = s; ls2[w] = s2; }
  __syncthreads();
  if (tid == 0) {
    float S = ls[0] + ls[1] + ls[2] + ls[3];
    float S2 = ls2[0] + ls2[1] + ls2[2] + ls2[3];
    float mean = S * (1.f / 2048.f);
    float var = fmaxf(S2 * (1.f / 2048.f) - mean * mean, 0.f);
    float inv = rsqrtf(var + kEPS);
    float gg = g3[n];
    sscale = inv * gg;
    sshift = b3[n] - mean * inv * gg;
  }
  __syncthreads();
  const float scale = sscale, shift = sshift;
#pragma unroll
  for (int i = 0; i < 4; ++i) {
    const int e = i * 256 + tid;
    const int b = e >> 6, c = e & 63;
    x[((size_t)(b * kN + n)) * kC + c] = val[i] * scale + shift;
  }
#pragma unroll
  for (int i = 0; i < 4; ++i) {
    const int e = i * 256 + tid;
    const int b = e >> 6, c = e & 63;
    x[((size_t)(b * kN + n)) * kC + 64 + c] = nfs[c] * scale + shift;
  }
}

// ---- 5. q/k projections + fused x^T bf16 emit ----
__global__ __launch_bounds__(256) void k_qkgen(const float* __restrict__ x,
                                               const float* __restrict__ wq,
                                               const float* __restrict__ wk,
                                               ushort* __restrict__ qb,
                                               ushort* __restrict__ kb,
                                               ushort* __restrict__ xt) {
  __shared__ float a_s[32 * 68];
  __shared__ float w_s[32 * 128];
  const int row0 = blockIdx.x * 32;
  const int bb = row0 >> 10, n0 = row0 & 1023;
  const int tid = threadIdx.x;
  const int tr = tid >> 5, tc = tid & 31;
  const int r0 = tr * 4, c0 = tc * 4;
  float acc[4][4] = {};
  for (int kc = 0; kc < 4; ++kc) {
    const int k0 = kc * 32;
    __syncthreads();
    {
      int r = tid >> 3, kk4 = tid & 7;
      float4 v = *reinterpret_cast<const float4*>(&x[(size_t)(row0 + r) * kC + k0 + kk4 * 4]);
      *reinterpret_cast<float4*>(&a_s[r * 68 + kk4 * 4]) = v;
    }
    for (int it = 0; it < 16; ++it) {
      int e = it * 256 + tid;
      int kk = e >> 7, h2 = e & 127;
      int c = k0 + kk;
      float v = (h2 < 64) ? wq[c * 64 + h2] : wk[c * 64 + (h2 - 64)];
      w_s[kk * 128 + h2] = v;
    }
    __syncthreads();
#pragma unroll
    for (int q = 0; q < 4; ++q) {
      const int e = q * 256 + tid;
      const int kk = e >> 5, r = e & 31;
      xt[(size_t)(bb * kC + k0 + kk) * kN + n0 + r] = f2bf(a_s[r * 68 + kk]);
    }
#pragma unroll 8
    for (int k = 0; k < 32; ++k) {
      float a[4];
#pragma unroll
      for (int i = 0; i < 4; ++i) a[i] = a_s[(r0 + i) * 68 + k];
      float4 b4 = *reinterpret_cast<float4*>(&w_s[k * 128 + c0]);
      float bj[4] = {b4.x, b4.y, b4.z, b4.w};
#pragma unroll
      for (int i = 0; i < 4; ++i)
#pragma unroll
        for (int j = 0; j < 4; ++j) acc[i][j] += a[i] * bj[j];
    }
  }
  const bool isq = (c0 < 64);
  const int h0 = isq ? c0 : (c0 - 64);
  ushort* oh = isq ? qb : kb;
#pragma unroll
  for (int i = 0; i < 4; ++i) {
    ushort hs[4];
#pragma unroll
    for (int j = 0; j < 4; ++j) hs[j] = f2bf(acc[i][j]);
    const size_t o = (size_t)(row0 + r0 + i) * 64 + h0;
    *reinterpret_cast<ushort4*>(&oh[o]) = *reinterpret_cast<ushort4*>(hs);
  }
}

// ---- 6. att sum-stats via MFMA (single bf16), K double-buffered LDS ----
__global__ __launch_bounds__(512) void k_att_stats(const ushort* __restrict__ qb,
                                                   const ushort* __restrict__ kb,
                                                   float* __restrict__ psum) {
  const int nt = blockIdx.x, b = blockIdx.y;
  const int mc0 = blockIdx.z * 4;
  __shared__ uint4 smem4[2560];
  char* smem = (char*)smem4;
  const int tid = threadIdx.x;
  const int lane = tid & 63, w = tid >> 6;
  const int l15 = lane & 15, lg = lane >> 4;

  {
    const int r = tid >> 3, ch = tid & 7;
    const size_t g = (size_t)(b * kN + nt * 64 + r) * 64 + ch * 8;
    const unsigned off = (unsigned)(r * 128 + ch * 16) ^ (unsigned)((r & 7) << 4);
    *reinterpret_cast<uint4*>(smem + off) = *reinterpret_cast<const uint4*>(qb + g);
  }

  const int c0s = tid >> 3, c1s = 64 + (tid >> 3);
  const int chs = tid & 7;
  const unsigned offK0 = (unsigned)(c0s * 128 + chs * 16) ^ (unsigned)((c0s & 7) << 4);
  const unsigned offK1 = (unsigned)(c1s * 128 + chs * 16) ^ (unsigned)((c1s & 7) << 4);
  const size_t gK0 = (size_t)(b * kN + mc0 * 128 + c0s) * 64 + chs * 8;
  const size_t gK1 = (size_t)(b * kN + mc0 * 128 + c1s) * 64 + chs * 8;

  uint4 ph0 = *reinterpret_cast<const uint4*>(kb + gK0);
  uint4 ph1 = *reinterpret_cast<const uint4*>(kb + gK1);
  *reinterpret_cast<uint4*>(smem + 8192 + offK0) = ph0;
  *reinterpret_cast<uint4*>(smem + 8192 + offK1) = ph1;
  {
    const size_t k1 = (size_t)128 * 64;
    ph0 = *reinterpret_cast<const uint4*>(kb + gK0 + k1);
    ph1 = *reinterpret_cast<const uint4*>(kb + gK1 + k1);
  }
  __syncthreads();

  for (int it = 0; it < 4; ++it) {
    const int mc = mc0 + it;
    const unsigned bufC = 8192 + (unsigned)(it & 1) * 16384;
    const unsigned bufN = 8192 + (unsigned)((it + 1) & 1) * 16384;
    if (it < 3) {
      *reinterpret_cast<uint4*>(smem + bufN + offK0) = ph0;
      *reinterpret_cast<uint4*>(smem + bufN + offK1) = ph1;
      if (it < 2) {
        const size_t k2 = (size_t)(it + 2) * 128 * 64;
        ph0 = *reinterpret_cast<const uint4*>(kb + gK0 + k2);
        ph1 = *reinterpret_cast<const uint4*>(kb + gK1 + k2);
      }
    }
    f32x4 acc[4] = {{0.f,0.f,0.f,0.f},{0.f,0.f,0.f,0.f},{0.f,0.f,0.f,0.f},{0.f,0.f,0.f,0.f}};
#pragma unroll
    for (int ss = 0; ss < 2; ++ss) {
      const int r = w * 16 + l15;
      const unsigned aoff = ((unsigned)(r * 128 + ss * 64 + lg * 16) ^ (unsigned)((r & 7) << 4)) + bufC;
      bfrag ah = *reinterpret_cast<const bfrag*>(smem + aoff);
#pragma unroll
      for (int nf = 0; nf < 4; ++nf) {
        const int c = nf * 16 + l15;
        const unsigned boff = (unsigned)(c * 128 + ss * 64 + lg * 16) ^ (unsigned)((c & 7) << 4);
        bfrag bh = *reinterpret_cast<const bfrag*>(smem + boff);
        acc[nf] = __builtin_amdgcn_mfma_f32_16x16x32_bf16(ah, bh, acc[nf], 0, 0, 0);
      }
    }
#pragma unroll
    for (int i = 0; i < 4; ++i) {
      float sm = __expf(acc[0][i] * 0.125f) + __expf(acc[1][i] * 0.125f)
               + __expf(acc[2][i] * 0.125f) + __expf(acc[3][i] * 0.125f);
#pragma unroll
      for (int msk = 1; msk < 16; msk <<= 1) sm += __shfl_xor(sm, msk);
      if (l15 == 0) {
        const int m = mc * 128 + w * 16 + lg * 4 + i;
        psum[(size_t)(b * 16 + nt) * kN + m] = sm;
      }
    }
    __syncthreads();
  }
}

// ---- 8. adj emit: recompute Q·K^T, adj = go_adj + exp(s/8)*cinv -> single bf16 ----
__global__ __launch_bounds__(512) void k_adj_emit(const ushort* __restrict__ qb,
                                                  const ushort* __restrict__ kb,
                                                  const float* __restrict__ go_adj,
                                                  const float* __restrict__ psum,
                                                  ushort* __restrict__ adj) {
  const int mc = blockIdx.x, nt = blockIdx.y, b = blockIdx.z;
  __shared__ uint4 smem4[2304];
  __shared__ float cinvs[128];
  char* smem = (char*)smem4;
  float* c32 = (float*)smem4;
  const int tid = threadIdx.x;
  const int lane = tid & 63, w = tid >> 6;
  const int wr = w >> 2, wc = w & 3;
  const int l15 = lane & 15, lg = lane >> 4;

  if (tid < 128) {
    const int m = mc * 128 + tid;
    float S = 0.f;
#pragma unroll
    for (int c = 0; c < 16; ++c) S += psum[(size_t)(b * 16 + c) * kN + m];
    cinvs[tid] = 1.f / S;
  }
  {
    const int r = tid >> 3, ch = tid & 7;
    const size_t g = (size_t)(b * kN + nt * 64 + r) * 64 + ch * 8;
    const unsigned off = (unsigned)(r * 128 + ch * 16) ^ (unsigned)((r & 7) << 4);
    *reinterpret_cast<uint4*>(smem + off) = *reinterpret_cast<const uint4*>(qb + g);
  }
#pragma unroll
  for (int p = 0; p < 2; ++p) {
    const int e = p * 512 + tid;
    const int c = e >> 3, ch = e & 7;
    const size_t g = (size_t)(b * kN + mc * 128 + c) * 64 + ch * 8;
    const unsigned off = (unsigned)(c * 128 + ch * 16) ^ (unsigned)((c & 7) << 4);
    *reinterpret_cast<uint4*>(smem + 8192 + off) = *reinterpret_cast<const uint4*>(kb + g);
  }
  __syncthreads();
  f32x4 acc[2][2] = {{{0.f,0.f,0.f,0.f},{0.f,0.f,0.f,0.f}},
                     {{0.f,0.f,0.f,0.f},{0.f,0.f,0.f,0.f}}};
#pragma unroll
  for (int ss = 0; ss < 2; ++ss) {
    bfrag ah[2], bh[2];
#pragma unroll
    for (int nf = 0; nf < 2; ++nf) {
      const int r = wr * 32 + nf * 16 + l15;
      const unsigned aoff = (unsigned)(r * 128 + ss * 64 + lg * 16) ^ (unsigned)((r & 7) << 4);
      ah[nf] = *reinterpret_cast<const bfrag*>(smem + aoff);
    }
#pragma unroll
    for (int mf = 0; mf < 2; ++mf) {
      const int c = wc * 32 + mf * 16 + l15;
      const unsigned boff = (unsigned)(c * 128 + ss * 64 + lg * 16) ^ (unsigned)((c & 7) << 4);
      bh[mf] = *reinterpret_cast<const bfrag*>(smem + 8192 + boff);
    }
#pragma unroll
    for (int nf = 0; nf < 2; ++nf)
#pragma unroll
      for (int mf = 0; mf < 2; ++mf)
        acc[nf][mf] = __builtin_amdgcn_mfma_f32_16x16x32_bf16(ah[nf], bh[mf], acc[nf][mf], 0, 0, 0);
  }
  __syncthreads();
#pragma unroll
  for (int mf = 0; mf < 2; ++mf) {
    const int mLoc = wc * 32 + mf * 16 + l15;
    const float I = cinvs[mLoc];
#pragma unroll
    for (int nf = 0; nf < 2; ++nf) {
#pragma unroll
      for (int i = 0; i < 4; ++i) {
        const int nLoc = wr * 32 + nf * 16 + lg * 4 + i;
        c32[nLoc * 132 + mLoc] = __expf(acc[nf][mf][i] * 0.125f) * I;
      }
    }
  }
  __syncthreads();
#pragma unroll
  for (int p = 0; p < 2; ++p) {
    const int e = p * 512 + tid;
    const int n = e >> 4, m0 = (e & 15) * 8;
    const float* cr = &c32[n * 132 + m0];
    const float* ga = &go_adj[(size_t)(nt * 64 + n) * kN + mc * 128 + m0];
    ushort hs[8];
#pragma unroll
    for (int j = 0; j < 8; ++j) hs[j] = f2bf(cr[j] + ga[j]);
    const size_t o = (size_t)(b * kN + nt * 64 + n) * kN + mc * 128 + m0;
    *reinterpret_cast<uint4*>(&adj[o]) = *reinterpret_cast<uint4*>(hs);
  }
}

// ---- 9. Yb = bf16(alpha * adj @ X (- Zsub)); double-buffered LDS ----
__global__ __launch_bounds__(512) void k_adjmm_mfma(const ushort* __restrict__ adj,
                                                    const ushort* __restrict__ xt,
                                                    const float* __restrict__ Zsub,
                                                    ushort* __restrict__ Yb, float alpha,
                                                    ushort* __restrict__ yt) {
  const int bid = blockIdx.x;
  const int swz = (bid & 7) * 32 + (bid >> 3);
  const int b = swz >> 4, rb = swz & 15;
  __shared__ uint4 smem4[3072];
  char* smem = (char*)smem4;
  float* c32 = (float*)smem4;
  const int tid = threadIdx.x;
  const int lane = tid & 63, w = tid >> 6;
  const int wr = w >> 1, wc = w & 1;
  const int l15 = lane & 15, lg = lane >> 4;

  const int ra = tid >> 3, cha = tid & 7;
  const unsigned offA = (unsigned)(ra * 128 + cha * 16) ^ (unsigned)((ra & 7) << 4);
  const size_t gA = ((size_t)(b * kN + rb * 64 + ra)) * kN + cha * 8;
  const int cb0 = tid >> 3, cb1 = 64 + (tid >> 3);
  const unsigned offB0 = (unsigned)(cb0 * 128 + cha * 16) ^ (unsigned)((cb0 & 7) << 4);
  const unsigned offB1 = (unsigned)(cb1 * 128 + cha * 16) ^ (unsigned)((cb1 & 7) << 4);
  const size_t gB0 = ((size_t)b * kC + cb0) * kN + cha * 8;
  const size_t gB1 = ((size_t)b * kC + cb1) * kN + cha * 8;

  f32x4 acc[4] = {{0.f,0.f,0.f,0.f},{0.f,0.f,0.f,0.f},{0.f,0.f,0.f,0.f},{0.f,0.f,0.f,0.f}};

  uint4 pa  = *reinterpret_cast<const uint4*>(adj + gA);
  uint4 pb0 = *reinterpret_cast<const uint4*>(xt + gB0);
  uint4 pb1 = *reinterpret_cast<const uint4*>(xt + gB1);
  *reinterpret_cast<uint4*>(smem + offA)         = pa;
  *reinterpret_cast<uint4*>(smem + 8192 + offB0) = pb0;
  *reinterpret_cast<uint4*>(smem + 8192 + offB1) = pb1;
  pa  = *reinterpret_cast<const uint4*>(adj + gA + 64);
  pb0 = *reinterpret_cast<const uint4*>(xt + gB0 + 64);
  pb1 = *reinterpret_cast<const uint4*>(xt + gB1 + 64);
  __syncthreads();

  for (int kt = 0; kt < 16; ++kt) {
    const unsigned bufC = (unsigned)(kt & 1) * 24576;
    const unsigned bufN = (unsigned)((kt + 1) & 1) * 24576;
    if (kt < 15) {
      *reinterpret_cast<uint4*>(smem + bufN + offA)         = pa;
      *reinterpret_cast<uint4*>(smem + bufN + 8192 + offB0) = pb0;
      *reinterpret_cast<uint4*>(smem + bufN + 8192 + offB1) = pb1;
      if (kt < 14) {
        const int k2 = (kt + 2) * 64;
        pa  = *reinterpret_cast<const uint4*>(adj + gA + k2);
        pb0 = *reinterpret_cast<const uint4*>(xt + gB0 + k2);
        pb1 = *reinterpret_cast<const uint4*>(xt + gB1 + k2);
      }
    }
#pragma unroll
    for (int ss = 0; ss < 2; ++ss) {
      const int r = wr * 16 + l15;
      const unsigned aoff = ((unsigned)(r * 128 + ss * 64 + lg * 16) ^ (unsigned)((r & 7) << 4)) + bufC;
      bfrag ah = *reinterpret_cast<const bfrag*>(smem + aoff);
      bfrag bh[4];
#pragma unroll
      for (int ct = 0; ct < 4; ++ct) {
        const int c = wc * 64 + ct * 16 + l15;
        const unsigned boff = ((unsigned)(c * 128 + ss * 64 + lg * 16) ^ (unsigned)((c & 7) << 4)) + bufC;
        bh[ct] = *reinterpret_cast<const bfrag*>(smem + 8192 + boff);
      }
#pragma unroll
      for (int ct = 0; ct < 4; ++ct)
        acc[ct] = __builtin_amdgcn_mfma_f32_16x16x32_bf16(ah, bh[ct], acc[ct], 0, 0, 0);
    }
    __syncthreads();
  }
  const int orow = rb * 64 + wr * 16 + lg * 4;
#pragma unroll
  for (int ct = 0; ct < 4; ++ct) {
    const int ocol = wc * 64 + ct * 16 + l15;
#pragma unroll
    for (int i = 0; i < 4; ++i) {
      const size_t idx = ((size_t)(b * kN + orow + i)) * kC + ocol;
      float v = alpha * acc[ct][i];
      if (Zsub) v -= Zsub[idx];
      Yb[idx] = f2bf(v);
      if (yt) c32[(wr * 16 + lg * 4 + i) * 132 + ocol] = v;
    }
  }
  if (yt) {
    __syncthreads();
    const int c = tid >> 2, nch = tid & 3;
    const int n0 = nch * 16;
    ushort hs[16];
#pragma unroll
    for (int j = 0; j < 16; ++j) hs[j] = f2bf(c32[(n0 + j) * 132 + c]);
    const size_t obase = (size_t)(b * kC + c) * kN + rb * 64 + n0;
    *reinterpret_cast<uint4*>(&yt[obase]) = *reinterpret_cast<uint4*>(hs);
    *reinterpret_cast<uint4*>(&yt[obase + 8]) = *reinterpret_cast<uint4*>(hs + 8);
  }
}

// ---- 10. z = x@th0 + tcur@th1 + tnext@th2 + x via MFMA (tcur/tnext bf16 rows) ----
__global__ __launch_bounds__(512) void k_theta_mfma(const float* __restrict__ x,
                                                    const ushort* __restrict__ tcb,
                                                    const ushort* __restrict__ tnb,
                                                    const ushort* __restrict__ thT,
                                                    float* __restrict__ z,
                                                    float* __restrict__ sumz,
                                                    float* __restrict__ sumzz) {
  const int rb = blockIdx.x, b = blockIdx.y;
  const int tid = threadIdx.x;
  const int lane = tid & 63, w = tid >> 6;
  const int wr = w >> 1, wc = w & 1;
  const int l15 = lane & 15, lg = lane >> 4;
  __shared__ float rsS[2][64], rqS[2][64];

  f32x4 acc[4] = {{0.f,0.f,0.f,0.f},{0.f,0.f,0.f,0.f},{0.f,0.f,0.f,0.f},{0.f,0.f,0.f,0.f}};
  const size_t rowOff = ((size_t)(b * kN + rb * 64 + wr * 16 + l15)) * kC;
  {  // s = 0: x (f32, convert)
    const float* A = x + rowOff;
    const ushort* TH = thT;
#pragma unroll
    for (int ss = 0; ss < 4; ++ss) {
      const int k0 = ss * 32 + lg * 8;
      float4 a0 = *reinterpret_cast<const float4*>(A + k0);
      float4 a1 = *reinterpret_cast<const float4*>(A + k0 + 4);
      ushort av[8] = {f2bf(a0.x), f2bf(a0.y), f2bf(a0.z), f2bf(a0.w),
                      f2bf(a1.x), f2bf(a1.y), f2bf(a1.z), f2bf(a1.w)};
      bfrag af = *reinterpret_cast<bfrag*>(av);
#pragma unroll
      for (int ct = 0; ct < 4; ++ct) {
        const int d = wc * 64 + ct * 16 + l15;
        bfrag bf = *reinterpret_cast<const bfrag*>(TH + (size_t)d * 128 + k0);
        acc[ct] = __builtin_amdgcn_mfma_f32_16x16x32_bf16(af, bf, acc[ct], 0, 0, 0);
      }
    }
  }
  const ushort* srcs2[2] = {tcb, tnb};
#pragma unroll
  for (int s2 = 0; s2 < 2; ++s2) {  // s = 1,2: bf16 rows, direct fragments
    const ushort* A = srcs2[s2] + rowOff;
    const ushort* TH = thT + (size_t)(s2 + 1) * 16384;
#pragma unroll
    for (int ss = 0; ss < 4; ++ss) {
      const int k0 = ss * 32 + lg * 8;
      bfrag af = *reinterpret_cast<const bfrag*>(A + k0);
#pragma unroll
      for (int ct = 0; ct < 4; ++ct) {
        const int d = wc * 64 + ct * 16 + l15;
        bfrag bf = *reinterpret_cast<const bfrag*>(TH + (size_t)d * 128 + k0);
        acc[ct] = __builtin_amdgcn_mfma_f32_16x16x32_bf16(af, bf, acc[ct], 0, 0, 0);
      }
    }
  }
  float rs[4] = {0.f, 0.f, 0.f, 0.f}, rq[4] = {0.f, 0.f, 0.f, 0.f};
  const int nBase = rb * 64 + wr * 16 + lg * 4;
#pragma unroll
  for (int ct = 0; ct < 4; ++ct) {
    const int ocol = wc * 64 + ct * 16 + l15;
#pragma unroll
    for (int i = 0; i < 4; ++i) {
      const size_t idx = ((size_t)(b * kN + nBase + i)) * kC + ocol;
      float v = acc[ct][i] + x[idx];
      z[idx] = v;
      rs[i] += v; rq[i] += v * v;
    }
  }
#pragma unroll
  for (int m = 1; m < 16; m <<= 1) {
#pragma unroll
    for (int i = 0; i < 4; ++i) { rs[i] += __shfl_xor(rs[i], m); rq[i] += __shfl_xor(rq[i], m); }
  }
  if (l15 == 0) {
#pragma unroll
    for (int i = 0; i < 4; ++i) {
      rsS[wc][wr * 16 + lg * 4 + i] = rs[i];
      rqS[wc][wr * 16 + lg * 4 + i] = rq[i];
    }
  }
  __syncthreads();
  if (tid < 64) {
    const int n = rb * 64 + tid;
    sumz[(size_t)b * kN + n] = rsS[0][tid] + rsS[1][tid];
    sumzz[(size_t)b * kN + n] = rqS[0][tid] + rqS[1][tid];
  }
}

// ---- 11. per-node BN (stats precomputed) + relu + dot(w_out) -> out ----
__global__ __launch_bounds__(256) void k_final(const float* __restrict__ z,
                                               const float* __restrict__ sumz,
                                               const float* __restrict__ sumzz,
                                               const float* __restrict__ g4,
                                               const float* __restrict__ b4v,
                                               const float* __restrict__ w_out,
                                               const float* __restrict__ b_out,
                                               float* __restrict__ out) {
  const int n = blockIdx.x;
  const int tid = threadIdx.x;
  __shared__ float sscale, sshift;
  if (tid < 16) {
    float a = sumz[tid * kN + n];
    float q = sumzz[tid * kN + n];
#pragma unroll
    for (int m = 1; m < 16; m <<= 1) { a += __shfl_xor(a, m); q += __shfl_xor(q, m); }
    if (tid == 0) {
      float mean = a * (1.f / 2048.f);
      float var = fmaxf(q * (1.f / 2048.f) - mean * mean, 0.f);
      float inv = rsqrtf(var + kEPS);
      float gg = g4[n];
      sscale = inv * gg;
      sshift = b4v[n] - mean * inv * gg;
    }
  }
  __syncthreads();
  const float scale = sscale, shift = sshift;
  const int b = tid >> 4, c0 = (tid & 15) * 8;
  float p = 0.f;
#pragma unroll
  for (int j = 0; j < 8; ++j) {
    float v = z[(size_t)(b * kN + n) * kC + c0 + j] * scale + shift;
    v = fmaxf(v, 0.f);
    p += v * w_out[c0 + j];
  }
  for (int o = 8; o > 0; o >>= 1) p += __shfl_down(p, o, 16);
  if ((tid & 15) == 0) out[b * kN + n] = p + b_out[0];
}

extern "C" void kernel_launch(void* const* d_in, const int* in_sizes, int n_in,
                              void* d_out, int out_size, void* d_ws, size_t ws_size,
                              hipStream_t stream) {
  const int*   data = (const int*)d_in[0];
  const float* node_features = (const float*)d_in[1];
  const float* go_adj = (const float*)d_in[2];
  const float* emb  = (const float*)d_in[4];
  const float* w_go = (const float*)d_in[5];
  const float* b_go = (const float*)d_in[6];
  const float* wq   = (const float*)d_in[7];
  const float* wk   = (const float*)d_in[8];
  const float* theta= (const float*)d_in[9];
  const float* g1   = (const float*)d_in[10];
  const float* b1   = (const float*)d_in[11];
  const float* g3   = (const float*)d_in[12];
  const float* b3   = (const float*)d_in[13];
  const float* g4   = (const float*)d_in[14];
  const float* b4   = (const float*)d_in[15];
  const float* w_out= (const float*)d_in[16];
  const float* b_out= (const float*)d_in[17];

  float* ws = (float*)d_ws;
  float* featpart = ws + OFF_FEATPART;
  float* m1t   = ws + OFF_M1;
  float* x     = ws + OFF_X;
  float* z     = ws + OFF_Z;
  float* gopart= ws + OFF_GOPART;
  float* psum  = ws + OFF_PSUM;
  float* sumz  = ws + OFF_SUMZ;
  float* sumzz = ws + OFF_SUMZZ;
  ushort* tcb  = (ushort*)(ws + OFF_TCB);
  ushort* tnb  = (ushort*)(ws + OFF_TNB);
  ushort* adj  = (ushort*)(ws + OFF_ADJ);
  ushort* xt   = (ushort*)(ws + OFF_XT);
  ushort* qb   = (ushort*)(ws + OFF_Q);
  ushort* kb   = (ushort*)(ws + OFF_K);
  ushort* tt   = (ushort*)(ws + OFF_TT);
  ushort* thT  = (ushort*)(ws + OFF_THT);

  k_embsum<<<dim3(16, 64), 256, 0, stream>>>(data, emb, featpart);
  k_bn_feat<<<16, 256, 0, stream>>>(featpart, data, g1, b1, theta, m1t, thT);
  k_go_gemm2<<<dim3(64, 4), 256, 0, stream>>>(m1t, w_go, gopart);
  k_go_bn<<<1024, 256, 0, stream>>>(gopart, b_go, node_features, g3, b3, x);
  k_qkgen<<<512, 256, 0, stream>>>(x, wq, wk, qb, kb, xt);
  k_att_stats<<<dim3(16, 16, 2), 512, 0, stream>>>(qb, kb, psum);
  k_adj_emit<<<dim3(8, 16, 16), 512, 0, stream>>>(qb, kb, go_adj, psum, adj);
  k_adjmm_mfma<<<256, 512, 0, stream>>>(adj, xt, nullptr, tcb, 1.0f, tt);
  k_adjmm_mfma<<<256, 512, 0, stream>>>(adj, tt, x, tnb, 2.0f, nullptr);
  k_theta_mfma<<<dim3(16, 16), 512, 0, stream>>>(x, tcb, tnb, thT, z, sumz, sumzz);
  k_final<<<1024, 256, 0, stream>>>(z, sumz, sumzz, g4, b4, w_out, b_out, (float*)d_out);
}